// Round 2
// baseline (6996.716 us; speedup 1.0000x reference)
//
#include <hip/hip_runtime.h>
#include <stdint.h>

// Problem constants
static constexpr int H_ = 200, W_ = 200, HW_ = 40000;
static constexpr int C_ = 512;
static constexpr int A_ = 9;
static constexpr int NANCH = 360000;   // HW_ * A_
static constexpr int KPRE = 1000;
static constexpr int KPOST = 100;

// ---------------------------------------------------------------------------
// K0: weight transpose  w[co][ci][tap] (512 x 4608) -> wt[k=ci*9+tap][co]
// ---------------------------------------------------------------------------
__global__ void k_transpose_w(const float* __restrict__ w, float* __restrict__ wt) {
    __shared__ float t[32][33];
    int kb = blockIdx.x * 32;   // k base (k-dim 4608 = 144*32)
    int cb = blockIdx.y * 32;   // co base (512 = 16*32)
    int lx = threadIdx.x;       // 0..31
    int ly = threadIdx.y;       // 0..7
    for (int r = ly; r < 32; r += 8)
        t[r][lx] = w[(cb + r) * 4608 + kb + lx];
    __syncthreads();
    for (int r = ly; r < 32; r += 8)
        wt[(size_t)(kb + r) * 512 + cb + lx] = t[lx][r];
}

// ---------------------------------------------------------------------------
// K1: 3x3 conv 512->512, SAME pad, + bias + ReLU.  fp32 vector FMA.
// Block tile: 128 co x (8 rows x 16 cols px). 256 threads; per-thread 8co x 8px
// (one row of 8 consecutive cols). K-chunk: 4 input channels (all 9 taps).
// LDS per chunk: weights [4][9][128] (18.4 KB) + input [4][10][20] (3.2 KB).
// Weight reads: 2 b128 per tap feeding 64 FMAs -> LDS/FMA cycle ratio ~1.1.
// ---------------------------------------------------------------------------
__launch_bounds__(256, 4)
__global__ void k_conv3(const float* __restrict__ feat, const float* __restrict__ wt,
                        const float* __restrict__ bias, float* __restrict__ x) {
    __shared__ __align__(16) float wlds[4 * 9 * 128];   // [ci4][tap9][co128]
    __shared__ __align__(16) float ilds[4 * 10 * 20];   // [ci4][row10][col20] (18 used)

    int b = blockIdx.x;
    int cot = b & 3;
    int tile = b >> 2;            // 0..324
    int xt = tile % 13, yt = tile / 13;
    int x0 = xt * 16, y0 = yt * 8;
    int co0 = cot * 128;
    int tid = threadIdx.x;
    int tco = tid >> 4;           // 0..15 -> co = co0 + tco*8
    int tpx = tid & 15;
    int r = tpx >> 1;             // row 0..7
    int half = tpx & 1;           // col oct: cols x0 + half*8 .. +7

    float acc[8][8];
#pragma unroll
    for (int i = 0; i < 8; ++i)
#pragma unroll
        for (int j = 0; j < 8; ++j) acc[i][j] = 0.f;

    for (int ccb = 0; ccb < 512; ccb += 4) {
        // stage weights: 36 rows x 128 floats = 1152 float4
        for (int t = tid; t < 1152; t += 256) {
            int u = t >> 5;               // local (ci*9+tap), 0..35
            int l = (t & 31) << 2;        // co offset
            float4 v = *(const float4*)&wt[(size_t)(ccb * 9 + u) * 512 + co0 + l];
            *(float4*)&wlds[u * 128 + l] = v;
        }
        // stage input: 4 ci x 10 rows x 20 cols (18 real cols, halo, zero-pad)
        for (int t = tid; t < 800; t += 256) {
            int ci = t / 200;
            int rem = t - ci * 200;
            int rr = rem / 20;
            int cc = rem - rr * 20;
            int gy = y0 - 1 + rr, gx = x0 - 1 + cc;
            float v = 0.f;
            if (cc < 18 && (unsigned)gy < (unsigned)H_ && (unsigned)gx < (unsigned)W_)
                v = feat[(size_t)(ccb + ci) * HW_ + gy * W_ + gx];
            ilds[(ci * 10 + rr) * 20 + cc] = v;
        }
        __syncthreads();

#pragma unroll
        for (int ci = 0; ci < 4; ++ci) {
#pragma unroll
            for (int kh = 0; kh < 3; ++kh) {
                // input row r+kh, cols half*8 .. half*8+11 (10 used) : 3x float4
                const float* ip = &ilds[(ci * 10 + r + kh) * 20 + half * 8];
                float iv[12];
                *(float4*)&iv[0] = *(const float4*)&ip[0];
                *(float4*)&iv[4] = *(const float4*)&ip[4];
                *(float4*)&iv[8] = *(const float4*)&ip[8];
#pragma unroll
                for (int kw = 0; kw < 3; ++kw) {
                    const float* wp = &wlds[(ci * 9 + kh * 3 + kw) * 128 + tco * 8];
                    float wv[8];
                    *(float4*)&wv[0] = *(const float4*)&wp[0];
                    *(float4*)&wv[4] = *(const float4*)&wp[4];
#pragma unroll
                    for (int i = 0; i < 8; ++i)
#pragma unroll
                        for (int j = 0; j < 8; ++j)
                            acc[i][j] = fmaf(wv[i], iv[kw + j], acc[i][j]);
                }
            }
        }
        __syncthreads();
    }

    // epilogue: bias + relu, 2x float4 stores per co row
    int gy = y0 + r;
    int gx0 = x0 + half * 8;
    if (gx0 < W_) {  // col octs are fully in (W_ = 25*8) or fully out
        float bv[8];
        *(float4*)&bv[0] = *(const float4*)&bias[co0 + tco * 8];
        *(float4*)&bv[4] = *(const float4*)&bias[co0 + tco * 8 + 4];
#pragma unroll
        for (int i = 0; i < 8; ++i) {
            int co = co0 + tco * 8 + i;
            float o[8];
#pragma unroll
            for (int j = 0; j < 8; ++j) {
                float v = acc[i][j] + bv[i];
                o[j] = v > 0.f ? v : 0.f;
            }
            float* op = &x[(size_t)co * HW_ + gy * W_ + gx0];
            *(float4*)&op[0] = *(float4*)&o[0];
            *(float4*)&op[4] = *(float4*)&o[4];
        }
    }
}

// ---------------------------------------------------------------------------
// K2: cls 1x1 conv (512->9) + bias + sigmoid -> scores[p*9+a]
// ---------------------------------------------------------------------------
__global__ void k_cls(const float* __restrict__ xbuf, const float* __restrict__ cls_w,
                      const float* __restrict__ cls_b, float* __restrict__ scores) {
    __shared__ float wl[9 * 512];
    int tid = threadIdx.x;
    for (int t = tid; t < 9 * 512; t += 256) wl[t] = cls_w[t];
    __syncthreads();
    int p = blockIdx.x * 256 + tid;
    if (p >= HW_) return;
    float acc[9];
#pragma unroll
    for (int a = 0; a < 9; ++a) acc[a] = 0.f;
    for (int ci = 0; ci < C_; ++ci) {
        float xv = xbuf[(size_t)ci * HW_ + p];
#pragma unroll
        for (int a = 0; a < 9; ++a) acc[a] = fmaf(xv, wl[a * 512 + ci], acc[a]);
    }
#pragma unroll
    for (int a = 0; a < 9; ++a) {
        float lg = acc[a] + cls_b[a];
        scores[(size_t)p * 9 + a] = 1.f / (1.f + expf(-lg));
    }
}

// ---------------------------------------------------------------------------
// K3: exact top-1000 (radix select on float bits; ties -> smallest index)
// meta layout: [0]=P (hi16 prefix) [1]=countAboveP [2]=T (full bits)
//              [3]=cntGtT [4]=need(#eq to take) [8]=atomic cnt_gt [9]=atomic cnt_eq
// ---------------------------------------------------------------------------
__global__ void k_zero_u32(unsigned* __restrict__ p, int n) {
    int i = blockIdx.x * 256 + threadIdx.x;
    if (i < n) p[i] = 0u;
}

__global__ void k_hist1(const float* __restrict__ scores, unsigned* __restrict__ hist) {
    int i = blockIdx.x * 256 + threadIdx.x;
    if (i < NANCH) atomicAdd(&hist[__float_as_uint(scores[i]) >> 16], 1u);
}

__global__ void k_hist2(const float* __restrict__ scores, const unsigned* __restrict__ meta,
                        unsigned* __restrict__ hist2) {
    int i = blockIdx.x * 256 + threadIdx.x;
    if (i >= NANCH) return;
    unsigned b = __float_as_uint(scores[i]);
    if ((b >> 16) == meta[0]) atomicAdd(&hist2[b & 0xFFFFu], 1u);
}

// mode 0: hist over hi16, base=0 -> meta[0]=P, meta[1]=countAbove
// mode 1: hist over lo16 (prefix==P), base=meta[1] -> meta[2]=T, meta[3]=cntGt, meta[4]=need
__global__ void k_find_thr(const unsigned* __restrict__ hist, unsigned* __restrict__ meta, int mode) {
    __shared__ unsigned csum[1024];
    int t = threadIdx.x;
    unsigned base = (mode == 0) ? 0u : meta[1];
    unsigned s = 0;
    for (int b = 0; b < 64; ++b) s += hist[t * 64 + b];
    csum[t] = s;
    __syncthreads();
    // inclusive suffix sum: csum[t] = sum_{c>=t}
    for (int off = 1; off < 1024; off <<= 1) {
        unsigned add = (t + off < 1024) ? csum[t + off] : 0u;
        __syncthreads();
        csum[t] += add;
        __syncthreads();
    }
    unsigned run = base + ((t < 1023) ? csum[t + 1] : 0u);
    for (int b = 63; b >= 0; --b) {
        unsigned h = hist[t * 64 + b];
        if (run < (unsigned)KPRE && run + h >= (unsigned)KPRE) {
            if (mode == 0) {
                meta[0] = (unsigned)(t * 64 + b);
                meta[1] = run;
            } else {
                meta[2] = (meta[0] << 16) | (unsigned)(t * 64 + b);
                meta[3] = run;
                meta[4] = (unsigned)KPRE - run;
            }
            break;
        }
        run += h;
    }
}

__global__ void k_collect(const float* __restrict__ scores, unsigned* __restrict__ meta,
                          unsigned* __restrict__ sel_bits, unsigned* __restrict__ sel_idx,
                          unsigned* __restrict__ eq_idx) {
    int i = blockIdx.x * 256 + threadIdx.x;
    if (i >= NANCH) return;
    unsigned b = __float_as_uint(scores[i]);
    unsigned T = meta[2];
    if (b > T) {
        unsigned s = atomicAdd(&meta[8], 1u);
        sel_bits[s] = b;
        sel_idx[s] = (unsigned)i;
    } else if (b == T) {
        unsigned s = atomicAdd(&meta[9], 1u);
        eq_idx[s] = (unsigned)i;
    }
}

__global__ void k_topk_final(const unsigned* __restrict__ sel_bits, const unsigned* __restrict__ sel_idx,
                             const unsigned* __restrict__ eq_idx, const unsigned* __restrict__ meta,
                             unsigned* __restrict__ top_idx, float* __restrict__ top_sc) {
    __shared__ uint64_t keys[1024];
    __shared__ int lcnt;
    __shared__ int lred;
    int t = threadIdx.x;
    unsigned cntGt = meta[3];
    unsigned need = meta[4];
    unsigned cntEq = meta[9];
    unsigned T = meta[2];

    unsigned idx_cut = 0xFFFFFFFFu;
    if (cntEq > need) {
        // smallest m with count(eq_idx <= m) >= need
        unsigned lo = 0, hi = NANCH - 1;
        while (lo < hi) {
            unsigned mid = (lo + hi) >> 1;
            int c = 0;
            for (unsigned e = t; e < cntEq; e += 1024)
                if (eq_idx[e] <= mid) c++;
            if (t == 0) lred = 0;
            __syncthreads();
            atomicAdd(&lred, c);
            __syncthreads();
            int tot = lred;
            __syncthreads();
            if ((unsigned)tot >= need) hi = mid; else lo = mid + 1;
        }
        idx_cut = lo;
    }

    keys[t] = 0ull;
    if (t == 0) lcnt = 0;
    __syncthreads();
    for (unsigned s = t; s < cntGt; s += 1024)
        keys[s] = ((uint64_t)sel_bits[s] << 32) | (uint64_t)(0xFFFFFFFFu - sel_idx[s]);
    for (unsigned e = t; e < cntEq; e += 1024) {
        unsigned ix = eq_idx[e];
        if (ix <= idx_cut) {
            int s2 = (int)cntGt + atomicAdd(&lcnt, 1);
            keys[s2] = ((uint64_t)T << 32) | (uint64_t)(0xFFFFFFFFu - ix);
        }
    }
    __syncthreads();
    // bitonic sort, descending
    for (int k = 2; k <= 1024; k <<= 1) {
        for (int j = k >> 1; j > 0; j >>= 1) {
            int ixj = t ^ j;
            if (ixj > t) {
                uint64_t a = keys[t], b = keys[ixj];
                bool desc = (t & k) == 0;
                if (desc ? (a < b) : (a > b)) { keys[t] = b; keys[ixj] = a; }
            }
            __syncthreads();
        }
    }
    if (t < KPRE) {
        top_sc[t] = __uint_as_float((unsigned)(keys[t] >> 32));
        top_idx[t] = 0xFFFFFFFFu - (unsigned)keys[t];
    }
}

// ---------------------------------------------------------------------------
// K4: reg head for the 1000 selected + decode + clamp; one block (64 thr) each
// ---------------------------------------------------------------------------
__global__ void k_decode(const float* __restrict__ xbuf, const float* __restrict__ reg_w,
                         const float* __restrict__ reg_b, const unsigned* __restrict__ top_idx,
                         float* __restrict__ props, float* __restrict__ areas) {
    int j = blockIdx.x;
    int lane = threadIdx.x;  // 64
    unsigned idx = top_idx[j];
    int pix = (int)(idx / 9u);
    int a = (int)(idx - (unsigned)pix * 9u);
    float s0 = 0, s1 = 0, s2 = 0, s3 = 0;
    for (int c = lane; c < C_; c += 64) {
        float xv = xbuf[(size_t)c * HW_ + pix];
        s0 = fmaf(xv, reg_w[(a * 4 + 0) * C_ + c], s0);
        s1 = fmaf(xv, reg_w[(a * 4 + 1) * C_ + c], s1);
        s2 = fmaf(xv, reg_w[(a * 4 + 2) * C_ + c], s2);
        s3 = fmaf(xv, reg_w[(a * 4 + 3) * C_ + c], s3);
    }
#pragma unroll
    for (int o = 32; o > 0; o >>= 1) {
        s0 += __shfl_down(s0, o);
        s1 += __shfl_down(s1, o);
        s2 += __shfl_down(s2, o);
        s3 += __shfl_down(s3, o);
    }
    if (lane == 0) {
        float d0 = s0 + reg_b[a * 4 + 0];
        float d1 = s1 + reg_b[a * 4 + 1];
        float d2 = s2 + reg_b[a * 4 + 2];
        float d3 = s3 + reg_b[a * 4 + 3];
        int h = pix / W_, w2 = pix - h * W_;
        int rr = a / 3, ss = a - rr * 3;
        float ratio = (rr == 0) ? 0.5f : (rr == 1) ? 1.0f : 2.0f;
        float scale = (ss == 0) ? 128.f : (ss == 1) ? 256.f : 512.f;
        float hr = sqrtf(ratio);
        float wr = 1.0f / hr;
        float wsc = wr * scale, hsc = hr * scale;
        float sx = (float)w2 * 16.f, sy = (float)h * 16.f;
        float a0 = sx - wsc * 0.5f, a1 = sy - hsc * 0.5f;
        float a2 = sx + wsc * 0.5f, a3 = sy + hsc * 0.5f;
        float bw = a2 - a0, bh = a3 - a1;
        float cx = a0 + 0.5f * bw, cy = a1 + 0.5f * bh;
        float px = d0 * bw + cx, py = d1 * bh + cy;
        float pw = expf(d2) * bw, ph = expf(d3) * bh;
        float b0 = px - 0.5f * pw, b1 = py - 0.5f * ph;
        float b2 = px + 0.5f * pw, b3 = py + 0.5f * ph;
        b0 = fminf(fmaxf(b0, 0.f), 3200.f);
        b1 = fminf(fmaxf(b1, 0.f), 3200.f);
        b2 = fminf(fmaxf(b2, 0.f), 3200.f);
        b3 = fminf(fmaxf(b3, 0.f), 3200.f);
        props[j * 4 + 0] = b0;
        props[j * 4 + 1] = b1;
        props[j * 4 + 2] = b2;
        props[j * 4 + 3] = b3;
        areas[j] = (b2 - b0) * (b3 - b1);
    }
}

// ---------------------------------------------------------------------------
// K5: NMS suppression bitmask (1000 x 16 words); block i vs all j
// ---------------------------------------------------------------------------
__global__ void k_nms_mask(const float* __restrict__ props, const float* __restrict__ areas,
                           unsigned long long* __restrict__ mask, float* __restrict__ out) {
    int i = blockIdx.x;
    int tid = threadIdx.x;  // 256
    if (i == 0) {
        for (int t = tid; t < KPOST * 5; t += 256) out[t] = 0.f;
    }
    float x1i = props[i * 4 + 0], y1i = props[i * 4 + 1];
    float x2i = props[i * 4 + 2], y2i = props[i * 4 + 3];
    float ai = areas[i];
#pragma unroll
    for (int k = 0; k < 4; ++k) {
        int j = k * 256 + tid;
        bool sup = false;
        if (j < KPRE && j > i) {
            float iw = fminf(x2i, props[j * 4 + 2]) - fmaxf(x1i, props[j * 4 + 0]);
            float ih = fminf(y2i, props[j * 4 + 3]) - fmaxf(y1i, props[j * 4 + 1]);
            iw = fmaxf(iw, 0.f);
            ih = fmaxf(ih, 0.f);
            float inter = iw * ih;
            float iou = inter / (ai + areas[j] - inter);
            sup = iou > 0.7f;
        }
        unsigned long long b = __ballot(sup);
        int word = k * 4 + (tid >> 6);
        if ((tid & 63) == 0) mask[(size_t)i * 16 + word] = b;
    }
}

// ---------------------------------------------------------------------------
// K6: serial NMS scan over bitmask + compact first 100 kept -> output
// single wave (64 threads); lanes 0..15 own the 16 keep words
// ---------------------------------------------------------------------------
__global__ void k_nms_scan_out(const unsigned long long* __restrict__ mask,
                               const float* __restrict__ props, const float* __restrict__ top_sc,
                               float* __restrict__ out) {
    int lane = threadIdx.x;  // 64
    unsigned long long keep = 0ull;
    if (lane < 16) keep = (lane < 15) ? ~0ull : ((1ull << 40) - 1);  // 1000 bits
    for (int i = 0; i < KPRE; ++i) {
        unsigned long long kw = __shfl(keep, i >> 6);
        if ((kw >> (i & 63)) & 1ull) {
            if (lane < 16) keep &= ~mask[(size_t)i * 16 + lane];
        }
    }
    int pcv = (lane < 16) ? (int)__popcll(keep) : 0;
    int pre = 0;
    for (int j = 0; j < 16; ++j) {
        int v = __shfl(pcv, j);
        if (j < lane) pre += v;
    }
    for (int w = 0; w < 16; ++w) {
        unsigned long long kw = __shfl(keep, w);
        int base = __shfl(pre, w);
        int idx = w * 64 + lane;
        if (idx < KPRE && ((kw >> lane) & 1ull)) {
            int rank = base + (int)__popcll(kw & ((1ull << lane) - 1ull));
            if (rank < KPOST) {
                out[rank * 4 + 0] = props[idx * 4 + 0];
                out[rank * 4 + 1] = props[idx * 4 + 1];
                out[rank * 4 + 2] = props[idx * 4 + 2];
                out[rank * 4 + 3] = props[idx * 4 + 3];
                out[KPOST * 4 + rank] = top_sc[idx];
            }
        }
    }
}

// ---------------------------------------------------------------------------
extern "C" void kernel_launch(void* const* d_in, const int* in_sizes, int n_in,
                              void* d_out, int out_size, void* d_ws, size_t ws_size,
                              hipStream_t stream) {
    const float* feat   = (const float*)d_in[0];
    const float* conv_w = (const float*)d_in[1];
    const float* conv_b = (const float*)d_in[2];
    const float* cls_w  = (const float*)d_in[3];
    const float* cls_b  = (const float*)d_in[4];
    const float* reg_w  = (const float*)d_in[5];
    const float* reg_b  = (const float*)d_in[6];
    float* out = (float*)d_out;

    // workspace bump allocator (256B aligned)
    size_t off = 0;
    auto alloc = [&](size_t bytes) -> void* {
        off = (off + 255) & ~(size_t)255;
        void* p = (char*)d_ws + off;
        off += bytes;
        return p;
    };
    float* wt      = (float*)alloc((size_t)4608 * 512 * 4);       // 9.44 MB
    float* xbuf    = (float*)alloc((size_t)C_ * HW_ * 4);         // 81.9 MB
    float* scores  = (float*)alloc((size_t)NANCH * 4);            // 1.44 MB
    unsigned* hist1 = (unsigned*)alloc(65536 * 4);
    unsigned* hist2 = (unsigned*)alloc(65536 * 4);
    unsigned* meta  = (unsigned*)alloc(64 * 4);
    unsigned* sel_bits = (unsigned*)alloc(1024 * 4);
    unsigned* sel_idx  = (unsigned*)alloc(1024 * 4);
    unsigned* eq_idx   = (unsigned*)alloc((size_t)NANCH * 4);     // 1.44 MB
    unsigned* top_idx  = (unsigned*)alloc(KPRE * 4);
    float* top_sc      = (float*)alloc(KPRE * 4);
    float* props       = (float*)alloc(KPRE * 4 * 4);
    float* areas       = (float*)alloc(KPRE * 4);
    unsigned long long* mask = (unsigned long long*)alloc((size_t)KPRE * 16 * 8);
    (void)ws_size; (void)in_sizes; (void)n_in; (void)out_size;

    // 0) transpose weights
    k_transpose_w<<<dim3(144, 16), dim3(32, 8), 0, stream>>>(conv_w, wt);
    // 1) conv 3x3 + bias + relu (4 co-tiles x 25 row-tiles x 13 col-tiles)
    k_conv3<<<4 * 25 * 13, 256, 0, stream>>>(feat, wt, conv_b, xbuf);
    // 2) cls head + sigmoid
    k_cls<<<(HW_ + 255) / 256, 256, 0, stream>>>(xbuf, cls_w, cls_b, scores);
    // 3) top-1000 radix select (hist1/hist2/meta are contiguous: zero in one go)
    k_zero_u32<<<(65536 * 2 + 64 + 255) / 256, 256, 0, stream>>>(hist1, 65536 * 2 + 64);
    k_hist1<<<(NANCH + 255) / 256, 256, 0, stream>>>(scores, hist1);
    k_find_thr<<<1, 1024, 0, stream>>>(hist1, meta, 0);
    k_hist2<<<(NANCH + 255) / 256, 256, 0, stream>>>(scores, meta, hist2);
    k_find_thr<<<1, 1024, 0, stream>>>(hist2, meta, 1);
    k_collect<<<(NANCH + 255) / 256, 256, 0, stream>>>(scores, meta, sel_bits, sel_idx, eq_idx);
    k_topk_final<<<1, 1024, 0, stream>>>(sel_bits, sel_idx, eq_idx, meta, top_idx, top_sc);
    // 4) reg head + decode + clamp for selected
    k_decode<<<KPRE, 64, 0, stream>>>(xbuf, reg_w, reg_b, top_idx, props, areas);
    // 5) NMS mask (+ zero d_out)
    k_nms_mask<<<KPRE, 256, 0, stream>>>(props, areas, mask, out);
    // 6) NMS scan + compact to outputs
    k_nms_scan_out<<<1, 64, 0, stream>>>(mask, props, top_sc, out);
}

// Round 3
// 4011.893 us; speedup vs baseline: 1.7440x; 1.7440x over previous
//
#include <hip/hip_runtime.h>
#include <stdint.h>

// Problem constants
static constexpr int H_ = 200, W_ = 200, HW_ = 40000;
static constexpr int C_ = 512;
static constexpr int A_ = 9;
static constexpr int NANCH = 360000;   // HW_ * A_
static constexpr int KPRE = 1000;
static constexpr int KPOST = 100;

// ---------------------------------------------------------------------------
// K0: weight transpose  w[co][ci][tap] (512 x 4608) -> wt[k=ci*9+tap][co]
// ---------------------------------------------------------------------------
__global__ void k_transpose_w(const float* __restrict__ w, float* __restrict__ wt) {
    __shared__ float t[32][33];
    int kb = blockIdx.x * 32;   // k base (k-dim 4608 = 144*32)
    int cb = blockIdx.y * 32;   // co base (512 = 16*32)
    int lx = threadIdx.x;       // 0..31
    int ly = threadIdx.y;       // 0..7
    for (int r = ly; r < 32; r += 8)
        t[r][lx] = w[(cb + r) * 4608 + kb + lx];
    __syncthreads();
    for (int r = ly; r < 32; r += 8)
        wt[(size_t)(kb + r) * 512 + cb + lx] = t[lx][r];
}

// ---------------------------------------------------------------------------
// K1: 3x3 conv 512->512, SAME pad, + bias + ReLU.  fp32 vector FMA.
// Block tile: 128 co x (8 rows x 16 cols px). 256 threads; per-thread 8co x 8px.
// NOTE: __launch_bounds__(256,4) made clang target 8 waves/EU -> 64 VGPR cap
// -> acc[8][8] spilled (13.8 GB scratch writes, R2). Need-based allocation via
// amdgpu_waves_per_eu(2,4): budget 256, target <=4 waves/EU, ~110 VGPR, no spill.
// ---------------------------------------------------------------------------
__global__ __launch_bounds__(256)
__attribute__((amdgpu_waves_per_eu(2, 4)))
void k_conv3(const float* __restrict__ feat, const float* __restrict__ wt,
             const float* __restrict__ bias, float* __restrict__ x) {
    __shared__ __align__(16) float wlds[4 * 9 * 128];   // [ci4][tap9][co128]
    __shared__ __align__(16) float ilds[4 * 10 * 20];   // [ci4][row10][col20] (18 used)

    int b = blockIdx.x;
    int cot = b / 325;            // tile-major: consecutive blocks share co-slice (L2)
    int tile = b - cot * 325;     // 0..324
    int xt = tile % 13, yt = tile / 13;
    int x0 = xt * 16, y0 = yt * 8;
    int co0 = cot * 128;
    int tid = threadIdx.x;
    int tco = tid >> 4;           // 0..15 -> co = co0 + tco*8
    int tpx = tid & 15;
    int r = tpx >> 1;             // row 0..7
    int half = tpx & 1;           // col oct: cols x0 + half*8 .. +7

    float acc[8][8];
#pragma unroll
    for (int i = 0; i < 8; ++i)
#pragma unroll
        for (int j = 0; j < 8; ++j) acc[i][j] = 0.f;

    for (int ccb = 0; ccb < 512; ccb += 4) {
        // stage weights: 36 rows x 128 floats = 1152 float4
        for (int t = tid; t < 1152; t += 256) {
            int u = t >> 5;               // local (ci*9+tap), 0..35
            int l = (t & 31) << 2;        // co offset
            float4 v = *(const float4*)&wt[(size_t)(ccb * 9 + u) * 512 + co0 + l];
            *(float4*)&wlds[u * 128 + l] = v;
        }
        // stage input: 4 ci x 10 rows x 20 cols (18 real cols, halo, zero-pad)
        for (int t = tid; t < 800; t += 256) {
            int ci = t / 200;
            int rem = t - ci * 200;
            int rr = rem / 20;
            int cc = rem - rr * 20;
            int gy = y0 - 1 + rr, gx = x0 - 1 + cc;
            float v = 0.f;
            if (cc < 18 && (unsigned)gy < (unsigned)H_ && (unsigned)gx < (unsigned)W_)
                v = feat[(size_t)(ccb + ci) * HW_ + gy * W_ + gx];
            ilds[(ci * 10 + rr) * 20 + cc] = v;
        }
        __syncthreads();

#pragma unroll
        for (int ci = 0; ci < 4; ++ci) {
#pragma unroll
            for (int kh = 0; kh < 3; ++kh) {
                // input row r+kh, cols half*8 .. half*8+11 (10 used) : 3x float4
                const float* ip = &ilds[(ci * 10 + r + kh) * 20 + half * 8];
                float iv[12];
                *(float4*)&iv[0] = *(const float4*)&ip[0];
                *(float4*)&iv[4] = *(const float4*)&ip[4];
                *(float4*)&iv[8] = *(const float4*)&ip[8];
#pragma unroll
                for (int kw = 0; kw < 3; ++kw) {
                    const float* wp = &wlds[(ci * 9 + kh * 3 + kw) * 128 + tco * 8];
                    float wv[8];
                    *(float4*)&wv[0] = *(const float4*)&wp[0];
                    *(float4*)&wv[4] = *(const float4*)&wp[4];
#pragma unroll
                    for (int i = 0; i < 8; ++i)
#pragma unroll
                        for (int j = 0; j < 8; ++j)
                            acc[i][j] = fmaf(wv[i], iv[kw + j], acc[i][j]);
                }
            }
        }
        __syncthreads();
    }

    // epilogue: bias + relu, 2x float4 stores per co row
    int gy = y0 + r;
    int gx0 = x0 + half * 8;
    if (gx0 < W_) {  // col octs are fully in (W_ = 25*8) or fully out
        float bv[8];
        *(float4*)&bv[0] = *(const float4*)&bias[co0 + tco * 8];
        *(float4*)&bv[4] = *(const float4*)&bias[co0 + tco * 8 + 4];
#pragma unroll
        for (int i = 0; i < 8; ++i) {
            int co = co0 + tco * 8 + i;
            float o[8];
#pragma unroll
            for (int j = 0; j < 8; ++j) {
                float v = acc[i][j] + bv[i];
                o[j] = v > 0.f ? v : 0.f;
            }
            float* op = &x[(size_t)co * HW_ + gy * W_ + gx0];
            *(float4*)&op[0] = *(float4*)&o[0];
            *(float4*)&op[4] = *(float4*)&o[4];
        }
    }
}

// ---------------------------------------------------------------------------
// K2: cls 1x1 conv (512->9) + bias + sigmoid -> scores[p*9+a]
// 64 px/block, 4 ci-chunks of 128 across threads, LDS reduce. 625 blocks.
// ---------------------------------------------------------------------------
__global__ void k_cls(const float* __restrict__ xbuf, const float* __restrict__ cls_w,
                      const float* __restrict__ cls_b, float* __restrict__ scores) {
    __shared__ float wl[9 * 512];
    __shared__ float red[3][64][10];
    int tid = threadIdx.x;
    for (int t = tid; t < 9 * 512; t += 256) wl[t] = cls_w[t];
    __syncthreads();
    int px = tid & 63, ch = tid >> 6;       // ch 0..3
    int p = blockIdx.x * 64 + px;
    float acc[9];
#pragma unroll
    for (int a = 0; a < 9; ++a) acc[a] = 0.f;
    int c0 = ch * 128;
    for (int ci = c0; ci < c0 + 128; ++ci) {
        float xv = xbuf[(size_t)ci * HW_ + p];
#pragma unroll
        for (int a = 0; a < 9; ++a) acc[a] = fmaf(xv, wl[a * 512 + ci], acc[a]);
    }
    if (ch > 0) {
#pragma unroll
        for (int a = 0; a < 9; ++a) red[ch - 1][px][a] = acc[a];
    }
    __syncthreads();
    if (ch == 0) {
#pragma unroll
        for (int a = 0; a < 9; ++a) {
            float lg = acc[a] + red[0][px][a] + red[1][px][a] + red[2][px][a] + cls_b[a];
            scores[(size_t)p * 9 + a] = 1.f / (1.f + expf(-lg));
        }
    }
}

// ---------------------------------------------------------------------------
// K3: exact top-1000 (radix select on float bits; ties -> smallest index)
// meta layout: [0]=P (hi16 prefix) [1]=countAboveP [2]=T (full bits)
//              [3]=cntGtT [4]=need(#eq to take) [8]=atomic cnt_gt [9]=atomic cnt_eq
// ---------------------------------------------------------------------------
__global__ void k_zero_u32(unsigned* __restrict__ p, int n) {
    int i = blockIdx.x * 256 + threadIdx.x;
    if (i < n) p[i] = 0u;
}

__global__ void k_hist1(const float* __restrict__ scores, unsigned* __restrict__ hist) {
    int i = blockIdx.x * 256 + threadIdx.x;
    if (i < NANCH) atomicAdd(&hist[__float_as_uint(scores[i]) >> 16], 1u);
}

__global__ void k_hist2(const float* __restrict__ scores, const unsigned* __restrict__ meta,
                        unsigned* __restrict__ hist2) {
    int i = blockIdx.x * 256 + threadIdx.x;
    if (i >= NANCH) return;
    unsigned b = __float_as_uint(scores[i]);
    if ((b >> 16) == meta[0]) atomicAdd(&hist2[b & 0xFFFFu], 1u);
}

// mode 0: hist over hi16, base=0 -> meta[0]=P, meta[1]=countAbove
// mode 1: hist over lo16 (prefix==P), base=meta[1] -> meta[2]=T, meta[3]=cntGt, meta[4]=need
__global__ void k_find_thr(const unsigned* __restrict__ hist, unsigned* __restrict__ meta, int mode) {
    __shared__ unsigned csum[1024];
    int t = threadIdx.x;
    unsigned base = (mode == 0) ? 0u : meta[1];
    unsigned s = 0;
    for (int b = 0; b < 64; ++b) s += hist[t * 64 + b];
    csum[t] = s;
    __syncthreads();
    // inclusive suffix sum: csum[t] = sum_{c>=t}
    for (int off = 1; off < 1024; off <<= 1) {
        unsigned add = (t + off < 1024) ? csum[t + off] : 0u;
        __syncthreads();
        csum[t] += add;
        __syncthreads();
    }
    unsigned run = base + ((t < 1023) ? csum[t + 1] : 0u);
    for (int b = 63; b >= 0; --b) {
        unsigned h = hist[t * 64 + b];
        if (run < (unsigned)KPRE && run + h >= (unsigned)KPRE) {
            if (mode == 0) {
                meta[0] = (unsigned)(t * 64 + b);
                meta[1] = run;
            } else {
                meta[2] = (meta[0] << 16) | (unsigned)(t * 64 + b);
                meta[3] = run;
                meta[4] = (unsigned)KPRE - run;
            }
            break;
        }
        run += h;
    }
}

__global__ void k_collect(const float* __restrict__ scores, unsigned* __restrict__ meta,
                          unsigned* __restrict__ sel_bits, unsigned* __restrict__ sel_idx,
                          unsigned* __restrict__ eq_idx) {
    int i = blockIdx.x * 256 + threadIdx.x;
    if (i >= NANCH) return;
    unsigned b = __float_as_uint(scores[i]);
    unsigned T = meta[2];
    if (b > T) {
        unsigned s = atomicAdd(&meta[8], 1u);
        sel_bits[s] = b;
        sel_idx[s] = (unsigned)i;
    } else if (b == T) {
        unsigned s = atomicAdd(&meta[9], 1u);
        eq_idx[s] = (unsigned)i;
    }
}

__global__ void k_topk_final(const unsigned* __restrict__ sel_bits, const unsigned* __restrict__ sel_idx,
                             const unsigned* __restrict__ eq_idx, const unsigned* __restrict__ meta,
                             unsigned* __restrict__ top_idx, float* __restrict__ top_sc) {
    __shared__ uint64_t keys[1024];
    __shared__ int lcnt;
    __shared__ int lred;
    int t = threadIdx.x;
    unsigned cntGt = meta[3];
    unsigned need = meta[4];
    unsigned cntEq = meta[9];
    unsigned T = meta[2];

    unsigned idx_cut = 0xFFFFFFFFu;
    if (cntEq > need) {
        // smallest m with count(eq_idx <= m) >= need
        unsigned lo = 0, hi = NANCH - 1;
        while (lo < hi) {
            unsigned mid = (lo + hi) >> 1;
            int c = 0;
            for (unsigned e = t; e < cntEq; e += 1024)
                if (eq_idx[e] <= mid) c++;
            if (t == 0) lred = 0;
            __syncthreads();
            atomicAdd(&lred, c);
            __syncthreads();
            int tot = lred;
            __syncthreads();
            if ((unsigned)tot >= need) hi = mid; else lo = mid + 1;
        }
        idx_cut = lo;
    }

    keys[t] = 0ull;
    if (t == 0) lcnt = 0;
    __syncthreads();
    for (unsigned s = t; s < cntGt; s += 1024)
        keys[s] = ((uint64_t)sel_bits[s] << 32) | (uint64_t)(0xFFFFFFFFu - sel_idx[s]);
    for (unsigned e = t; e < cntEq; e += 1024) {
        unsigned ix = eq_idx[e];
        if (ix <= idx_cut) {
            int s2 = (int)cntGt + atomicAdd(&lcnt, 1);
            keys[s2] = ((uint64_t)T << 32) | (uint64_t)(0xFFFFFFFFu - ix);
        }
    }
    __syncthreads();
    // bitonic sort, descending
    for (int k = 2; k <= 1024; k <<= 1) {
        for (int j = k >> 1; j > 0; j >>= 1) {
            int ixj = t ^ j;
            if (ixj > t) {
                uint64_t a = keys[t], b = keys[ixj];
                bool desc = (t & k) == 0;
                if (desc ? (a < b) : (a > b)) { keys[t] = b; keys[ixj] = a; }
            }
            __syncthreads();
        }
    }
    if (t < KPRE) {
        top_sc[t] = __uint_as_float((unsigned)(keys[t] >> 32));
        top_idx[t] = 0xFFFFFFFFu - (unsigned)keys[t];
    }
}

// ---------------------------------------------------------------------------
// K4: reg head for the 1000 selected + decode + clamp; one block (64 thr) each
// ---------------------------------------------------------------------------
__global__ void k_decode(const float* __restrict__ xbuf, const float* __restrict__ reg_w,
                         const float* __restrict__ reg_b, const unsigned* __restrict__ top_idx,
                         float* __restrict__ props, float* __restrict__ areas) {
    int j = blockIdx.x;
    int lane = threadIdx.x;  // 64
    unsigned idx = top_idx[j];
    int pix = (int)(idx / 9u);
    int a = (int)(idx - (unsigned)pix * 9u);
    float s0 = 0, s1 = 0, s2 = 0, s3 = 0;
    for (int c = lane; c < C_; c += 64) {
        float xv = xbuf[(size_t)c * HW_ + pix];
        s0 = fmaf(xv, reg_w[(a * 4 + 0) * C_ + c], s0);
        s1 = fmaf(xv, reg_w[(a * 4 + 1) * C_ + c], s1);
        s2 = fmaf(xv, reg_w[(a * 4 + 2) * C_ + c], s2);
        s3 = fmaf(xv, reg_w[(a * 4 + 3) * C_ + c], s3);
    }
#pragma unroll
    for (int o = 32; o > 0; o >>= 1) {
        s0 += __shfl_down(s0, o);
        s1 += __shfl_down(s1, o);
        s2 += __shfl_down(s2, o);
        s3 += __shfl_down(s3, o);
    }
    if (lane == 0) {
        float d0 = s0 + reg_b[a * 4 + 0];
        float d1 = s1 + reg_b[a * 4 + 1];
        float d2 = s2 + reg_b[a * 4 + 2];
        float d3 = s3 + reg_b[a * 4 + 3];
        int h = pix / W_, w2 = pix - h * W_;
        int rr = a / 3, ss = a - rr * 3;
        float ratio = (rr == 0) ? 0.5f : (rr == 1) ? 1.0f : 2.0f;
        float scale = (ss == 0) ? 128.f : (ss == 1) ? 256.f : 512.f;
        float hr = sqrtf(ratio);
        float wr = 1.0f / hr;
        float wsc = wr * scale, hsc = hr * scale;
        float sx = (float)w2 * 16.f, sy = (float)h * 16.f;
        float a0 = sx - wsc * 0.5f, a1 = sy - hsc * 0.5f;
        float a2 = sx + wsc * 0.5f, a3 = sy + hsc * 0.5f;
        float bw = a2 - a0, bh = a3 - a1;
        float cx = a0 + 0.5f * bw, cy = a1 + 0.5f * bh;
        float px = d0 * bw + cx, py = d1 * bh + cy;
        float pw = expf(d2) * bw, ph = expf(d3) * bh;
        float b0 = px - 0.5f * pw, b1 = py - 0.5f * ph;
        float b2 = px + 0.5f * pw, b3 = py + 0.5f * ph;
        b0 = fminf(fmaxf(b0, 0.f), 3200.f);
        b1 = fminf(fmaxf(b1, 0.f), 3200.f);
        b2 = fminf(fmaxf(b2, 0.f), 3200.f);
        b3 = fminf(fmaxf(b3, 0.f), 3200.f);
        props[j * 4 + 0] = b0;
        props[j * 4 + 1] = b1;
        props[j * 4 + 2] = b2;
        props[j * 4 + 3] = b3;
        areas[j] = (b2 - b0) * (b3 - b1);
    }
}

// ---------------------------------------------------------------------------
// K5: NMS suppression bitmask (1000 x 16 words); block i vs all j
// ---------------------------------------------------------------------------
__global__ void k_nms_mask(const float* __restrict__ props, const float* __restrict__ areas,
                           unsigned long long* __restrict__ mask, float* __restrict__ out) {
    int i = blockIdx.x;
    int tid = threadIdx.x;  // 256
    if (i == 0) {
        for (int t = tid; t < KPOST * 5; t += 256) out[t] = 0.f;
    }
    float x1i = props[i * 4 + 0], y1i = props[i * 4 + 1];
    float x2i = props[i * 4 + 2], y2i = props[i * 4 + 3];
    float ai = areas[i];
#pragma unroll
    for (int k = 0; k < 4; ++k) {
        int j = k * 256 + tid;
        bool sup = false;
        if (j < KPRE && j > i) {
            float iw = fminf(x2i, props[j * 4 + 2]) - fmaxf(x1i, props[j * 4 + 0]);
            float ih = fminf(y2i, props[j * 4 + 3]) - fmaxf(y1i, props[j * 4 + 1]);
            iw = fmaxf(iw, 0.f);
            ih = fmaxf(ih, 0.f);
            float inter = iw * ih;
            float iou = inter / (ai + areas[j] - inter);
            sup = iou > 0.7f;
        }
        unsigned long long b = __ballot(sup);
        int word = k * 4 + (tid >> 6);
        if ((tid & 63) == 0) mask[(size_t)i * 16 + word] = b;
    }
}

// ---------------------------------------------------------------------------
// K6: serial NMS scan over bitmask + compact first 100 kept -> output
// single wave (64 threads); lanes 0..15 own the 16 keep words
// ---------------------------------------------------------------------------
__global__ void k_nms_scan_out(const unsigned long long* __restrict__ mask,
                               const float* __restrict__ props, const float* __restrict__ top_sc,
                               float* __restrict__ out) {
    int lane = threadIdx.x;  // 64
    unsigned long long keep = 0ull;
    if (lane < 16) keep = (lane < 15) ? ~0ull : ((1ull << 40) - 1);  // 1000 bits
    for (int i = 0; i < KPRE; ++i) {
        unsigned long long kw = __shfl(keep, i >> 6);
        if ((kw >> (i & 63)) & 1ull) {
            if (lane < 16) keep &= ~mask[(size_t)i * 16 + lane];
        }
    }
    int pcv = (lane < 16) ? (int)__popcll(keep) : 0;
    int pre = 0;
    for (int j = 0; j < 16; ++j) {
        int v = __shfl(pcv, j);
        if (j < lane) pre += v;
    }
    for (int w = 0; w < 16; ++w) {
        unsigned long long kw = __shfl(keep, w);
        int base = __shfl(pre, w);
        int idx = w * 64 + lane;
        if (idx < KPRE && ((kw >> lane) & 1ull)) {
            int rank = base + (int)__popcll(kw & ((1ull << lane) - 1ull));
            if (rank < KPOST) {
                out[rank * 4 + 0] = props[idx * 4 + 0];
                out[rank * 4 + 1] = props[idx * 4 + 1];
                out[rank * 4 + 2] = props[idx * 4 + 2];
                out[rank * 4 + 3] = props[idx * 4 + 3];
                out[KPOST * 4 + rank] = top_sc[idx];
            }
        }
    }
}

// ---------------------------------------------------------------------------
extern "C" void kernel_launch(void* const* d_in, const int* in_sizes, int n_in,
                              void* d_out, int out_size, void* d_ws, size_t ws_size,
                              hipStream_t stream) {
    const float* feat   = (const float*)d_in[0];
    const float* conv_w = (const float*)d_in[1];
    const float* conv_b = (const float*)d_in[2];
    const float* cls_w  = (const float*)d_in[3];
    const float* cls_b  = (const float*)d_in[4];
    const float* reg_w  = (const float*)d_in[5];
    const float* reg_b  = (const float*)d_in[6];
    float* out = (float*)d_out;

    // workspace bump allocator (256B aligned)
    size_t off = 0;
    auto alloc = [&](size_t bytes) -> void* {
        off = (off + 255) & ~(size_t)255;
        void* p = (char*)d_ws + off;
        off += bytes;
        return p;
    };
    float* wt      = (float*)alloc((size_t)4608 * 512 * 4);       // 9.44 MB
    float* xbuf    = (float*)alloc((size_t)C_ * HW_ * 4);         // 81.9 MB
    float* scores  = (float*)alloc((size_t)NANCH * 4);            // 1.44 MB
    unsigned* hist1 = (unsigned*)alloc(65536 * 4);
    unsigned* hist2 = (unsigned*)alloc(65536 * 4);
    unsigned* meta  = (unsigned*)alloc(64 * 4);
    unsigned* sel_bits = (unsigned*)alloc(1024 * 4);
    unsigned* sel_idx  = (unsigned*)alloc(1024 * 4);
    unsigned* eq_idx   = (unsigned*)alloc((size_t)NANCH * 4);     // 1.44 MB
    unsigned* top_idx  = (unsigned*)alloc(KPRE * 4);
    float* top_sc      = (float*)alloc(KPRE * 4);
    float* props       = (float*)alloc(KPRE * 4 * 4);
    float* areas       = (float*)alloc(KPRE * 4);
    unsigned long long* mask = (unsigned long long*)alloc((size_t)KPRE * 16 * 8);
    (void)ws_size; (void)in_sizes; (void)n_in; (void)out_size;

    // 0) transpose weights
    k_transpose_w<<<dim3(144, 16), dim3(32, 8), 0, stream>>>(conv_w, wt);
    // 1) conv 3x3 + bias + relu (4 co-tiles x 325 spatial tiles, tile-major)
    k_conv3<<<4 * 325, 256, 0, stream>>>(feat, wt, conv_b, xbuf);
    // 2) cls head + sigmoid (64 px/block, 4 ci-chunks)
    k_cls<<<HW_ / 64, 256, 0, stream>>>(xbuf, cls_w, cls_b, scores);
    // 3) top-1000 radix select (hist1/hist2/meta are contiguous: zero in one go)
    k_zero_u32<<<(65536 * 2 + 64 + 255) / 256, 256, 0, stream>>>(hist1, 65536 * 2 + 64);
    k_hist1<<<(NANCH + 255) / 256, 256, 0, stream>>>(scores, hist1);
    k_find_thr<<<1, 1024, 0, stream>>>(hist1, meta, 0);
    k_hist2<<<(NANCH + 255) / 256, 256, 0, stream>>>(scores, meta, hist2);
    k_find_thr<<<1, 1024, 0, stream>>>(hist2, meta, 1);
    k_collect<<<(NANCH + 255) / 256, 256, 0, stream>>>(scores, meta, sel_bits, sel_idx, eq_idx);
    k_topk_final<<<1, 1024, 0, stream>>>(sel_bits, sel_idx, eq_idx, meta, top_idx, top_sc);
    // 4) reg head + decode + clamp for selected
    k_decode<<<KPRE, 64, 0, stream>>>(xbuf, reg_w, reg_b, top_idx, props, areas);
    // 5) NMS mask (+ zero d_out)
    k_nms_mask<<<KPRE, 256, 0, stream>>>(props, areas, mask, out);
    // 6) NMS scan + compact to outputs
    k_nms_scan_out<<<1, 64, 0, stream>>>(mask, props, top_sc, out);
}

// Round 4
// 2319.811 us; speedup vs baseline: 3.0161x; 1.7294x over previous
//
#include <hip/hip_runtime.h>
#include <stdint.h>

// Problem constants
static constexpr int H_ = 200, W_ = 200, HW_ = 40000;
static constexpr int C_ = 512;
static constexpr int NANCH = 360000;   // HW_ * 9
static constexpr int KPRE = 1000;
static constexpr int KPOST = 100;
static constexpr int KSEL = 1400;      // approx candidate margin (top-1000 + 400)
static constexpr int PXCAP = 8192;     // candidate pixel cap
// feat_t padded dims: [204 y][212 x][512 ci] bf16, real (y,x) at index (y+1,x+1)
static constexpr int FT_Y = 204, FT_X = 212;

typedef __attribute__((ext_vector_type(8))) short bf16x8;
typedef __attribute__((ext_vector_type(4))) float f32x4;

__device__ inline ushort f2bf(float f) {               // RNE float->bf16 bits
    unsigned u = __float_as_uint(f);
    u += 0x7FFFu + ((u >> 16) & 1u);
    return (ushort)(u >> 16);
}
__device__ inline float bf2f(ushort h) { return __uint_as_float(((unsigned)h) << 16); }

// ---------------------------------------------------------------------------
__global__ void k_zero_u32(unsigned* __restrict__ p, int n) {
    int i = blockIdx.x * 256 + threadIdx.x;
    if (i < n) p[i] = 0u;
}

// ---------------------------------------------------------------------------
// feat [512][200][200] f32 -> feat_t [204][212][512] bf16 (zero-padded border)
// block: 32ci x 8y x 32x tile via LDS transpose. grid (7,25,16).
// ---------------------------------------------------------------------------
__global__ void k_feat_t(const float* __restrict__ feat, ushort* __restrict__ feat_t) {
    __shared__ ushort lt[32 * 8 * 33];
    int x0 = blockIdx.x * 32, y0 = blockIdx.y * 8, ci0 = blockIdx.z * 32;
    int tid = threadIdx.x;
    for (int u = tid; u < 8192; u += 256) {
        int ciL = u >> 8, rem = u & 255;
        int yy = rem >> 5, xx = rem & 31;
        int x = x0 + xx;
        float v = (x < W_) ? feat[(size_t)(ci0 + ciL) * HW_ + (y0 + yy) * W_ + x] : 0.f;
        lt[(ciL * 8 + yy) * 33 + xx] = f2bf(v);
    }
    __syncthreads();
    for (int u = tid; u < 1024; u += 256) {
        int pxu = u >> 2, part = u & 3;
        int yy = pxu >> 5, xx = pxu & 31;
        if (x0 + xx >= W_) continue;
        ushort tmp[8];
#pragma unroll
        for (int k = 0; k < 8; ++k) tmp[k] = lt[((part * 8 + k) * 8 + yy) * 33 + xx];
        *(uint4*)&feat_t[((size_t)(y0 + yy + 1) * FT_X + (x0 + xx + 1)) * 512 + ci0 + part * 8] =
            *(const uint4*)&tmp[0];
    }
}

// conv_w [co][ci][th][tw] f32 -> wt_t [tap9][co512][ci512] bf16
__global__ void k_wt_t(const float* __restrict__ conv_w, ushort* __restrict__ wt_t) {
    int i = blockIdx.x * 256 + threadIdx.x;
    if (i >= 9 * 512 * 512) return;
    int tap = i >> 18;           // /262144
    int rem = i & 262143;
    int co = rem >> 9, ci = rem & 511;
    wt_t[i] = f2bf(conv_w[((size_t)co * 512 + ci) * 9 + tap]);
}

// ---------------------------------------------------------------------------
// Approx conv: bf16 MFMA 16x16x32. Block tile 128co x (8r x 16c px), 4 waves.
// Wave: 4 px-rows (A-frags) x 64 co (4 B-frags), acc 4x4 f32x4.
// K: 16 chunks of 32 ci; per chunk stage halo [10][18][40] once, per tap stage
// wtile [128][40]. A row = px-col (l&15), k=(l>>4)*8+j; B col = co (l&15).
// C/D: col(N=co)=l&15, row(M=px-col)=(l>>4)*4+reg [m89-verified].
// Output: xab [px40000][co512] bf16 (approx).
// ---------------------------------------------------------------------------
__global__ __attribute__((amdgpu_waves_per_eu(2, 4)))
void k_conv3_mfma(const ushort* __restrict__ feat_t, const ushort* __restrict__ wt_t,
                  const float* __restrict__ bias, ushort* __restrict__ xab) {
    __shared__ ushort halo[10 * 18 * 40];   // [r][c][32ci + pad8]
    __shared__ ushort wtile[128 * 40];      // [co][32ci + pad8]
    int b = blockIdx.x;
    int cot = b / 325;
    int tile = b - cot * 325;
    int xt = tile % 13, yt = tile / 13;
    int x0 = xt * 16, y0 = yt * 8;
    int co0 = cot * 128;
    int tid = threadIdx.x;
    int lane = tid & 63, wid = tid >> 6;
    int wr = wid >> 1, wc = wid & 1;
    int l15 = lane & 15, l4 = lane >> 4;

    f32x4 acc[4][4];
#pragma unroll
    for (int i = 0; i < 4; ++i)
#pragma unroll
        for (int j = 0; j < 4; ++j) acc[i][j] = (f32x4){0.f, 0.f, 0.f, 0.f};

    for (int ch = 0; ch < 16; ++ch) {
        int ci0 = ch * 32;
        __syncthreads();  // prior reads of halo done
        for (int u = tid; u < 720; u += 256) {          // 180 px * 4x16B
            int p = u >> 2, q = u & 3;
            int r = p / 18, c = p - r * 18;
            const ushort* src = feat_t + ((size_t)(y0 + r) * FT_X + (x0 + c)) * 512 + ci0 + q * 8;
            *(uint4*)&halo[(r * 18 + c) * 40 + q * 8] = *(const uint4*)src;
        }
        for (int tap = 0; tap < 9; ++tap) {
            if (tap) __syncthreads();                    // prior wtile reads done
            for (int u = tid; u < 512; u += 256) {       // 128 co * 4x16B
                int co = u >> 2, q = u & 3;
                const ushort* src = wt_t + ((size_t)(tap * 512 + co0 + co)) * 512 + ci0 + q * 8;
                *(uint4*)&wtile[co * 40 + q * 8] = *(const uint4*)src;
            }
            __syncthreads();
            int th = tap / 3, tw = tap - th * 3;
            bf16x8 af[4], bf[4];
#pragma unroll
            for (int pi = 0; pi < 4; ++pi)
                af[pi] = *(const bf16x8*)&halo[((wr * 4 + pi + th) * 18 + (l15 + tw)) * 40 + l4 * 8];
#pragma unroll
            for (int cj = 0; cj < 4; ++cj)
                bf[cj] = *(const bf16x8*)&wtile[(wc * 64 + cj * 16 + l15) * 40 + l4 * 8];
#pragma unroll
            for (int pi = 0; pi < 4; ++pi)
#pragma unroll
                for (int cj = 0; cj < 4; ++cj)
                    acc[pi][cj] = __builtin_amdgcn_mfma_f32_16x16x32_bf16(af[pi], bf[cj], acc[pi][cj], 0, 0, 0);
        }
    }

    // epilogue: bias + relu -> bf16 store (px-major)
    float bv[4];
#pragma unroll
    for (int cj = 0; cj < 4; ++cj) bv[cj] = bias[co0 + wc * 64 + cj * 16 + l15];
#pragma unroll
    for (int pi = 0; pi < 4; ++pi) {
        int yy = y0 + wr * 4 + pi;
#pragma unroll
        for (int cj = 0; cj < 4; ++cj) {
            int co = co0 + wc * 64 + cj * 16 + l15;
#pragma unroll
            for (int r = 0; r < 4; ++r) {
                int xx = x0 + l4 * 4 + r;
                if (xx < W_) {
                    float v = acc[pi][cj][r] + bv[cj];
                    xab[((size_t)(yy * W_ + xx)) * 512 + co] = f2bf(v > 0.f ? v : 0.f);
                }
            }
        }
    }
}

// ---------------------------------------------------------------------------
// Approx cls: scores[px*9+a] = sigmoid(dot(xab row, cls_w[a]) + b). Wave/px.
// ---------------------------------------------------------------------------
__global__ void k_cls(const ushort* __restrict__ xab, const float* __restrict__ cls_w,
                      const float* __restrict__ cls_b, float* __restrict__ scores) {
    __shared__ float wl[9 * 512];
    int tid = threadIdx.x;
    for (int t = tid; t < 4608; t += 256) wl[t] = cls_w[t];
    __syncthreads();
    int l = tid & 63, w = tid >> 6;
    int pbase = blockIdx.x * 64 + w * 16;
    for (int u = 0; u < 16; ++u) {
        int px = pbase + u;
        float xv[8];
#pragma unroll
        for (int k = 0; k < 8; ++k) xv[k] = bf2f(xab[(size_t)px * 512 + k * 64 + l]);
#pragma unroll
        for (int a = 0; a < 9; ++a) {
            float s = 0.f;
#pragma unroll
            for (int k = 0; k < 8; ++k) s = fmaf(xv[k], wl[a * 512 + k * 64 + l], s);
#pragma unroll
            for (int o = 32; o > 0; o >>= 1) s += __shfl_down(s, o);
            if (l == 0) scores[(size_t)px * 9 + a] = 1.f / (1.f + expf(-(s + cls_b[a])));
        }
    }
}

// ---------------------------------------------------------------------------
// Radix-select helpers
// meta: [0]=P [1]=cntAboveP [2]=T [3]=cntGtT [4]=need [8]=atomGt [9]=atomEq [10]=npx
// ---------------------------------------------------------------------------
__global__ void k_hist1(const float* __restrict__ scores, unsigned* __restrict__ hist) {
    int i = blockIdx.x * 256 + threadIdx.x;
    if (i < NANCH) atomicAdd(&hist[__float_as_uint(scores[i]) >> 16], 1u);
}

// mode 0: over hi16, base 0 -> meta[0]=P, meta[1]=cnt strictly above P's bucket
// mode 1: over lo16 among prefix==P, base meta[1] -> meta[2..4]
__global__ void k_find_thr(const unsigned* __restrict__ hist, unsigned* __restrict__ meta,
                           int mode, int Kwant) {
    __shared__ unsigned csum[1024];
    int t = threadIdx.x;
    unsigned base = (mode == 0) ? 0u : meta[1];
    unsigned s = 0;
    for (int b = 0; b < 64; ++b) s += hist[t * 64 + b];
    csum[t] = s;
    __syncthreads();
    for (int off = 1; off < 1024; off <<= 1) {
        unsigned add = (t + off < 1024) ? csum[t + off] : 0u;
        __syncthreads();
        csum[t] += add;
        __syncthreads();
    }
    unsigned run = base + ((t < 1023) ? csum[t + 1] : 0u);
    for (int b = 63; b >= 0; --b) {
        unsigned h = hist[t * 64 + b];
        if (run < (unsigned)Kwant && run + h >= (unsigned)Kwant) {
            if (mode == 0) {
                meta[0] = (unsigned)(t * 64 + b);
                meta[1] = run;
            } else {
                meta[2] = (meta[0] << 16) | (unsigned)(t * 64 + b);
                meta[3] = run;
                meta[4] = (unsigned)Kwant - run;
            }
            break;
        }
        run += h;
    }
}

// mark candidate pixels: anchors with hi16(score) >= P
__global__ void k_collect_cand(const float* __restrict__ scores, const unsigned* __restrict__ meta,
                               unsigned* __restrict__ flags) {
    int i = blockIdx.x * 256 + threadIdx.x;
    if (i >= NANCH) return;
    if ((__float_as_uint(scores[i]) >> 16) >= meta[0]) flags[i / 9] = 1u;
}

__global__ void k_px_compact(unsigned* __restrict__ flags, unsigned* __restrict__ meta,
                             unsigned* __restrict__ px_list) {
    int px = blockIdx.x * 256 + threadIdx.x;
    if (px >= HW_) return;
    if (flags[px]) {
        unsigned s = atomicAdd(&meta[10], 1u);
        if (s < (unsigned)PXCAP) { px_list[s] = (unsigned)px; flags[px] = s + 1u; }
        else flags[px] = 0u;
    }
}

// ---------------------------------------------------------------------------
// Exact fp32 conv at candidate pixels: C[128co x 64px] per block, K=4608
// (k = ci*9 + th*3 + tw, matching conv_w layout). Output xex[slot][co] fp32.
// ---------------------------------------------------------------------------
__global__ __attribute__((amdgpu_waves_per_eu(2, 4)))
void k_exact_gemm(const float* __restrict__ feat, const float* __restrict__ conv_w,
                  const float* __restrict__ bias, const unsigned* __restrict__ meta,
                  const unsigned* __restrict__ px_list, float* __restrict__ xex) {
    int npx = (int)meta[10]; if (npx > PXCAP) npx = PXCAP;
    int pb = blockIdx.x;
    if (pb * 64 >= npx) return;
    int cot = blockIdx.y;
    __shared__ float A[32][132];
    __shared__ float B[32][68];
    __shared__ int plist[64];
    int tid = threadIdx.x;
    int co0 = cot * 128;
    if (tid < 64) {
        int slot = pb * 64 + tid;
        plist[tid] = (slot < npx) ? (int)px_list[slot] : (int)px_list[0];
    }
    int tcog = tid >> 4;   // 8 co each
    int tpxg = tid & 15;   // 4 px each
    float acc[8][4];
#pragma unroll
    for (int i = 0; i < 8; ++i)
#pragma unroll
        for (int j = 0; j < 4; ++j) acc[i][j] = 0.f;
    for (int k0 = 0; k0 < 4608; k0 += 32) {
        __syncthreads();
        for (int u = tid; u < 1024; u += 256) {          // A: 128co x 32k
            int co = u >> 3, part = u & 7;
            float4 v = *(const float4*)&conv_w[(size_t)(co0 + co) * 4608 + k0 + part * 4];
            A[part * 4 + 0][co] = v.x; A[part * 4 + 1][co] = v.y;
            A[part * 4 + 2][co] = v.z; A[part * 4 + 3][co] = v.w;
        }
        for (int u = tid; u < 2048; u += 256) {          // B: 32k x 64px gather
            int k = u >> 6, s2 = u & 63;
            int kk = k0 + k;
            int ci = kk / 9, tap = kk - ci * 9;
            int th = tap / 3, tw = tap - th * 3;
            int px = plist[s2];
            int y = px / W_, x = px - y * W_;
            int iy = y + th - 1, ix = x + tw - 1;
            float v = 0.f;
            if ((unsigned)iy < (unsigned)H_ && (unsigned)ix < (unsigned)W_)
                v = feat[(size_t)ci * HW_ + iy * W_ + ix];
            B[k][s2] = v;
        }
        __syncthreads();
#pragma unroll 4
        for (int k = 0; k < 32; ++k) {
            float wv[8], pv[4];
            *(float4*)&wv[0] = *(const float4*)&A[k][tcog * 8];
            *(float4*)&wv[4] = *(const float4*)&A[k][tcog * 8 + 4];
            *(float4*)&pv[0] = *(const float4*)&B[k][tpxg * 4];
#pragma unroll
            for (int i = 0; i < 8; ++i)
#pragma unroll
                for (int j = 0; j < 4; ++j) acc[i][j] = fmaf(wv[i], pv[j], acc[i][j]);
        }
    }
#pragma unroll
    for (int j = 0; j < 4; ++j) {
        int slot = pb * 64 + tpxg * 4 + j;
        if (slot >= npx) continue;
#pragma unroll
        for (int i = 0; i < 8; ++i) {
            int co = co0 + tcog * 8 + i;
            float v = acc[i][j] + bias[co];
            xex[(size_t)slot * 512 + co] = v > 0.f ? v : 0.f;
        }
    }
}

// exact scores for all 9 anchors of each candidate pixel
__global__ void k_exact_scores(const float* __restrict__ xex, const float* __restrict__ cls_w,
                               const float* __restrict__ cls_b, const unsigned* __restrict__ meta,
                               float* __restrict__ scores_ex) {
    int slot = blockIdx.x;
    int npx = (int)meta[10]; if (npx > PXCAP) npx = PXCAP;
    if (slot >= npx) return;
    int l = threadIdx.x;
    float xv[8];
#pragma unroll
    for (int k = 0; k < 8; ++k) xv[k] = xex[(size_t)slot * 512 + k * 64 + l];
#pragma unroll
    for (int a = 0; a < 9; ++a) {
        float s = 0.f;
#pragma unroll
        for (int k = 0; k < 8; ++k) s = fmaf(xv[k], cls_w[a * 512 + k * 64 + l], s);
#pragma unroll
        for (int o = 32; o > 0; o >>= 1) s += __shfl_down(s, o);
        if (l == 0) scores_ex[slot * 9 + a] = 1.f / (1.f + expf(-(s + cls_b[a])));
    }
}

__global__ void k_hist1_ex(const float* __restrict__ scores_ex, const unsigned* __restrict__ meta,
                           unsigned* __restrict__ hist) {
    int npx = (int)meta[10]; if (npx > PXCAP) npx = PXCAP;
    int i = blockIdx.x * 256 + threadIdx.x;
    if (i < npx * 9) atomicAdd(&hist[__float_as_uint(scores_ex[i]) >> 16], 1u);
}

__global__ void k_hist2_ex(const float* __restrict__ scores_ex, const unsigned* __restrict__ meta,
                           const unsigned* __restrict__ meta_ex, unsigned* __restrict__ hist2) {
    int npx = (int)meta[10]; if (npx > PXCAP) npx = PXCAP;
    int i = blockIdx.x * 256 + threadIdx.x;
    if (i >= npx * 9) return;
    unsigned b = __float_as_uint(scores_ex[i]);
    if ((b >> 16) == meta_ex[0]) atomicAdd(&hist2[b & 0xFFFFu], 1u);
}

__global__ void k_collect_ex(const float* __restrict__ scores_ex, const unsigned* __restrict__ meta,
                             unsigned* __restrict__ meta_ex, const unsigned* __restrict__ px_list,
                             unsigned* __restrict__ sel_bits, unsigned* __restrict__ sel_idx,
                             unsigned* __restrict__ eq_idx) {
    int npx = (int)meta[10]; if (npx > PXCAP) npx = PXCAP;
    int i = blockIdx.x * 256 + threadIdx.x;
    if (i >= npx * 9) return;
    unsigned b = __float_as_uint(scores_ex[i]);
    unsigned T = meta_ex[2];
    unsigned g = px_list[i / 9] * 9u + (unsigned)(i % 9);
    if (b > T) {
        unsigned s = atomicAdd(&meta_ex[8], 1u);
        if (s < 1024u) { sel_bits[s] = b; sel_idx[s] = g; }
    } else if (b == T) {
        unsigned s = atomicAdd(&meta_ex[9], 1u);
        if (s < 65536u) eq_idx[s] = g;
    }
}

// exact stable top-1000 (ties -> smallest global idx), bitonic final order
__global__ void k_topk_final(const unsigned* __restrict__ sel_bits, const unsigned* __restrict__ sel_idx,
                             const unsigned* __restrict__ eq_idx, const unsigned* __restrict__ meta,
                             unsigned* __restrict__ top_idx, float* __restrict__ top_sc) {
    __shared__ uint64_t keys[1024];
    __shared__ int lcnt;
    __shared__ int lred;
    int t = threadIdx.x;
    unsigned cntGt = meta[3];
    unsigned need = meta[4];
    unsigned cntEq = meta[9];
    unsigned T = meta[2];

    unsigned idx_cut = 0xFFFFFFFFu;
    if (cntEq > need) {
        unsigned lo = 0, hi = NANCH - 1;
        while (lo < hi) {
            unsigned mid = (lo + hi) >> 1;
            int c = 0;
            for (unsigned e = t; e < cntEq; e += 1024)
                if (eq_idx[e] <= mid) c++;
            if (t == 0) lred = 0;
            __syncthreads();
            atomicAdd(&lred, c);
            __syncthreads();
            int tot = lred;
            __syncthreads();
            if ((unsigned)tot >= need) hi = mid; else lo = mid + 1;
        }
        idx_cut = lo;
    }

    keys[t] = 0ull;
    if (t == 0) lcnt = 0;
    __syncthreads();
    for (unsigned s = t; s < cntGt; s += 1024)
        keys[s] = ((uint64_t)sel_bits[s] << 32) | (uint64_t)(0xFFFFFFFFu - sel_idx[s]);
    for (unsigned e = t; e < cntEq; e += 1024) {
        unsigned ix = eq_idx[e];
        if (ix <= idx_cut) {
            int s2 = (int)cntGt + atomicAdd(&lcnt, 1);
            keys[s2] = ((uint64_t)T << 32) | (uint64_t)(0xFFFFFFFFu - ix);
        }
    }
    __syncthreads();
    for (int k = 2; k <= 1024; k <<= 1) {
        for (int j = k >> 1; j > 0; j >>= 1) {
            int ixj = t ^ j;
            if (ixj > t) {
                uint64_t a = keys[t], b = keys[ixj];
                bool desc = (t & k) == 0;
                if (desc ? (a < b) : (a > b)) { keys[t] = b; keys[ixj] = a; }
            }
            __syncthreads();
        }
    }
    if (t < KPRE) {
        top_sc[t] = __uint_as_float((unsigned)(keys[t] >> 32));
        top_idx[t] = 0xFFFFFFFFu - (unsigned)keys[t];
    }
}

// ---------------------------------------------------------------------------
// decode from exact x (via flags px->slot map)
// ---------------------------------------------------------------------------
__global__ void k_decode(const float* __restrict__ xex, const unsigned* __restrict__ flags,
                         const float* __restrict__ reg_w, const float* __restrict__ reg_b,
                         const unsigned* __restrict__ top_idx,
                         float* __restrict__ props, float* __restrict__ areas) {
    int j = blockIdx.x;
    int lane = threadIdx.x;  // 64
    unsigned idx = top_idx[j];
    int pix = (int)(idx / 9u);
    int a = (int)(idx - (unsigned)pix * 9u);
    int slot = (int)flags[pix] - 1;
    if (slot < 0) slot = 0;
    const float* xr = xex + (size_t)slot * 512;
    float s0 = 0, s1 = 0, s2 = 0, s3 = 0;
    for (int c = lane; c < C_; c += 64) {
        float xv = xr[c];
        s0 = fmaf(xv, reg_w[(a * 4 + 0) * C_ + c], s0);
        s1 = fmaf(xv, reg_w[(a * 4 + 1) * C_ + c], s1);
        s2 = fmaf(xv, reg_w[(a * 4 + 2) * C_ + c], s2);
        s3 = fmaf(xv, reg_w[(a * 4 + 3) * C_ + c], s3);
    }
#pragma unroll
    for (int o = 32; o > 0; o >>= 1) {
        s0 += __shfl_down(s0, o);
        s1 += __shfl_down(s1, o);
        s2 += __shfl_down(s2, o);
        s3 += __shfl_down(s3, o);
    }
    if (lane == 0) {
        float d0 = s0 + reg_b[a * 4 + 0];
        float d1 = s1 + reg_b[a * 4 + 1];
        float d2 = s2 + reg_b[a * 4 + 2];
        float d3 = s3 + reg_b[a * 4 + 3];
        int h = pix / W_, w2 = pix - h * W_;
        int rr = a / 3, ss = a - rr * 3;
        float ratio = (rr == 0) ? 0.5f : (rr == 1) ? 1.0f : 2.0f;
        float scale = (ss == 0) ? 128.f : (ss == 1) ? 256.f : 512.f;
        float hr = sqrtf(ratio);
        float wr = 1.0f / hr;
        float wsc = wr * scale, hsc = hr * scale;
        float sx = (float)w2 * 16.f, sy = (float)h * 16.f;
        float a0 = sx - wsc * 0.5f, a1 = sy - hsc * 0.5f;
        float a2 = sx + wsc * 0.5f, a3 = sy + hsc * 0.5f;
        float bw = a2 - a0, bh = a3 - a1;
        float cx = a0 + 0.5f * bw, cy = a1 + 0.5f * bh;
        float px = d0 * bw + cx, py = d1 * bh + cy;
        float pw = expf(d2) * bw, ph = expf(d3) * bh;
        float b0 = px - 0.5f * pw, b1 = py - 0.5f * ph;
        float b2 = px + 0.5f * pw, b3 = py + 0.5f * ph;
        b0 = fminf(fmaxf(b0, 0.f), 3200.f);
        b1 = fminf(fmaxf(b1, 0.f), 3200.f);
        b2 = fminf(fmaxf(b2, 0.f), 3200.f);
        b3 = fminf(fmaxf(b3, 0.f), 3200.f);
        props[j * 4 + 0] = b0;
        props[j * 4 + 1] = b1;
        props[j * 4 + 2] = b2;
        props[j * 4 + 3] = b3;
        areas[j] = (b2 - b0) * (b3 - b1);
    }
}

// ---------------------------------------------------------------------------
__global__ void k_nms_mask(const float* __restrict__ props, const float* __restrict__ areas,
                           unsigned long long* __restrict__ mask, float* __restrict__ out) {
    int i = blockIdx.x;
    int tid = threadIdx.x;  // 256
    if (i == 0) {
        for (int t = tid; t < KPOST * 5; t += 256) out[t] = 0.f;
    }
    float x1i = props[i * 4 + 0], y1i = props[i * 4 + 1];
    float x2i = props[i * 4 + 2], y2i = props[i * 4 + 3];
    float ai = areas[i];
#pragma unroll
    for (int k = 0; k < 4; ++k) {
        int j = k * 256 + tid;
        bool sup = false;
        if (j < KPRE && j > i) {
            float iw = fminf(x2i, props[j * 4 + 2]) - fmaxf(x1i, props[j * 4 + 0]);
            float ih = fminf(y2i, props[j * 4 + 3]) - fmaxf(y1i, props[j * 4 + 1]);
            iw = fmaxf(iw, 0.f);
            ih = fmaxf(ih, 0.f);
            float inter = iw * ih;
            float iou = inter / (ai + areas[j] - inter);
            sup = iou > 0.7f;
        }
        unsigned long long b = __ballot(sup);
        int word = k * 4 + (tid >> 6);
        if ((tid & 63) == 0) mask[(size_t)i * 16 + word] = b;
    }
}

__global__ void k_nms_scan_out(const unsigned long long* __restrict__ mask,
                               const float* __restrict__ props, const float* __restrict__ top_sc,
                               float* __restrict__ out) {
    int lane = threadIdx.x;  // 64
    unsigned long long keep = 0ull;
    if (lane < 16) keep = (lane < 15) ? ~0ull : ((1ull << 40) - 1);  // 1000 bits
    for (int i = 0; i < KPRE; ++i) {
        unsigned long long kw = __shfl(keep, i >> 6);
        if ((kw >> (i & 63)) & 1ull) {
            if (lane < 16) keep &= ~mask[(size_t)i * 16 + lane];
        }
    }
    int pcv = (lane < 16) ? (int)__popcll(keep) : 0;
    int pre = 0;
    for (int j = 0; j < 16; ++j) {
        int v = __shfl(pcv, j);
        if (j < lane) pre += v;
    }
    for (int w = 0; w < 16; ++w) {
        unsigned long long kw = __shfl(keep, w);
        int base = __shfl(pre, w);
        int idx = w * 64 + lane;
        if (idx < KPRE && ((kw >> lane) & 1ull)) {
            int rank = base + (int)__popcll(kw & ((1ull << lane) - 1ull));
            if (rank < KPOST) {
                out[rank * 4 + 0] = props[idx * 4 + 0];
                out[rank * 4 + 1] = props[idx * 4 + 1];
                out[rank * 4 + 2] = props[idx * 4 + 2];
                out[rank * 4 + 3] = props[idx * 4 + 3];
                out[KPOST * 4 + rank] = top_sc[idx];
            }
        }
    }
}

// ---------------------------------------------------------------------------
extern "C" void kernel_launch(void* const* d_in, const int* in_sizes, int n_in,
                              void* d_out, int out_size, void* d_ws, size_t ws_size,
                              hipStream_t stream) {
    const float* feat   = (const float*)d_in[0];
    const float* conv_w = (const float*)d_in[1];
    const float* conv_b = (const float*)d_in[2];
    const float* cls_w  = (const float*)d_in[3];
    const float* cls_b  = (const float*)d_in[4];
    const float* reg_w  = (const float*)d_in[5];
    const float* reg_b  = (const float*)d_in[6];
    float* out = (float*)d_out;

    size_t off = 0;
    auto alloc = [&](size_t bytes) -> void* {
        off = (off + 255) & ~(size_t)255;
        void* p = (char*)d_ws + off;
        off += bytes;
        return p;
    };
    ushort* feat_t  = (ushort*)alloc((size_t)FT_Y * FT_X * 512 * 2);   // 44.3 MB
    ushort* wt_t    = (ushort*)alloc((size_t)9 * 512 * 512 * 2);       // 4.7 MB
    ushort* xab     = (ushort*)alloc((size_t)HW_ * 512 * 2);           // 41 MB
    float*  xex     = (float*)alloc((size_t)PXCAP * 512 * 4);          // 16.8 MB
    float*  scores  = (float*)alloc((size_t)NANCH * 4);                // 1.44 MB
    float*  scores_ex = (float*)alloc((size_t)PXCAP * 9 * 4);
    // contiguous zero region: hist1, hist2, meta, meta_ex, flags
    unsigned* hist1   = (unsigned*)alloc(65536 * 4);
    unsigned* hist2   = (unsigned*)alloc(65536 * 4);
    unsigned* meta    = (unsigned*)alloc(64 * 4);
    unsigned* meta_ex = (unsigned*)alloc(64 * 4);
    unsigned* flags   = (unsigned*)alloc((size_t)HW_ * 4);
    unsigned* px_list = (unsigned*)alloc(PXCAP * 4);
    unsigned* sel_bits = (unsigned*)alloc(1024 * 4);
    unsigned* sel_idx  = (unsigned*)alloc(1024 * 4);
    unsigned* eq_idx   = (unsigned*)alloc(65536 * 4);
    unsigned* top_idx  = (unsigned*)alloc(KPRE * 4);
    float* top_sc      = (float*)alloc(KPRE * 4);
    float* props       = (float*)alloc(KPRE * 4 * 4);
    float* areas       = (float*)alloc(KPRE * 4);
    unsigned long long* mask = (unsigned long long*)alloc((size_t)KPRE * 16 * 8);
    (void)ws_size; (void)in_sizes; (void)n_in; (void)out_size;

    // 0) prep: zero feat_t pad + zero radix region; build bf16 layouts
    int ftDw = FT_Y * FT_X * 512 / 2;
    k_zero_u32<<<(ftDw + 255) / 256, 256, 0, stream>>>((unsigned*)feat_t, ftDw);
    int zrDw = 65536 * 2 + 64 + 64 + HW_;
    k_zero_u32<<<(zrDw + 255) / 256, 256, 0, stream>>>(hist1, zrDw);
    k_feat_t<<<dim3(7, 25, 16), 256, 0, stream>>>(feat, feat_t);
    k_wt_t<<<(9 * 512 * 512 + 255) / 256, 256, 0, stream>>>(conv_w, wt_t);
    // 1) approx conv (bf16 MFMA) + approx cls
    k_conv3_mfma<<<4 * 325, 256, 0, stream>>>(feat_t, wt_t, conv_b, xab);
    k_cls<<<HW_ / 64, 256, 0, stream>>>(xab, cls_w, cls_b, scores);
    // 2) candidate pixels: approx top-KSEL bucket threshold
    k_hist1<<<(NANCH + 255) / 256, 256, 0, stream>>>(scores, hist1);
    k_find_thr<<<1, 1024, 0, stream>>>(hist1, meta, 0, KSEL);
    k_collect_cand<<<(NANCH + 255) / 256, 256, 0, stream>>>(scores, meta, flags);
    k_px_compact<<<(HW_ + 255) / 256, 256, 0, stream>>>(flags, meta, px_list);
    // 3) exact fp32 conv + cls at candidates
    k_zero_u32<<<(65536 * 2 + 255) / 256, 256, 0, stream>>>(hist1, 65536 * 2);
    k_exact_gemm<<<dim3(PXCAP / 64, 4), 256, 0, stream>>>(feat, conv_w, conv_b, meta, px_list, xex);
    k_exact_scores<<<PXCAP, 64, 0, stream>>>(xex, cls_w, cls_b, meta, scores_ex);
    // 4) exact stable top-1000 among candidate anchors (global indices)
    k_hist1_ex<<<(PXCAP * 9 + 255) / 256, 256, 0, stream>>>(scores_ex, meta, hist1);
    k_find_thr<<<1, 1024, 0, stream>>>(hist1, meta_ex, 0, KPRE);
    k_hist2_ex<<<(PXCAP * 9 + 255) / 256, 256, 0, stream>>>(scores_ex, meta, meta_ex, hist2);
    k_find_thr<<<1, 1024, 0, stream>>>(hist2, meta_ex, 1, KPRE);
    k_collect_ex<<<(PXCAP * 9 + 255) / 256, 256, 0, stream>>>(scores_ex, meta, meta_ex, px_list,
                                                              sel_bits, sel_idx, eq_idx);
    k_topk_final<<<1, 1024, 0, stream>>>(sel_bits, sel_idx, eq_idx, meta_ex, top_idx, top_sc);
    // 5) exact decode + NMS
    k_decode<<<KPRE, 64, 0, stream>>>(xex, flags, reg_w, reg_b, top_idx, props, areas);
    k_nms_mask<<<KPRE, 256, 0, stream>>>(props, areas, mask, out);
    k_nms_scan_out<<<1, 64, 0, stream>>>(mask, props, top_sc, out);
}

// Round 5
// 1639.698 us; speedup vs baseline: 4.2671x; 1.4148x over previous
//
#include <hip/hip_runtime.h>
#include <stdint.h>

// Problem constants
static constexpr int H_ = 200, W_ = 200, HW_ = 40000;
static constexpr int C_ = 512;
static constexpr int NANCH = 360000;   // HW_ * 9
static constexpr int KPRE = 1000;
static constexpr int KPOST = 100;
static constexpr int KSEL = 1400;      // approx candidate margin (top-1000 + 400)
static constexpr int PXCAP = 4096;     // candidate pixel cap (est npx ~1600)
static constexpr int KSPLIT = 4;       // exact-gemm K split (4608 = 4 x 1152)
// feat_t padded dims: [204 y][212 x][512 ci] bf16, real (y,x) at index (y+1,x+1)
static constexpr int FT_Y = 204, FT_X = 212;

typedef __attribute__((ext_vector_type(8))) short bf16x8;
typedef __attribute__((ext_vector_type(4))) float f32x4;

__device__ inline ushort f2bf(float f) {               // RNE float->bf16 bits
    unsigned u = __float_as_uint(f);
    u += 0x7FFFu + ((u >> 16) & 1u);
    return (ushort)(u >> 16);
}
__device__ inline float bf2f(ushort h) { return __uint_as_float(((unsigned)h) << 16); }

// ---------------------------------------------------------------------------
__global__ void k_zero_u32(unsigned* __restrict__ p, int n) {
    int i = blockIdx.x * 256 + threadIdx.x;
    if (i < n) p[i] = 0u;
}

// ---------------------------------------------------------------------------
// feat [512][200][200] f32 -> feat_t [204][212][512] bf16 (zero-padded border)
// ---------------------------------------------------------------------------
__global__ void k_feat_t(const float* __restrict__ feat, ushort* __restrict__ feat_t) {
    __shared__ ushort lt[32 * 8 * 33];
    int x0 = blockIdx.x * 32, y0 = blockIdx.y * 8, ci0 = blockIdx.z * 32;
    int tid = threadIdx.x;
    for (int u = tid; u < 8192; u += 256) {
        int ciL = u >> 8, rem = u & 255;
        int yy = rem >> 5, xx = rem & 31;
        int x = x0 + xx;
        float v = (x < W_) ? feat[(size_t)(ci0 + ciL) * HW_ + (y0 + yy) * W_ + x] : 0.f;
        lt[(ciL * 8 + yy) * 33 + xx] = f2bf(v);
    }
    __syncthreads();
    for (int u = tid; u < 1024; u += 256) {
        int pxu = u >> 2, part = u & 3;
        int yy = pxu >> 5, xx = pxu & 31;
        if (x0 + xx >= W_) continue;
        ushort tmp[8];
#pragma unroll
        for (int k = 0; k < 8; ++k) tmp[k] = lt[((part * 8 + k) * 8 + yy) * 33 + xx];
        *(uint4*)&feat_t[((size_t)(y0 + yy + 1) * FT_X + (x0 + xx + 1)) * 512 + ci0 + part * 8] =
            *(const uint4*)&tmp[0];
    }
}

// conv_w [co][ci][th][tw] f32 -> wt_t [tap9][co512][ci512] bf16
__global__ void k_wt_t(const float* __restrict__ conv_w, ushort* __restrict__ wt_t) {
    int i = blockIdx.x * 256 + threadIdx.x;
    if (i >= 9 * 512 * 512) return;
    int tap = i >> 18;
    int rem = i & 262143;
    int co = rem >> 9, ci = rem & 511;
    wt_t[i] = f2bf(conv_w[((size_t)co * 512 + ci) * 9 + tap]);
}

// ---------------------------------------------------------------------------
// Approx conv: bf16 MFMA 16x16x32. Block tile 128co x (8r x 16c px), 4 waves.
// ---------------------------------------------------------------------------
__global__ __attribute__((amdgpu_waves_per_eu(2, 4)))
void k_conv3_mfma(const ushort* __restrict__ feat_t, const ushort* __restrict__ wt_t,
                  const float* __restrict__ bias, ushort* __restrict__ xab) {
    __shared__ ushort halo[10 * 18 * 40];   // [r][c][32ci + pad8]
    __shared__ ushort wtile[128 * 40];      // [co][32ci + pad8]
    int b = blockIdx.x;
    int cot = b / 325;
    int tile = b - cot * 325;
    int xt = tile % 13, yt = tile / 13;
    int x0 = xt * 16, y0 = yt * 8;
    int co0 = cot * 128;
    int tid = threadIdx.x;
    int lane = tid & 63, wid = tid >> 6;
    int wr = wid >> 1, wc = wid & 1;
    int l15 = lane & 15, l4 = lane >> 4;

    f32x4 acc[4][4];
#pragma unroll
    for (int i = 0; i < 4; ++i)
#pragma unroll
        for (int j = 0; j < 4; ++j) acc[i][j] = (f32x4){0.f, 0.f, 0.f, 0.f};

    for (int ch = 0; ch < 16; ++ch) {
        int ci0 = ch * 32;
        __syncthreads();
        for (int u = tid; u < 720; u += 256) {
            int p = u >> 2, q = u & 3;
            int r = p / 18, c = p - r * 18;
            const ushort* src = feat_t + ((size_t)(y0 + r) * FT_X + (x0 + c)) * 512 + ci0 + q * 8;
            *(uint4*)&halo[(r * 18 + c) * 40 + q * 8] = *(const uint4*)src;
        }
        for (int tap = 0; tap < 9; ++tap) {
            if (tap) __syncthreads();
            for (int u = tid; u < 512; u += 256) {
                int co = u >> 2, q = u & 3;
                const ushort* src = wt_t + ((size_t)(tap * 512 + co0 + co)) * 512 + ci0 + q * 8;
                *(uint4*)&wtile[co * 40 + q * 8] = *(const uint4*)src;
            }
            __syncthreads();
            int th = tap / 3, tw = tap - th * 3;
            bf16x8 af[4], bf[4];
#pragma unroll
            for (int pi = 0; pi < 4; ++pi)
                af[pi] = *(const bf16x8*)&halo[((wr * 4 + pi + th) * 18 + (l15 + tw)) * 40 + l4 * 8];
#pragma unroll
            for (int cj = 0; cj < 4; ++cj)
                bf[cj] = *(const bf16x8*)&wtile[(wc * 64 + cj * 16 + l15) * 40 + l4 * 8];
#pragma unroll
            for (int pi = 0; pi < 4; ++pi)
#pragma unroll
                for (int cj = 0; cj < 4; ++cj)
                    acc[pi][cj] = __builtin_amdgcn_mfma_f32_16x16x32_bf16(af[pi], bf[cj], acc[pi][cj], 0, 0, 0);
        }
    }

    float bv[4];
#pragma unroll
    for (int cj = 0; cj < 4; ++cj) bv[cj] = bias[co0 + wc * 64 + cj * 16 + l15];
#pragma unroll
    for (int pi = 0; pi < 4; ++pi) {
        int yy = y0 + wr * 4 + pi;
#pragma unroll
        for (int cj = 0; cj < 4; ++cj) {
            int co = co0 + wc * 64 + cj * 16 + l15;
#pragma unroll
            for (int r = 0; r < 4; ++r) {
                int xx = x0 + l4 * 4 + r;
                if (xx < W_) {
                    float v = acc[pi][cj][r] + bv[cj];
                    xab[((size_t)(yy * W_ + xx)) * 512 + co] = f2bf(v > 0.f ? v : 0.f);
                }
            }
        }
    }
}

// ---------------------------------------------------------------------------
// Approx cls: scores[px*9+a] = sigmoid(dot(xab row, cls_w[a]) + b). Wave/px.
// ---------------------------------------------------------------------------
__global__ void k_cls(const ushort* __restrict__ xab, const float* __restrict__ cls_w,
                      const float* __restrict__ cls_b, float* __restrict__ scores) {
    __shared__ float wl[9 * 512];
    int tid = threadIdx.x;
    for (int t = tid; t < 4608; t += 256) wl[t] = cls_w[t];
    __syncthreads();
    int l = tid & 63, w = tid >> 6;
    int pbase = blockIdx.x * 64 + w * 16;
    for (int u = 0; u < 16; ++u) {
        int px = pbase + u;
        float xv[8];
#pragma unroll
        for (int k = 0; k < 8; ++k) xv[k] = bf2f(xab[(size_t)px * 512 + k * 64 + l]);
#pragma unroll
        for (int a = 0; a < 9; ++a) {
            float s = 0.f;
#pragma unroll
            for (int k = 0; k < 8; ++k) s = fmaf(xv[k], wl[a * 512 + k * 64 + l], s);
#pragma unroll
            for (int o = 32; o > 0; o >>= 1) s += __shfl_down(s, o);
            if (l == 0) scores[(size_t)px * 9 + a] = 1.f / (1.f + expf(-(s + cls_b[a])));
        }
    }
}

// ---------------------------------------------------------------------------
// Radix-select helpers
// meta: [0]=P [1]=cntAboveP [2]=T [3]=cntGtT [4]=need [8]=atomGt [9]=atomEq [10]=npx
// ---------------------------------------------------------------------------
__global__ void k_hist1(const float* __restrict__ scores, unsigned* __restrict__ hist) {
    int i = blockIdx.x * 256 + threadIdx.x;
    if (i < NANCH) atomicAdd(&hist[__float_as_uint(scores[i]) >> 16], 1u);
}

__global__ void k_find_thr(const unsigned* __restrict__ hist, unsigned* __restrict__ meta,
                           int mode, int Kwant) {
    __shared__ unsigned csum[1024];
    int t = threadIdx.x;
    unsigned base = (mode == 0) ? 0u : meta[1];
    unsigned s = 0;
    for (int b = 0; b < 64; ++b) s += hist[t * 64 + b];
    csum[t] = s;
    __syncthreads();
    for (int off = 1; off < 1024; off <<= 1) {
        unsigned add = (t + off < 1024) ? csum[t + off] : 0u;
        __syncthreads();
        csum[t] += add;
        __syncthreads();
    }
    unsigned run = base + ((t < 1023) ? csum[t + 1] : 0u);
    for (int b = 63; b >= 0; --b) {
        unsigned h = hist[t * 64 + b];
        if (run < (unsigned)Kwant && run + h >= (unsigned)Kwant) {
            if (mode == 0) {
                meta[0] = (unsigned)(t * 64 + b);
                meta[1] = run;
            } else {
                meta[2] = (meta[0] << 16) | (unsigned)(t * 64 + b);
                meta[3] = run;
                meta[4] = (unsigned)Kwant - run;
            }
            break;
        }
        run += h;
    }
}

// mark candidate pixels: anchors with hi16(score) >= P
__global__ void k_collect_cand(const float* __restrict__ scores, const unsigned* __restrict__ meta,
                               unsigned* __restrict__ flags) {
    int i = blockIdx.x * 256 + threadIdx.x;
    if (i >= NANCH) return;
    if ((__float_as_uint(scores[i]) >> 16) >= meta[0]) flags[i / 9] = 1u;
}

__global__ void k_px_compact(unsigned* __restrict__ flags, unsigned* __restrict__ meta,
                             unsigned* __restrict__ px_list) {
    int px = blockIdx.x * 256 + threadIdx.x;
    if (px >= HW_) return;
    if (flags[px]) {
        unsigned s = atomicAdd(&meta[10], 1u);
        if (s < (unsigned)PXCAP) { px_list[s] = (unsigned)px; flags[px] = s + 1u; }
        else flags[px] = 0u;
    }
}

// ---------------------------------------------------------------------------
// im2col at candidate pixels: B_packed[sb][k4608][s64] fp32, coalesced writes.
// grid (PXCAP/64, 72), 64 k-rows per block. Gather latency hidden by TLP.
// ---------------------------------------------------------------------------
__global__ void k_im2col(const float* __restrict__ feat, const unsigned* __restrict__ meta,
                         const unsigned* __restrict__ px_list, float* __restrict__ B_packed) {
    int npx = (int)meta[10]; if (npx > PXCAP) npx = PXCAP;
    int sb = blockIdx.x, kb = blockIdx.y;
    if (sb * 64 >= npx) return;
    __shared__ int plist[64];
    int tid = threadIdx.x;
    if (tid < 64) {
        int slot = sb * 64 + tid;
        plist[tid] = (slot < npx) ? (int)px_list[slot] : (int)px_list[0];
    }
    __syncthreads();
    for (int u = tid; u < 4096; u += 256) {
        int kl = u >> 6, s = u & 63;
        int k = kb * 64 + kl;
        int ci = k / 9, tap = k - ci * 9;
        int th = tap / 3, tw = tap - th * 3;
        int px = plist[s];
        int y = px / W_, x = px - y * W_;
        int iy = y + th - 1, ix = x + tw - 1;
        float v = 0.f;
        if ((unsigned)iy < (unsigned)H_ && (unsigned)ix < (unsigned)W_)
            v = feat[(size_t)ci * HW_ + iy * W_ + ix];
        B_packed[((size_t)sb * 4608 + k) * 64 + s] = v;
    }
}

// ---------------------------------------------------------------------------
// Exact fp32 conv GEMM v2: C[128co x 64px], K-split x4 -> xpart[kz].
// A (weights) and B (B_packed) staged with coalesced float4.
// ---------------------------------------------------------------------------
__global__ __attribute__((amdgpu_waves_per_eu(2, 4)))
void k_exact_gemm(const float* __restrict__ B_packed, const float* __restrict__ conv_w,
                  const unsigned* __restrict__ meta, float* __restrict__ xpart) {
    int npx = (int)meta[10]; if (npx > PXCAP) npx = PXCAP;
    int pb = blockIdx.x;
    if (pb * 64 >= npx) return;
    int cot = blockIdx.y;
    int kz = blockIdx.z;
    __shared__ float A[32][132];
    __shared__ float B[32][68];
    int tid = threadIdx.x;
    int co0 = cot * 128;
    int tcog = tid >> 4;   // 8 co each
    int tpxg = tid & 15;   // 4 px each
    float acc[8][4];
#pragma unroll
    for (int i = 0; i < 8; ++i)
#pragma unroll
        for (int j = 0; j < 4; ++j) acc[i][j] = 0.f;
    int kbase = kz * 1152;
    for (int kc = 0; kc < 36; ++kc) {
        int k0 = kbase + kc * 32;
        __syncthreads();
        for (int u = tid; u < 1024; u += 256) {          // A: 128co x 32k
            int co = u >> 3, part = u & 7;
            float4 v = *(const float4*)&conv_w[(size_t)(co0 + co) * 4608 + k0 + part * 4];
            A[part * 4 + 0][co] = v.x; A[part * 4 + 1][co] = v.y;
            A[part * 4 + 2][co] = v.z; A[part * 4 + 3][co] = v.w;
        }
        for (int u = tid; u < 512; u += 256) {           // B: 32k x 64px coalesced
            int k = u >> 4, s4 = (u & 15) * 4;
            *(float4*)&B[k][s4] = *(const float4*)&B_packed[((size_t)pb * 4608 + k0 + k) * 64 + s4];
        }
        __syncthreads();
#pragma unroll 4
        for (int k = 0; k < 32; ++k) {
            float wv[8], pv[4];
            *(float4*)&wv[0] = *(const float4*)&A[k][tcog * 8];
            *(float4*)&wv[4] = *(const float4*)&A[k][tcog * 8 + 4];
            *(float4*)&pv[0] = *(const float4*)&B[k][tpxg * 4];
#pragma unroll
            for (int i = 0; i < 8; ++i)
#pragma unroll
                for (int j = 0; j < 4; ++j) acc[i][j] = fmaf(wv[i], pv[j], acc[i][j]);
        }
    }
#pragma unroll
    for (int j = 0; j < 4; ++j) {
        int slot = pb * 64 + tpxg * 4 + j;
        if (slot >= npx) continue;
#pragma unroll
        for (int i = 0; i < 8; ++i) {
            int co = co0 + tcog * 8 + i;
            xpart[((size_t)kz * PXCAP + slot) * 512 + co] = acc[i][j];
        }
    }
}

// fixed-order reduce of K-split partials + bias + relu -> xex
__global__ void k_exact_reduce(const float* __restrict__ xpart, const float* __restrict__ bias,
                               const unsigned* __restrict__ meta, float* __restrict__ xex) {
    int npx = (int)meta[10]; if (npx > PXCAP) npx = PXCAP;
    int idx = blockIdx.x * 256 + threadIdx.x;
    int slot = idx >> 9, co = idx & 511;
    if (slot >= npx) return;
    float v = xpart[(size_t)slot * 512 + co];
    v += xpart[((size_t)PXCAP + slot) * 512 + co];
    v += xpart[((size_t)2 * PXCAP + slot) * 512 + co];
    v += xpart[((size_t)3 * PXCAP + slot) * 512 + co];
    v += bias[co];
    xex[(size_t)slot * 512 + co] = v > 0.f ? v : 0.f;
}

// exact scores for all 9 anchors of each candidate pixel
__global__ void k_exact_scores(const float* __restrict__ xex, const float* __restrict__ cls_w,
                               const float* __restrict__ cls_b, const unsigned* __restrict__ meta,
                               float* __restrict__ scores_ex) {
    int slot = blockIdx.x;
    int npx = (int)meta[10]; if (npx > PXCAP) npx = PXCAP;
    if (slot >= npx) return;
    int l = threadIdx.x;
    float xv[8];
#pragma unroll
    for (int k = 0; k < 8; ++k) xv[k] = xex[(size_t)slot * 512 + k * 64 + l];
#pragma unroll
    for (int a = 0; a < 9; ++a) {
        float s = 0.f;
#pragma unroll
        for (int k = 0; k < 8; ++k) s = fmaf(xv[k], cls_w[a * 512 + k * 64 + l], s);
#pragma unroll
        for (int o = 32; o > 0; o >>= 1) s += __shfl_down(s, o);
        if (l == 0) scores_ex[slot * 9 + a] = 1.f / (1.f + expf(-(s + cls_b[a])));
    }
}

__global__ void k_hist1_ex(const float* __restrict__ scores_ex, const unsigned* __restrict__ meta,
                           unsigned* __restrict__ hist) {
    int npx = (int)meta[10]; if (npx > PXCAP) npx = PXCAP;
    int i = blockIdx.x * 256 + threadIdx.x;
    if (i < npx * 9) atomicAdd(&hist[__float_as_uint(scores_ex[i]) >> 16], 1u);
}

__global__ void k_hist2_ex(const float* __restrict__ scores_ex, const unsigned* __restrict__ meta,
                           const unsigned* __restrict__ meta_ex, unsigned* __restrict__ hist2) {
    int npx = (int)meta[10]; if (npx > PXCAP) npx = PXCAP;
    int i = blockIdx.x * 256 + threadIdx.x;
    if (i >= npx * 9) return;
    unsigned b = __float_as_uint(scores_ex[i]);
    if ((b >> 16) == meta_ex[0]) atomicAdd(&hist2[b & 0xFFFFu], 1u);
}

__global__ void k_collect_ex(const float* __restrict__ scores_ex, const unsigned* __restrict__ meta,
                             unsigned* __restrict__ meta_ex, const unsigned* __restrict__ px_list,
                             unsigned* __restrict__ sel_bits, unsigned* __restrict__ sel_idx,
                             unsigned* __restrict__ eq_idx) {
    int npx = (int)meta[10]; if (npx > PXCAP) npx = PXCAP;
    int i = blockIdx.x * 256 + threadIdx.x;
    if (i >= npx * 9) return;
    unsigned b = __float_as_uint(scores_ex[i]);
    unsigned T = meta_ex[2];
    unsigned g = px_list[i / 9] * 9u + (unsigned)(i % 9);
    if (b > T) {
        unsigned s = atomicAdd(&meta_ex[8], 1u);
        if (s < 1024u) { sel_bits[s] = b; sel_idx[s] = g; }
    } else if (b == T) {
        unsigned s = atomicAdd(&meta_ex[9], 1u);
        if (s < 65536u) eq_idx[s] = g;
    }
}

// exact stable top-1000 (ties -> smallest global idx), bitonic final order
__global__ void k_topk_final(const unsigned* __restrict__ sel_bits, const unsigned* __restrict__ sel_idx,
                             const unsigned* __restrict__ eq_idx, const unsigned* __restrict__ meta,
                             unsigned* __restrict__ top_idx, float* __restrict__ top_sc) {
    __shared__ uint64_t keys[1024];
    __shared__ int lcnt;
    __shared__ int lred;
    int t = threadIdx.x;
    unsigned cntGt = meta[3];
    unsigned need = meta[4];
    unsigned cntEq = meta[9];
    unsigned T = meta[2];

    unsigned idx_cut = 0xFFFFFFFFu;
    if (cntEq > need) {
        unsigned lo = 0, hi = NANCH - 1;
        while (lo < hi) {
            unsigned mid = (lo + hi) >> 1;
            int c = 0;
            for (unsigned e = t; e < cntEq; e += 1024)
                if (eq_idx[e] <= mid) c++;
            if (t == 0) lred = 0;
            __syncthreads();
            atomicAdd(&lred, c);
            __syncthreads();
            int tot = lred;
            __syncthreads();
            if ((unsigned)tot >= need) hi = mid; else lo = mid + 1;
        }
        idx_cut = lo;
    }

    keys[t] = 0ull;
    if (t == 0) lcnt = 0;
    __syncthreads();
    for (unsigned s = t; s < cntGt; s += 1024)
        keys[s] = ((uint64_t)sel_bits[s] << 32) | (uint64_t)(0xFFFFFFFFu - sel_idx[s]);
    for (unsigned e = t; e < cntEq; e += 1024) {
        unsigned ix = eq_idx[e];
        if (ix <= idx_cut) {
            int s2 = (int)cntGt + atomicAdd(&lcnt, 1);
            keys[s2] = ((uint64_t)T << 32) | (uint64_t)(0xFFFFFFFFu - ix);
        }
    }
    __syncthreads();
    for (int k = 2; k <= 1024; k <<= 1) {
        for (int j = k >> 1; j > 0; j >>= 1) {
            int ixj = t ^ j;
            if (ixj > t) {
                uint64_t a = keys[t], b = keys[ixj];
                bool desc = (t & k) == 0;
                if (desc ? (a < b) : (a > b)) { keys[t] = b; keys[ixj] = a; }
            }
            __syncthreads();
        }
    }
    if (t < KPRE) {
        top_sc[t] = __uint_as_float((unsigned)(keys[t] >> 32));
        top_idx[t] = 0xFFFFFFFFu - (unsigned)keys[t];
    }
}

// ---------------------------------------------------------------------------
// decode from exact x (via flags px->slot map)
// ---------------------------------------------------------------------------
__global__ void k_decode(const float* __restrict__ xex, const unsigned* __restrict__ flags,
                         const float* __restrict__ reg_w, const float* __restrict__ reg_b,
                         const unsigned* __restrict__ top_idx,
                         float* __restrict__ props, float* __restrict__ areas) {
    int j = blockIdx.x;
    int lane = threadIdx.x;  // 64
    unsigned idx = top_idx[j];
    int pix = (int)(idx / 9u);
    int a = (int)(idx - (unsigned)pix * 9u);
    int slot = (int)flags[pix] - 1;
    if (slot < 0) slot = 0;
    const float* xr = xex + (size_t)slot * 512;
    float s0 = 0, s1 = 0, s2 = 0, s3 = 0;
    for (int c = lane; c < C_; c += 64) {
        float xv = xr[c];
        s0 = fmaf(xv, reg_w[(a * 4 + 0) * C_ + c], s0);
        s1 = fmaf(xv, reg_w[(a * 4 + 1) * C_ + c], s1);
        s2 = fmaf(xv, reg_w[(a * 4 + 2) * C_ + c], s2);
        s3 = fmaf(xv, reg_w[(a * 4 + 3) * C_ + c], s3);
    }
#pragma unroll
    for (int o = 32; o > 0; o >>= 1) {
        s0 += __shfl_down(s0, o);
        s1 += __shfl_down(s1, o);
        s2 += __shfl_down(s2, o);
        s3 += __shfl_down(s3, o);
    }
    if (lane == 0) {
        float d0 = s0 + reg_b[a * 4 + 0];
        float d1 = s1 + reg_b[a * 4 + 1];
        float d2 = s2 + reg_b[a * 4 + 2];
        float d3 = s3 + reg_b[a * 4 + 3];
        int h = pix / W_, w2 = pix - h * W_;
        int rr = a / 3, ss = a - rr * 3;
        float ratio = (rr == 0) ? 0.5f : (rr == 1) ? 1.0f : 2.0f;
        float scale = (ss == 0) ? 128.f : (ss == 1) ? 256.f : 512.f;
        float hr = sqrtf(ratio);
        float wr = 1.0f / hr;
        float wsc = wr * scale, hsc = hr * scale;
        float sx = (float)w2 * 16.f, sy = (float)h * 16.f;
        float a0 = sx - wsc * 0.5f, a1 = sy - hsc * 0.5f;
        float a2 = sx + wsc * 0.5f, a3 = sy + hsc * 0.5f;
        float bw = a2 - a0, bh = a3 - a1;
        float cx = a0 + 0.5f * bw, cy = a1 + 0.5f * bh;
        float px = d0 * bw + cx, py = d1 * bh + cy;
        float pw = expf(d2) * bw, ph = expf(d3) * bh;
        float b0 = px - 0.5f * pw, b1 = py - 0.5f * ph;
        float b2 = px + 0.5f * pw, b3 = py + 0.5f * ph;
        b0 = fminf(fmaxf(b0, 0.f), 3200.f);
        b1 = fminf(fmaxf(b1, 0.f), 3200.f);
        b2 = fminf(fmaxf(b2, 0.f), 3200.f);
        b3 = fminf(fmaxf(b3, 0.f), 3200.f);
        props[j * 4 + 0] = b0;
        props[j * 4 + 1] = b1;
        props[j * 4 + 2] = b2;
        props[j * 4 + 3] = b3;
        areas[j] = (b2 - b0) * (b3 - b1);
    }
}

// ---------------------------------------------------------------------------
__global__ void k_nms_mask(const float* __restrict__ props, const float* __restrict__ areas,
                           unsigned long long* __restrict__ mask, float* __restrict__ out) {
    int i = blockIdx.x;
    int tid = threadIdx.x;  // 256
    if (i == 0) {
        for (int t = tid; t < KPOST * 5; t += 256) out[t] = 0.f;
    }
    float x1i = props[i * 4 + 0], y1i = props[i * 4 + 1];
    float x2i = props[i * 4 + 2], y2i = props[i * 4 + 3];
    float ai = areas[i];
#pragma unroll
    for (int k = 0; k < 4; ++k) {
        int j = k * 256 + tid;
        bool sup = false;
        if (j < KPRE && j > i) {
            float iw = fminf(x2i, props[j * 4 + 2]) - fmaxf(x1i, props[j * 4 + 0]);
            float ih = fminf(y2i, props[j * 4 + 3]) - fmaxf(y1i, props[j * 4 + 1]);
            iw = fmaxf(iw, 0.f);
            ih = fmaxf(ih, 0.f);
            float inter = iw * ih;
            float iou = inter / (ai + areas[j] - inter);
            sup = iou > 0.7f;
        }
        unsigned long long b = __ballot(sup);
        int word = k * 4 + (tid >> 6);
        if ((tid & 63) == 0) mask[(size_t)i * 16 + word] = b;
    }
}

__global__ void k_nms_scan_out(const unsigned long long* __restrict__ mask,
                               const float* __restrict__ props, const float* __restrict__ top_sc,
                               float* __restrict__ out) {
    int lane = threadIdx.x;  // 64
    unsigned long long keep = 0ull;
    if (lane < 16) keep = (lane < 15) ? ~0ull : ((1ull << 40) - 1);  // 1000 bits
    for (int i = 0; i < KPRE; ++i) {
        unsigned long long kw = __shfl(keep, i >> 6);
        if ((kw >> (i & 63)) & 1ull) {
            if (lane < 16) keep &= ~mask[(size_t)i * 16 + lane];
        }
    }
    int pcv = (lane < 16) ? (int)__popcll(keep) : 0;
    int pre = 0;
    for (int j = 0; j < 16; ++j) {
        int v = __shfl(pcv, j);
        if (j < lane) pre += v;
    }
    for (int w = 0; w < 16; ++w) {
        unsigned long long kw = __shfl(keep, w);
        int base = __shfl(pre, w);
        int idx = w * 64 + lane;
        if (idx < KPRE && ((kw >> lane) & 1ull)) {
            int rank = base + (int)__popcll(kw & ((1ull << lane) - 1ull));
            if (rank < KPOST) {
                out[rank * 4 + 0] = props[idx * 4 + 0];
                out[rank * 4 + 1] = props[idx * 4 + 1];
                out[rank * 4 + 2] = props[idx * 4 + 2];
                out[rank * 4 + 3] = props[idx * 4 + 3];
                out[KPOST * 4 + rank] = top_sc[idx];
            }
        }
    }
}

// ---------------------------------------------------------------------------
extern "C" void kernel_launch(void* const* d_in, const int* in_sizes, int n_in,
                              void* d_out, int out_size, void* d_ws, size_t ws_size,
                              hipStream_t stream) {
    const float* feat   = (const float*)d_in[0];
    const float* conv_w = (const float*)d_in[1];
    const float* conv_b = (const float*)d_in[2];
    const float* cls_w  = (const float*)d_in[3];
    const float* cls_b  = (const float*)d_in[4];
    const float* reg_w  = (const float*)d_in[5];
    const float* reg_b  = (const float*)d_in[6];
    float* out = (float*)d_out;

    size_t off = 0;
    auto alloc = [&](size_t bytes) -> void* {
        off = (off + 255) & ~(size_t)255;
        void* p = (char*)d_ws + off;
        off += bytes;
        return p;
    };
    ushort* feat_t  = (ushort*)alloc((size_t)FT_Y * FT_X * 512 * 2);    // 44.3 MB
    ushort* wt_t    = (ushort*)alloc((size_t)9 * 512 * 512 * 2);        // 4.7 MB
    ushort* xab     = (ushort*)alloc((size_t)HW_ * 512 * 2);            // 41 MB
    float*  B_packed = (float*)alloc((size_t)PXCAP * 4608 * 4);         // 75.5 MB
    float*  xpart   = (float*)alloc((size_t)KSPLIT * PXCAP * 512 * 4);  // 33.6 MB
    float*  xex     = (float*)alloc((size_t)PXCAP * 512 * 4);           // 8.4 MB
    float*  scores  = (float*)alloc((size_t)NANCH * 4);                 // 1.44 MB
    float*  scores_ex = (float*)alloc((size_t)PXCAP * 9 * 4);
    // contiguous zero region: hist1, hist2, meta, meta_ex, flags
    unsigned* hist1   = (unsigned*)alloc(65536 * 4);
    unsigned* hist2   = (unsigned*)alloc(65536 * 4);
    unsigned* meta    = (unsigned*)alloc(64 * 4);
    unsigned* meta_ex = (unsigned*)alloc(64 * 4);
    unsigned* flags   = (unsigned*)alloc((size_t)HW_ * 4);
    unsigned* px_list = (unsigned*)alloc(PXCAP * 4);
    unsigned* sel_bits = (unsigned*)alloc(1024 * 4);
    unsigned* sel_idx  = (unsigned*)alloc(1024 * 4);
    unsigned* eq_idx   = (unsigned*)alloc(65536 * 4);
    unsigned* top_idx  = (unsigned*)alloc(KPRE * 4);
    float* top_sc      = (float*)alloc(KPRE * 4);
    float* props       = (float*)alloc(KPRE * 4 * 4);
    float* areas       = (float*)alloc(KPRE * 4);
    unsigned long long* mask = (unsigned long long*)alloc((size_t)KPRE * 16 * 8);
    (void)ws_size; (void)in_sizes; (void)n_in; (void)out_size;

    // 0) prep: zero feat_t pad + zero radix region; build bf16 layouts
    int ftDw = FT_Y * FT_X * 512 / 2;
    k_zero_u32<<<(ftDw + 255) / 256, 256, 0, stream>>>((unsigned*)feat_t, ftDw);
    int zrDw = 65536 * 2 + 64 + 64 + HW_;
    k_zero_u32<<<(zrDw + 255) / 256, 256, 0, stream>>>(hist1, zrDw);
    k_feat_t<<<dim3(7, 25, 16), 256, 0, stream>>>(feat, feat_t);
    k_wt_t<<<(9 * 512 * 512 + 255) / 256, 256, 0, stream>>>(conv_w, wt_t);
    // 1) approx conv (bf16 MFMA) + approx cls
    k_conv3_mfma<<<4 * 325, 256, 0, stream>>>(feat_t, wt_t, conv_b, xab);
    k_cls<<<HW_ / 64, 256, 0, stream>>>(xab, cls_w, cls_b, scores);
    // 2) candidate pixels: approx top-KSEL bucket threshold
    k_hist1<<<(NANCH + 255) / 256, 256, 0, stream>>>(scores, hist1);
    k_find_thr<<<1, 1024, 0, stream>>>(hist1, meta, 0, KSEL);
    k_collect_cand<<<(NANCH + 255) / 256, 256, 0, stream>>>(scores, meta, flags);
    k_px_compact<<<(HW_ + 255) / 256, 256, 0, stream>>>(flags, meta, px_list);
    // 3) exact fp32 conv at candidates: im2col -> K-split GEMM -> reduce
    k_zero_u32<<<(65536 * 2 + 255) / 256, 256, 0, stream>>>(hist1, 65536 * 2);
    k_im2col<<<dim3(PXCAP / 64, 72), 256, 0, stream>>>(feat, meta, px_list, B_packed);
    k_exact_gemm<<<dim3(PXCAP / 64, 4, KSPLIT), 256, 0, stream>>>(B_packed, conv_w, meta, xpart);
    k_exact_reduce<<<PXCAP * 512 / 256, 256, 0, stream>>>(xpart, conv_b, meta, xex);
    k_exact_scores<<<PXCAP, 64, 0, stream>>>(xex, cls_w, cls_b, meta, scores_ex);
    // 4) exact stable top-1000 among candidate anchors (global indices)
    k_hist1_ex<<<(PXCAP * 9 + 255) / 256, 256, 0, stream>>>(scores_ex, meta, hist1);
    k_find_thr<<<1, 1024, 0, stream>>>(hist1, meta_ex, 0, KPRE);
    k_hist2_ex<<<(PXCAP * 9 + 255) / 256, 256, 0, stream>>>(scores_ex, meta, meta_ex, hist2);
    k_find_thr<<<1, 1024, 0, stream>>>(hist2, meta_ex, 1, KPRE);
    k_collect_ex<<<(PXCAP * 9 + 255) / 256, 256, 0, stream>>>(scores_ex, meta, meta_ex, px_list,
                                                              sel_bits, sel_idx, eq_idx);
    k_topk_final<<<1, 1024, 0, stream>>>(sel_bits, sel_idx, eq_idx, meta_ex, top_idx, top_sc);
    // 5) exact decode + NMS
    k_decode<<<KPRE, 64, 0, stream>>>(xex, flags, reg_w, reg_b, top_idx, props, areas);
    k_nms_mask<<<KPRE, 256, 0, stream>>>(props, areas, mask, out);
    k_nms_scan_out<<<1, 64, 0, stream>>>(mask, props, top_sc, out);
}

// Round 6
// 1158.620 us; speedup vs baseline: 6.0388x; 1.4152x over previous
//
#include <hip/hip_runtime.h>
#include <stdint.h>

// Problem constants
static constexpr int H_ = 200, W_ = 200, HW_ = 40000;
static constexpr int C_ = 512;
static constexpr int NANCH = 360000;   // HW_ * 9
static constexpr int KPRE = 1000;
static constexpr int KPOST = 100;
static constexpr int KSEL = 1400;      // approx candidate margin (top-1000 + 400)
static constexpr int PXCAP = 4096;     // candidate pixel cap (est npx ~1600)
static constexpr int KSPLIT = 4;       // exact-gemm K split (4608 = 4 x 1152)
// feat_t padded dims: [212 y][212 x][512 ci] bf16, real (y,x) at (y+1,x+1)
static constexpr int FT = 212;
// feat_px padded dims: [202][202][512] fp32, real (y,x) at (y+1,x+1)
static constexpr int FP = 202;

typedef __attribute__((ext_vector_type(8))) short bf16x8;
typedef __attribute__((ext_vector_type(4))) float f32x4;

__device__ inline ushort f2bf(float f) {               // RNE float->bf16 bits
    unsigned u = __float_as_uint(f);
    u += 0x7FFFu + ((u >> 16) & 1u);
    return (ushort)(u >> 16);
}
__device__ inline float bf2f(ushort h) { return __uint_as_float(((unsigned)h) << 16); }

// ---------------------------------------------------------------------------
__global__ void k_zero_u32(unsigned* __restrict__ p, int n) {
    int i = blockIdx.x * 256 + threadIdx.x;
    if (i < n) p[i] = 0u;
}

// ---------------------------------------------------------------------------
// feat [512][200][200] f32 -> feat_t [212][212][512] bf16 (zero-padded)
// ---------------------------------------------------------------------------
__global__ void k_feat_t(const float* __restrict__ feat, ushort* __restrict__ feat_t) {
    __shared__ ushort lt[32 * 8 * 33];
    int x0 = blockIdx.x * 32, y0 = blockIdx.y * 8, ci0 = blockIdx.z * 32;
    int tid = threadIdx.x;
    for (int u = tid; u < 8192; u += 256) {
        int ciL = u >> 8, rem = u & 255;
        int yy = rem >> 5, xx = rem & 31;
        int x = x0 + xx;
        float v = (x < W_) ? feat[(size_t)(ci0 + ciL) * HW_ + (y0 + yy) * W_ + x] : 0.f;
        lt[(ciL * 8 + yy) * 33 + xx] = f2bf(v);
    }
    __syncthreads();
    for (int u = tid; u < 1024; u += 256) {
        int pxu = u >> 2, part = u & 3;
        int yy = pxu >> 5, xx = pxu & 31;
        if (x0 + xx >= W_) continue;
        ushort tmp[8];
#pragma unroll
        for (int k = 0; k < 8; ++k) tmp[k] = lt[((part * 8 + k) * 8 + yy) * 33 + xx];
        *(uint4*)&feat_t[((size_t)(y0 + yy + 1) * FT + (x0 + xx + 1)) * 512 + ci0 + part * 8] =
            *(const uint4*)&tmp[0];
    }
}

// feat -> feat_px [202][202][512] fp32 (zero-padded)
__global__ void k_feat_px(const float* __restrict__ feat, float* __restrict__ feat_px) {
    __shared__ float lt[32 * 8 * 33];
    int x0 = blockIdx.x * 32, y0 = blockIdx.y * 8, ci0 = blockIdx.z * 32;
    int tid = threadIdx.x;
    for (int u = tid; u < 8192; u += 256) {
        int ciL = u >> 8, rem = u & 255;
        int yy = rem >> 5, xx = rem & 31;
        int x = x0 + xx;
        float v = (x < W_) ? feat[(size_t)(ci0 + ciL) * HW_ + (y0 + yy) * W_ + x] : 0.f;
        lt[(ciL * 8 + yy) * 33 + xx] = v;
    }
    __syncthreads();
    for (int u = tid; u < 1024; u += 256) {
        int pxu = u >> 2, part = u & 3;
        int yy = pxu >> 5, xx = pxu & 31;
        if (x0 + xx >= W_) continue;
        float tmp[8];
#pragma unroll
        for (int k = 0; k < 8; ++k) tmp[k] = lt[((part * 8 + k) * 8 + yy) * 33 + xx];
        float* dst = &feat_px[((size_t)(y0 + yy + 1) * FP + (x0 + xx + 1)) * 512 + ci0 + part * 8];
        *(float4*)&dst[0] = *(const float4*)&tmp[0];
        *(float4*)&dst[4] = *(const float4*)&tmp[4];
    }
}

// conv_w [co][ci][th][tw] f32 -> wt_t [tap9][co512][ci512] bf16
__global__ void k_wt_t(const float* __restrict__ conv_w, ushort* __restrict__ wt_t) {
    int i = blockIdx.x * 256 + threadIdx.x;
    if (i >= 9 * 512 * 512) return;
    int tap = i >> 18;
    int rem = i & 262143;
    int co = rem >> 9, ci = rem & 511;
    wt_t[i] = f2bf(conv_w[((size_t)co * 512 + ci) * 9 + tap]);
}

// conv_w -> wt_ex [k'=tap*512+ci][co512] fp32 (LDS 32x32 transpose)
__global__ void k_wt_ex(const float* __restrict__ conv_w, float* __restrict__ wt_ex) {
    __shared__ float t[32][33];
    int kb = blockIdx.x * 32;   // k' base (4608/32 = 144), single tap per tile
    int cb = blockIdx.y * 32;
    int lx = threadIdx.x, ly = threadIdx.y;
    int tap = kb >> 9, ci0 = kb & 511;
    for (int r = ly; r < 32; r += 8)
        t[r][lx] = conv_w[((size_t)(cb + r) * 512 + ci0 + lx) * 9 + tap];
    __syncthreads();
    for (int r = ly; r < 32; r += 8)
        wt_ex[(size_t)(kb + r) * 512 + cb + lx] = t[lx][r];
}

// ---------------------------------------------------------------------------
// Approx conv v2: bf16 MFMA 16x16x32. Block = 64 co x (16x16 px), 4 waves.
// Per 32-ci chunk: stage halo[18][18][40] + ALL 9 taps wtile[9][64][40] once
// (2 barriers/chunk, 32 total vs 288 in v1). LDS 72KB -> 2 blocks/CU so one
// block's staging overlaps the other's 144-MFMA compute run.
// ---------------------------------------------------------------------------
__global__ __launch_bounds__(256)
__attribute__((amdgpu_waves_per_eu(2, 4)))
void k_conv3_mfma(const ushort* __restrict__ feat_t, const ushort* __restrict__ wt_t,
                  const float* __restrict__ bias, ushort* __restrict__ xab) {
    __shared__ ushort halo[18 * 18 * 40];   // [r][c][32ci + pad8]  25.9 KB
    __shared__ ushort wtile[9 * 64 * 40];   // [tap][co][32ci+pad8] 46.1 KB
    int b = blockIdx.x;
    int cot = b / 169;
    int tile = b - cot * 169;
    int xt = tile % 13, yt = tile / 13;
    int x0 = xt * 16, y0 = yt * 16;
    int co0 = cot * 64;
    int tid = threadIdx.x;
    int lane = tid & 63, wid = tid >> 6;
    int l15 = lane & 15, l4 = lane >> 4;

    f32x4 acc[4][4];
#pragma unroll
    for (int i = 0; i < 4; ++i)
#pragma unroll
        for (int j = 0; j < 4; ++j) acc[i][j] = (f32x4){0.f, 0.f, 0.f, 0.f};

    for (int ch = 0; ch < 16; ++ch) {
        int ci0 = ch * 32;
        __syncthreads();   // previous chunk's reads done
        // halo: 18x18 px * 4 parts = 1296 units of 16B
        for (int u = tid; u < 1296; u += 256) {
            int p = u >> 2, q = u & 3;
            int r = p / 18, c = p - r * 18;
            const ushort* src = feat_t + ((size_t)(y0 + r) * FT + (x0 + c)) * 512 + ci0 + q * 8;
            *(uint4*)&halo[(r * 18 + c) * 40 + q * 8] = *(const uint4*)src;
        }
        // weights: 9 taps * 64 co * 4 parts = 2304 units of 16B
        for (int u = tid; u < 2304; u += 256) {
            int row = u >> 2, q = u & 3;       // row = tap*64 + co
            int tap = row >> 6, co = row & 63;
            const ushort* src = wt_t + ((size_t)(tap * 512 + co0 + co)) * 512 + ci0 + q * 8;
            *(uint4*)&wtile[row * 40 + q * 8] = *(const uint4*)src;
        }
        __syncthreads();
#pragma unroll
        for (int tap = 0; tap < 9; ++tap) {
            int th = tap / 3, tw = tap - th * 3;
            bf16x8 af[4], bf[4];
#pragma unroll
            for (int pi = 0; pi < 4; ++pi)
                af[pi] = *(const bf16x8*)&halo[((wid * 4 + pi + th) * 18 + (l15 + tw)) * 40 + l4 * 8];
#pragma unroll
            for (int cj = 0; cj < 4; ++cj)
                bf[cj] = *(const bf16x8*)&wtile[(tap * 64 + cj * 16 + l15) * 40 + l4 * 8];
#pragma unroll
            for (int pi = 0; pi < 4; ++pi)
#pragma unroll
                for (int cj = 0; cj < 4; ++cj)
                    acc[pi][cj] = __builtin_amdgcn_mfma_f32_16x16x32_bf16(af[pi], bf[cj], acc[pi][cj], 0, 0, 0);
        }
    }

    float bv[4];
#pragma unroll
    for (int cj = 0; cj < 4; ++cj) bv[cj] = bias[co0 + cj * 16 + l15];
#pragma unroll
    for (int pi = 0; pi < 4; ++pi) {
        int yy = y0 + wid * 4 + pi;
        if (yy >= H_) continue;
#pragma unroll
        for (int cj = 0; cj < 4; ++cj) {
            int co = co0 + cj * 16 + l15;
#pragma unroll
            for (int r = 0; r < 4; ++r) {
                int xx = x0 + l4 * 4 + r;
                if (xx < W_) {
                    float v = acc[pi][cj][r] + bv[cj];
                    xab[((size_t)(yy * W_ + xx)) * 512 + co] = f2bf(v > 0.f ? v : 0.f);
                }
            }
        }
    }
}

// ---------------------------------------------------------------------------
// Approx cls: scores[px*9+a] = sigmoid(dot(xab row, cls_w[a]) + b). Wave/px.
// ---------------------------------------------------------------------------
__global__ void k_cls(const ushort* __restrict__ xab, const float* __restrict__ cls_w,
                      const float* __restrict__ cls_b, float* __restrict__ scores) {
    __shared__ float wl[9 * 512];
    int tid = threadIdx.x;
    for (int t = tid; t < 4608; t += 256) wl[t] = cls_w[t];
    __syncthreads();
    int l = tid & 63, w = tid >> 6;
    int pbase = blockIdx.x * 64 + w * 16;
    for (int u = 0; u < 16; ++u) {
        int px = pbase + u;
        float xv[8];
#pragma unroll
        for (int k = 0; k < 8; ++k) xv[k] = bf2f(xab[(size_t)px * 512 + k * 64 + l]);
#pragma unroll
        for (int a = 0; a < 9; ++a) {
            float s = 0.f;
#pragma unroll
            for (int k = 0; k < 8; ++k) s = fmaf(xv[k], wl[a * 512 + k * 64 + l], s);
#pragma unroll
            for (int o = 32; o > 0; o >>= 1) s += __shfl_down(s, o);
            if (l == 0) scores[(size_t)px * 9 + a] = 1.f / (1.f + expf(-(s + cls_b[a])));
        }
    }
}

// ---------------------------------------------------------------------------
// Radix-select helpers
// meta: [0]=P [1]=cntAboveP [2]=T [3]=cntGtT [4]=need [8]=atomGt [9]=atomEq [10]=npx
// ---------------------------------------------------------------------------
// LDS histogram over hi16 (scores in [0,1] -> hi16 < 16384). Kills the
// same-address L2 atomic serialization of the concentrated score distribution.
__global__ void k_hist1_lds(const float* __restrict__ scores, unsigned* __restrict__ hist) {
    __shared__ unsigned h[16384];
    int tid = threadIdx.x;
    for (int j = tid; j < 16384; j += 256) h[j] = 0u;
    __syncthreads();
    for (int i = blockIdx.x * 256 + tid; i < NANCH; i += 256 * 256)
        atomicAdd(&h[(__float_as_uint(scores[i]) >> 16) & 16383], 1u);
    __syncthreads();
    for (int j = tid; j < 16384; j += 256) {
        unsigned v = h[j];
        if (v) atomicAdd(&hist[j], v);
    }
}

__global__ void k_find_thr(const unsigned* __restrict__ hist, unsigned* __restrict__ meta,
                           int mode, int Kwant) {
    __shared__ unsigned csum[1024];
    int t = threadIdx.x;
    unsigned base = (mode == 0) ? 0u : meta[1];
    unsigned s = 0;
    for (int b = 0; b < 64; ++b) s += hist[t * 64 + b];
    csum[t] = s;
    __syncthreads();
    for (int off = 1; off < 1024; off <<= 1) {
        unsigned add = (t + off < 1024) ? csum[t + off] : 0u;
        __syncthreads();
        csum[t] += add;
        __syncthreads();
    }
    unsigned run = base + ((t < 1023) ? csum[t + 1] : 0u);
    for (int b = 63; b >= 0; --b) {
        unsigned h = hist[t * 64 + b];
        if (run < (unsigned)Kwant && run + h >= (unsigned)Kwant) {
            if (mode == 0) {
                meta[0] = (unsigned)(t * 64 + b);
                meta[1] = run;
            } else {
                meta[2] = (meta[0] << 16) | (unsigned)(t * 64 + b);
                meta[3] = run;
                meta[4] = (unsigned)Kwant - run;
            }
            break;
        }
        run += h;
    }
}

// mark candidate pixels: anchors with hi16(score) >= P
__global__ void k_collect_cand(const float* __restrict__ scores, const unsigned* __restrict__ meta,
                               unsigned* __restrict__ flags) {
    int i = blockIdx.x * 256 + threadIdx.x;
    if (i >= NANCH) return;
    if ((__float_as_uint(scores[i]) >> 16) >= meta[0]) flags[i / 9] = 1u;
}

__global__ void k_px_compact(unsigned* __restrict__ flags, unsigned* __restrict__ meta,
                             unsigned* __restrict__ px_list) {
    int px = blockIdx.x * 256 + threadIdx.x;
    if (px >= HW_) return;
    if (flags[px]) {
        unsigned s = atomicAdd(&meta[10], 1u);
        if (s < (unsigned)PXCAP) { px_list[s] = (unsigned)px; flags[px] = s + 1u; }
        else flags[px] = 0u;
    }
}

// ---------------------------------------------------------------------------
// Exact fp32 conv GEMM v3: C[128co x 64px], K' = tap*512+ci (tap-major),
// K-split x4 -> xpart[kz]. B staged DIRECTLY from feat_px (contiguous 128B
// ci-runs per px per tap; 32-k chunks never straddle a tap since 512%32==0).
// ---------------------------------------------------------------------------
__global__ __attribute__((amdgpu_waves_per_eu(2, 4)))
void k_exact_gemm(const float* __restrict__ feat_px, const float* __restrict__ wt_ex,
                  const unsigned* __restrict__ meta, const unsigned* __restrict__ px_list,
                  float* __restrict__ xpart) {
    int npx = (int)meta[10]; if (npx > PXCAP) npx = PXCAP;
    int pb = blockIdx.x;
    if (pb * 64 >= npx) return;
    int cot = blockIdx.y;
    int kz = blockIdx.z;
    __shared__ float A[32][132];
    __shared__ float B[32][68];
    __shared__ int plist[64];
    int tid = threadIdx.x;
    int co0 = cot * 128;
    if (tid < 64) {
        int slot = pb * 64 + tid;
        plist[tid] = (slot < npx) ? (int)px_list[slot] : (int)px_list[0];
    }
    int tcog = tid >> 4;   // 8 co each
    int tpxg = tid & 15;   // 4 px each
    float acc[8][4];
#pragma unroll
    for (int i = 0; i < 8; ++i)
#pragma unroll
        for (int j = 0; j < 4; ++j) acc[i][j] = 0.f;
    int kbase = kz * 1152;
    for (int kc = 0; kc < 36; ++kc) {
        int k0 = kbase + kc * 32;
        int tap = k0 >> 9, ci0c = k0 & 511;
        int th = tap / 3, tw = tap - th * 3;
        __syncthreads();
        for (int u = tid; u < 1024; u += 256) {          // A: 32k x 128co from wt_ex
            int k = u >> 5, cp = (u & 31) * 4;
            float4 v = *(const float4*)&wt_ex[(size_t)(k0 + k) * 512 + co0 + cp];
            *(float4*)&A[k][cp] = v;
        }
        for (int u = tid; u < 512; u += 256) {           // B: 64px x 32ci from feat_px
            int s = u >> 3, part = u & 7;
            int px = plist[s];
            int y = px / W_, x = px - y * W_;
            float4 v = *(const float4*)&feat_px[((size_t)(y + th) * FP + (x + tw)) * 512 + ci0c + part * 4];
            B[part * 4 + 0][s] = v.x; B[part * 4 + 1][s] = v.y;
            B[part * 4 + 2][s] = v.z; B[part * 4 + 3][s] = v.w;
        }
        __syncthreads();
#pragma unroll 4
        for (int k = 0; k < 32; ++k) {
            float wv[8], pv[4];
            *(float4*)&wv[0] = *(const float4*)&A[k][tcog * 8];
            *(float4*)&wv[4] = *(const float4*)&A[k][tcog * 8 + 4];
            *(float4*)&pv[0] = *(const float4*)&B[k][tpxg * 4];
#pragma unroll
            for (int i = 0; i < 8; ++i)
#pragma unroll
                for (int j = 0; j < 4; ++j) acc[i][j] = fmaf(wv[i], pv[j], acc[i][j]);
        }
    }
#pragma unroll
    for (int j = 0; j < 4; ++j) {
        int slot = pb * 64 + tpxg * 4 + j;
        if (slot >= npx) continue;
#pragma unroll
        for (int i = 0; i < 8; ++i) {
            int co = co0 + tcog * 8 + i;
            xpart[((size_t)kz * PXCAP + slot) * 512 + co] = acc[i][j];
        }
    }
}

// fixed-order reduce of K-split partials + bias + relu -> xex
__global__ void k_exact_reduce(const float* __restrict__ xpart, const float* __restrict__ bias,
                               const unsigned* __restrict__ meta, float* __restrict__ xex) {
    int npx = (int)meta[10]; if (npx > PXCAP) npx = PXCAP;
    int idx = blockIdx.x * 256 + threadIdx.x;
    int slot = idx >> 9, co = idx & 511;
    if (slot >= npx) return;
    float v = xpart[(size_t)slot * 512 + co];
    v += xpart[((size_t)PXCAP + slot) * 512 + co];
    v += xpart[((size_t)2 * PXCAP + slot) * 512 + co];
    v += xpart[((size_t)3 * PXCAP + slot) * 512 + co];
    v += bias[co];
    xex[(size_t)slot * 512 + co] = v > 0.f ? v : 0.f;
}

// exact scores for all 9 anchors of each candidate pixel
__global__ void k_exact_scores(const float* __restrict__ xex, const float* __restrict__ cls_w,
                               const float* __restrict__ cls_b, const unsigned* __restrict__ meta,
                               float* __restrict__ scores_ex) {
    int slot = blockIdx.x;
    int npx = (int)meta[10]; if (npx > PXCAP) npx = PXCAP;
    if (slot >= npx) return;
    int l = threadIdx.x;
    float xv[8];
#pragma unroll
    for (int k = 0; k < 8; ++k) xv[k] = xex[(size_t)slot * 512 + k * 64 + l];
#pragma unroll
    for (int a = 0; a < 9; ++a) {
        float s = 0.f;
#pragma unroll
        for (int k = 0; k < 8; ++k) s = fmaf(xv[k], cls_w[a * 512 + k * 64 + l], s);
#pragma unroll
        for (int o = 32; o > 0; o >>= 1) s += __shfl_down(s, o);
        if (l == 0) scores_ex[slot * 9 + a] = 1.f / (1.f + expf(-(s + cls_b[a])));
    }
}

__global__ void k_hist1_ex_lds(const float* __restrict__ scores_ex, const unsigned* __restrict__ meta,
                               unsigned* __restrict__ hist) {
    __shared__ unsigned h[16384];
    int npx = (int)meta[10]; if (npx > PXCAP) npx = PXCAP;
    int n = npx * 9;
    int tid = threadIdx.x;
    for (int j = tid; j < 16384; j += 256) h[j] = 0u;
    __syncthreads();
    for (int i = blockIdx.x * 256 + tid; i < n; i += 32 * 256)
        atomicAdd(&h[(__float_as_uint(scores_ex[i]) >> 16) & 16383], 1u);
    __syncthreads();
    for (int j = tid; j < 16384; j += 256) {
        unsigned v = h[j];
        if (v) atomicAdd(&hist[j], v);
    }
}

__global__ void k_hist2_ex(const float* __restrict__ scores_ex, const unsigned* __restrict__ meta,
                           const unsigned* __restrict__ meta_ex, unsigned* __restrict__ hist2) {
    int npx = (int)meta[10]; if (npx > PXCAP) npx = PXCAP;
    int i = blockIdx.x * 256 + threadIdx.x;
    if (i >= npx * 9) return;
    unsigned b = __float_as_uint(scores_ex[i]);
    if ((b >> 16) == meta_ex[0]) atomicAdd(&hist2[b & 0xFFFFu], 1u);
}

__global__ void k_collect_ex(const float* __restrict__ scores_ex, const unsigned* __restrict__ meta,
                             unsigned* __restrict__ meta_ex, const unsigned* __restrict__ px_list,
                             unsigned* __restrict__ sel_bits, unsigned* __restrict__ sel_idx,
                             unsigned* __restrict__ eq_idx) {
    int npx = (int)meta[10]; if (npx > PXCAP) npx = PXCAP;
    int i = blockIdx.x * 256 + threadIdx.x;
    if (i >= npx * 9) return;
    unsigned b = __float_as_uint(scores_ex[i]);
    unsigned T = meta_ex[2];
    unsigned g = px_list[i / 9] * 9u + (unsigned)(i % 9);
    if (b > T) {
        unsigned s = atomicAdd(&meta_ex[8], 1u);
        if (s < 1024u) { sel_bits[s] = b; sel_idx[s] = g; }
    } else if (b == T) {
        unsigned s = atomicAdd(&meta_ex[9], 1u);
        if (s < 65536u) eq_idx[s] = g;
    }
}

// exact stable top-1000 (ties -> smallest global idx), bitonic final order
__global__ void k_topk_final(const unsigned* __restrict__ sel_bits, const unsigned* __restrict__ sel_idx,
                             const unsigned* __restrict__ eq_idx, const unsigned* __restrict__ meta,
                             unsigned* __restrict__ top_idx, float* __restrict__ top_sc) {
    __shared__ uint64_t keys[1024];
    __shared__ int lcnt;
    __shared__ int lred;
    int t = threadIdx.x;
    unsigned cntGt = meta[3];
    unsigned need = meta[4];
    unsigned cntEq = meta[9];
    unsigned T = meta[2];

    unsigned idx_cut = 0xFFFFFFFFu;
    if (cntEq > need) {
        unsigned lo = 0, hi = NANCH - 1;
        while (lo < hi) {
            unsigned mid = (lo + hi) >> 1;
            int c = 0;
            for (unsigned e = t; e < cntEq; e += 1024)
                if (eq_idx[e] <= mid) c++;
            if (t == 0) lred = 0;
            __syncthreads();
            atomicAdd(&lred, c);
            __syncthreads();
            int tot = lred;
            __syncthreads();
            if ((unsigned)tot >= need) hi = mid; else lo = mid + 1;
        }
        idx_cut = lo;
    }

    keys[t] = 0ull;
    if (t == 0) lcnt = 0;
    __syncthreads();
    for (unsigned s = t; s < cntGt; s += 1024)
        keys[s] = ((uint64_t)sel_bits[s] << 32) | (uint64_t)(0xFFFFFFFFu - sel_idx[s]);
    for (unsigned e = t; e < cntEq; e += 1024) {
        unsigned ix = eq_idx[e];
        if (ix <= idx_cut) {
            int s2 = (int)cntGt + atomicAdd(&lcnt, 1);
            keys[s2] = ((uint64_t)T << 32) | (uint64_t)(0xFFFFFFFFu - ix);
        }
    }
    __syncthreads();
    for (int k = 2; k <= 1024; k <<= 1) {
        for (int j = k >> 1; j > 0; j >>= 1) {
            int ixj = t ^ j;
            if (ixj > t) {
                uint64_t a = keys[t], b = keys[ixj];
                bool desc = (t & k) == 0;
                if (desc ? (a < b) : (a > b)) { keys[t] = b; keys[ixj] = a; }
            }
            __syncthreads();
        }
    }
    if (t < KPRE) {
        top_sc[t] = __uint_as_float((unsigned)(keys[t] >> 32));
        top_idx[t] = 0xFFFFFFFFu - (unsigned)keys[t];
    }
}

// ---------------------------------------------------------------------------
// decode from exact x (via flags px->slot map)
// ---------------------------------------------------------------------------
__global__ void k_decode(const float* __restrict__ xex, const unsigned* __restrict__ flags,
                         const float* __restrict__ reg_w, const float* __restrict__ reg_b,
                         const unsigned* __restrict__ top_idx,
                         float* __restrict__ props, float* __restrict__ areas) {
    int j = blockIdx.x;
    int lane = threadIdx.x;  // 64
    unsigned idx = top_idx[j];
    int pix = (int)(idx / 9u);
    int a = (int)(idx - (unsigned)pix * 9u);
    int slot = (int)flags[pix] - 1;
    if (slot < 0) slot = 0;
    const float* xr = xex + (size_t)slot * 512;
    float s0 = 0, s1 = 0, s2 = 0, s3 = 0;
    for (int c = lane; c < C_; c += 64) {
        float xv = xr[c];
        s0 = fmaf(xv, reg_w[(a * 4 + 0) * C_ + c], s0);
        s1 = fmaf(xv, reg_w[(a * 4 + 1) * C_ + c], s1);
        s2 = fmaf(xv, reg_w[(a * 4 + 2) * C_ + c], s2);
        s3 = fmaf(xv, reg_w[(a * 4 + 3) * C_ + c], s3);
    }
#pragma unroll
    for (int o = 32; o > 0; o >>= 1) {
        s0 += __shfl_down(s0, o);
        s1 += __shfl_down(s1, o);
        s2 += __shfl_down(s2, o);
        s3 += __shfl_down(s3, o);
    }
    if (lane == 0) {
        float d0 = s0 + reg_b[a * 4 + 0];
        float d1 = s1 + reg_b[a * 4 + 1];
        float d2 = s2 + reg_b[a * 4 + 2];
        float d3 = s3 + reg_b[a * 4 + 3];
        int h = pix / W_, w2 = pix - h * W_;
        int rr = a / 3, ss = a - rr * 3;
        float ratio = (rr == 0) ? 0.5f : (rr == 1) ? 1.0f : 2.0f;
        float scale = (ss == 0) ? 128.f : (ss == 1) ? 256.f : 512.f;
        float hr = sqrtf(ratio);
        float wr = 1.0f / hr;
        float wsc = wr * scale, hsc = hr * scale;
        float sx = (float)w2 * 16.f, sy = (float)h * 16.f;
        float a0 = sx - wsc * 0.5f, a1 = sy - hsc * 0.5f;
        float a2 = sx + wsc * 0.5f, a3 = sy + hsc * 0.5f;
        float bw = a2 - a0, bh = a3 - a1;
        float cx = a0 + 0.5f * bw, cy = a1 + 0.5f * bh;
        float px = d0 * bw + cx, py = d1 * bh + cy;
        float pw = expf(d2) * bw, ph = expf(d3) * bh;
        float b0 = px - 0.5f * pw, b1 = py - 0.5f * ph;
        float b2 = px + 0.5f * pw, b3 = py + 0.5f * ph;
        b0 = fminf(fmaxf(b0, 0.f), 3200.f);
        b1 = fminf(fmaxf(b1, 0.f), 3200.f);
        b2 = fminf(fmaxf(b2, 0.f), 3200.f);
        b3 = fminf(fmaxf(b3, 0.f), 3200.f);
        props[j * 4 + 0] = b0;
        props[j * 4 + 1] = b1;
        props[j * 4 + 2] = b2;
        props[j * 4 + 3] = b3;
        areas[j] = (b2 - b0) * (b3 - b1);
    }
}

// ---------------------------------------------------------------------------
__global__ void k_nms_mask(const float* __restrict__ props, const float* __restrict__ areas,
                           unsigned long long* __restrict__ mask, float* __restrict__ out) {
    int i = blockIdx.x;
    int tid = threadIdx.x;  // 256
    if (i == 0) {
        for (int t = tid; t < KPOST * 5; t += 256) out[t] = 0.f;
    }
    float x1i = props[i * 4 + 0], y1i = props[i * 4 + 1];
    float x2i = props[i * 4 + 2], y2i = props[i * 4 + 3];
    float ai = areas[i];
#pragma unroll
    for (int k = 0; k < 4; ++k) {
        int j = k * 256 + tid;
        bool sup = false;
        if (j < KPRE && j > i) {
            float iw = fminf(x2i, props[j * 4 + 2]) - fmaxf(x1i, props[j * 4 + 0]);
            float ih = fminf(y2i, props[j * 4 + 3]) - fmaxf(y1i, props[j * 4 + 1]);
            iw = fmaxf(iw, 0.f);
            ih = fmaxf(ih, 0.f);
            float inter = iw * ih;
            float iou = inter / (ai + areas[j] - inter);
            sup = iou > 0.7f;
        }
        unsigned long long b = __ballot(sup);
        int word = k * 4 + (tid >> 6);
        if ((tid & 63) == 0) mask[(size_t)i * 16 + word] = b;
    }
}

__global__ void k_nms_scan_out(const unsigned long long* __restrict__ mask,
                               const float* __restrict__ props, const float* __restrict__ top_sc,
                               float* __restrict__ out) {
    int lane = threadIdx.x;  // 64
    unsigned long long keep = 0ull;
    if (lane < 16) keep = (lane < 15) ? ~0ull : ((1ull << 40) - 1);  // 1000 bits
    for (int i = 0; i < KPRE; ++i) {
        unsigned long long kw = __shfl(keep, i >> 6);
        if ((kw >> (i & 63)) & 1ull) {
            if (lane < 16) keep &= ~mask[(size_t)i * 16 + lane];
        }
    }
    int pcv = (lane < 16) ? (int)__popcll(keep) : 0;
    int pre = 0;
    for (int j = 0; j < 16; ++j) {
        int v = __shfl(pcv, j);
        if (j < lane) pre += v;
    }
    for (int w = 0; w < 16; ++w) {
        unsigned long long kw = __shfl(keep, w);
        int base = __shfl(pre, w);
        int idx = w * 64 + lane;
        if (idx < KPRE && ((kw >> lane) & 1ull)) {
            int rank = base + (int)__popcll(kw & ((1ull << lane) - 1ull));
            if (rank < KPOST) {
                out[rank * 4 + 0] = props[idx * 4 + 0];
                out[rank * 4 + 1] = props[idx * 4 + 1];
                out[rank * 4 + 2] = props[idx * 4 + 2];
                out[rank * 4 + 3] = props[idx * 4 + 3];
                out[KPOST * 4 + rank] = top_sc[idx];
            }
        }
    }
}

// ---------------------------------------------------------------------------
extern "C" void kernel_launch(void* const* d_in, const int* in_sizes, int n_in,
                              void* d_out, int out_size, void* d_ws, size_t ws_size,
                              hipStream_t stream) {
    const float* feat   = (const float*)d_in[0];
    const float* conv_w = (const float*)d_in[1];
    const float* conv_b = (const float*)d_in[2];
    const float* cls_w  = (const float*)d_in[3];
    const float* cls_b  = (const float*)d_in[4];
    const float* reg_w  = (const float*)d_in[5];
    const float* reg_b  = (const float*)d_in[6];
    float* out = (float*)d_out;

    size_t off = 0;
    auto alloc = [&](size_t bytes) -> void* {
        off = (off + 255) & ~(size_t)255;
        void* p = (char*)d_ws + off;
        off += bytes;
        return p;
    };
    // feat_t and feat_px adjacent: zeroed by one kernel
    ushort* feat_t  = (ushort*)alloc((size_t)FT * FT * 512 * 2);        // 46.0 MB
    float*  feat_px = (float*)alloc((size_t)FP * FP * 512 * 4);         // 83.6 MB
    ushort* wt_t    = (ushort*)alloc((size_t)9 * 512 * 512 * 2);        // 4.7 MB
    float*  wt_ex   = (float*)alloc((size_t)9 * 512 * 512 * 4);         // 9.4 MB
    ushort* xab     = (ushort*)alloc((size_t)HW_ * 512 * 2);            // 41 MB
    float*  xpart   = (float*)alloc((size_t)KSPLIT * PXCAP * 512 * 4);  // 33.6 MB
    float*  xex     = (float*)alloc((size_t)PXCAP * 512 * 4);           // 8.4 MB
    float*  scores  = (float*)alloc((size_t)NANCH * 4);                 // 1.44 MB
    float*  scores_ex = (float*)alloc((size_t)PXCAP * 9 * 4);
    // contiguous zero region: hist1, hist2, meta, meta_ex, flags
    unsigned* hist1   = (unsigned*)alloc(65536 * 4);
    unsigned* hist2   = (unsigned*)alloc(65536 * 4);
    unsigned* meta    = (unsigned*)alloc(64 * 4);
    unsigned* meta_ex = (unsigned*)alloc(64 * 4);
    unsigned* flags   = (unsigned*)alloc((size_t)HW_ * 4);
    unsigned* px_list = (unsigned*)alloc(PXCAP * 4);
    unsigned* sel_bits = (unsigned*)alloc(1024 * 4);
    unsigned* sel_idx  = (unsigned*)alloc(1024 * 4);
    unsigned* eq_idx   = (unsigned*)alloc(65536 * 4);
    unsigned* top_idx  = (unsigned*)alloc(KPRE * 4);
    float* top_sc      = (float*)alloc(KPRE * 4);
    float* props       = (float*)alloc(KPRE * 4 * 4);
    float* areas       = (float*)alloc(KPRE * 4);
    unsigned long long* mask = (unsigned long long*)alloc((size_t)KPRE * 16 * 8);
    (void)ws_size; (void)in_sizes; (void)n_in; (void)out_size;

    // 0) prep: zero feat_t+feat_px (adjacent) + radix region; build layouts
    int bigDw = (int)(((size_t)FT * FT * 512 * 2 + (size_t)FP * FP * 512 * 4) / 4);
    k_zero_u32<<<(bigDw + 255) / 256, 256, 0, stream>>>((unsigned*)feat_t, bigDw);
    int zrDw = 65536 * 2 + 64 + 64 + HW_;
    k_zero_u32<<<(zrDw + 255) / 256, 256, 0, stream>>>(hist1, zrDw);
    k_feat_t<<<dim3(7, 25, 16), 256, 0, stream>>>(feat, feat_t);
    k_feat_px<<<dim3(7, 25, 16), 256, 0, stream>>>(feat, feat_px);
    k_wt_t<<<(9 * 512 * 512 + 255) / 256, 256, 0, stream>>>(conv_w, wt_t);
    k_wt_ex<<<dim3(144, 16), dim3(32, 8), 0, stream>>>(conv_w, wt_ex);
    // 1) approx conv (bf16 MFMA, 64co x 16x16px tiles) + approx cls
    k_conv3_mfma<<<8 * 169, 256, 0, stream>>>(feat_t, wt_t, conv_b, xab);
    k_cls<<<HW_ / 64, 256, 0, stream>>>(xab, cls_w, cls_b, scores);
    // 2) candidate pixels: approx top-KSEL bucket threshold (LDS hist)
    k_hist1_lds<<<256, 256, 0, stream>>>(scores, hist1);
    k_find_thr<<<1, 1024, 0, stream>>>(hist1, meta, 0, KSEL);
    k_collect_cand<<<(NANCH + 255) / 256, 256, 0, stream>>>(scores, meta, flags);
    k_px_compact<<<(HW_ + 255) / 256, 256, 0, stream>>>(flags, meta, px_list);
    // 3) exact fp32 conv at candidates: direct-staged K-split GEMM -> reduce
    k_zero_u32<<<(65536 * 2 + 255) / 256, 256, 0, stream>>>(hist1, 65536 * 2);
    k_exact_gemm<<<dim3(PXCAP / 64, 4, KSPLIT), 256, 0, stream>>>(feat_px, wt_ex, meta, px_list, xpart);
    k_exact_reduce<<<PXCAP * 512 / 256, 256, 0, stream>>>(xpart, conv_b, meta, xex);
    k_exact_scores<<<PXCAP, 64, 0, stream>>>(xex, cls_w, cls_b, meta, scores_ex);
    // 4) exact stable top-1000 among candidate anchors (global indices)
    k_hist1_ex_lds<<<32, 256, 0, stream>>>(scores_ex, meta, hist1);
    k_find_thr<<<1, 1024, 0, stream>>>(hist1, meta_ex, 0, KPRE);
    k_hist2_ex<<<(PXCAP * 9 + 255) / 256, 256, 0, stream>>>(scores_ex, meta, meta_ex, hist2);
    k_find_thr<<<1, 1024, 0, stream>>>(hist2, meta_ex, 1, KPRE);
    k_collect_ex<<<(PXCAP * 9 + 255) / 256, 256, 0, stream>>>(scores_ex, meta, meta_ex, px_list,
                                                              sel_bits, sel_idx, eq_idx);
    k_topk_final<<<1, 1024, 0, stream>>>(sel_bits, sel_idx, eq_idx, meta_ex, top_idx, top_sc);
    // 5) exact decode + NMS
    k_decode<<<KPRE, 64, 0, stream>>>(xex, flags, reg_w, reg_b, top_idx, props, areas);
    k_nms_mask<<<KPRE, 256, 0, stream>>>(props, areas, mask, out);
    k_nms_scan_out<<<1, 64, 0, stream>>>(mask, props, top_sc, out);
}

// Round 7
// 874.622 us; speedup vs baseline: 7.9997x; 1.3247x over previous
//
#include <hip/hip_runtime.h>
#include <stdint.h>

// Problem constants
static constexpr int H_ = 200, W_ = 200, HW_ = 40000;
static constexpr int C_ = 512;
static constexpr int NANCH = 360000;   // HW_ * 9
static constexpr int KPRE = 1000;
static constexpr int KPOST = 100;
static constexpr int KSEL = 1400;      // approx candidate margin (top-1000 + 400)
static constexpr int PXCAP = 4096;     // candidate pixel cap (est npx ~1600)
static constexpr int KSPLIT = 4;       // exact-gemm K split (4608 = 4 x 1152)
// feat_t padded dims: [212 y][212 x][512 ci] bf16, real (y,x) at (y+1,x+1)
static constexpr int FT = 212;
// feat_px padded dims: [202][202][512] fp32, real (y,x) at (y+1,x+1)
static constexpr int FP = 202;

typedef __attribute__((ext_vector_type(8))) short bf16x8;
typedef __attribute__((ext_vector_type(4))) float f32x4;

__device__ inline ushort f2bf(float f) {               // RNE float->bf16 bits
    unsigned u = __float_as_uint(f);
    u += 0x7FFFu + ((u >> 16) & 1u);
    return (ushort)(u >> 16);
}
__device__ inline float bf2f(ushort h) { return __uint_as_float(((unsigned)h) << 16); }

// ---------------------------------------------------------------------------
__global__ void k_zero_u32(unsigned* __restrict__ p, int n) {
    int i = blockIdx.x * 256 + threadIdx.x;
    if (i < n) p[i] = 0u;
}

// Border-only zeroing (interiors are fully overwritten by k_feat_t/k_feat_px).
// feat_t border: px with y notin [1,200] or x notin [1,200]: 12*212 + 200*12 = 4944 px.
__global__ void k_zero_border_t(ushort* __restrict__ feat_t) {
    int t = blockIdx.x * 256 + threadIdx.x;
    int total = 4944 * 64;           // 512 bf16 = 64 x uint4 per px
    if (t >= total) return;
    int px = t >> 6, part = t & 63;
    int y, x;
    if (px < 2544) { int ri = px / 212; x = px - ri * 212; y = (ri == 0) ? 0 : 200 + ri; }
    else { int q = px - 2544; int r12 = q / 12; int c = q - r12 * 12; y = 1 + r12; x = (c == 0) ? 0 : 200 + c; }
    uint4 z = {0u, 0u, 0u, 0u};
    *(uint4*)&feat_t[((size_t)y * FT + x) * 512 + part * 8] = z;
}

// feat_px border: 2*202 + 2*200 = 804 px.
__global__ void k_zero_border_px(float* __restrict__ feat_px) {
    int t = blockIdx.x * 256 + threadIdx.x;
    int total = 804 * 128;           // 512 f32 = 128 x float4 per px
    if (t >= total) return;
    int px = t >> 7, part = t & 127;
    int y, x;
    if (px < 202)      { y = 0;   x = px; }
    else if (px < 404) { y = 201; x = px - 202; }
    else if (px < 604) { x = 0;   y = 1 + (px - 404); }
    else               { x = 201; y = 1 + (px - 604); }
    float4 z = {0.f, 0.f, 0.f, 0.f};
    *(float4*)&feat_px[((size_t)y * FP + x) * 512 + part * 4] = z;
}

// ---------------------------------------------------------------------------
// feat [512][200][200] f32 -> feat_t [212][212][512] bf16 (zero-padded)
// ---------------------------------------------------------------------------
__global__ void k_feat_t(const float* __restrict__ feat, ushort* __restrict__ feat_t) {
    __shared__ ushort lt[32 * 8 * 33];
    int x0 = blockIdx.x * 32, y0 = blockIdx.y * 8, ci0 = blockIdx.z * 32;
    int tid = threadIdx.x;
    for (int u = tid; u < 8192; u += 256) {
        int ciL = u >> 8, rem = u & 255;
        int yy = rem >> 5, xx = rem & 31;
        int x = x0 + xx;
        float v = (x < W_) ? feat[(size_t)(ci0 + ciL) * HW_ + (y0 + yy) * W_ + x] : 0.f;
        lt[(ciL * 8 + yy) * 33 + xx] = f2bf(v);
    }
    __syncthreads();
    for (int u = tid; u < 1024; u += 256) {
        int pxu = u >> 2, part = u & 3;
        int yy = pxu >> 5, xx = pxu & 31;
        if (x0 + xx >= W_) continue;
        ushort tmp[8];
#pragma unroll
        for (int k = 0; k < 8; ++k) tmp[k] = lt[((part * 8 + k) * 8 + yy) * 33 + xx];
        *(uint4*)&feat_t[((size_t)(y0 + yy + 1) * FT + (x0 + xx + 1)) * 512 + ci0 + part * 8] =
            *(const uint4*)&tmp[0];
    }
}

// feat -> feat_px [202][202][512] fp32 (zero-padded)
__global__ void k_feat_px(const float* __restrict__ feat, float* __restrict__ feat_px) {
    __shared__ float lt[32 * 8 * 33];
    int x0 = blockIdx.x * 32, y0 = blockIdx.y * 8, ci0 = blockIdx.z * 32;
    int tid = threadIdx.x;
    for (int u = tid; u < 8192; u += 256) {
        int ciL = u >> 8, rem = u & 255;
        int yy = rem >> 5, xx = rem & 31;
        int x = x0 + xx;
        float v = (x < W_) ? feat[(size_t)(ci0 + ciL) * HW_ + (y0 + yy) * W_ + x] : 0.f;
        lt[(ciL * 8 + yy) * 33 + xx] = v;
    }
    __syncthreads();
    for (int u = tid; u < 1024; u += 256) {
        int pxu = u >> 2, part = u & 3;
        int yy = pxu >> 5, xx = pxu & 31;
        if (x0 + xx >= W_) continue;
        float tmp[8];
#pragma unroll
        for (int k = 0; k < 8; ++k) tmp[k] = lt[((part * 8 + k) * 8 + yy) * 33 + xx];
        float* dst = &feat_px[((size_t)(y0 + yy + 1) * FP + (x0 + xx + 1)) * 512 + ci0 + part * 8];
        *(float4*)&dst[0] = *(const float4*)&tmp[0];
        *(float4*)&dst[4] = *(const float4*)&tmp[4];
    }
}

// conv_w [co][ci][th][tw] f32 -> wt_t [tap9][co512][ci512] bf16
__global__ void k_wt_t(const float* __restrict__ conv_w, ushort* __restrict__ wt_t) {
    int i = blockIdx.x * 256 + threadIdx.x;
    if (i >= 9 * 512 * 512) return;
    int tap = i >> 18;
    int rem = i & 262143;
    int co = rem >> 9, ci = rem & 511;
    wt_t[i] = f2bf(conv_w[((size_t)co * 512 + ci) * 9 + tap]);
}

// conv_w -> wt_ex [k'=tap*512+ci][co512] fp32 (LDS 32x32 transpose)
__global__ void k_wt_ex(const float* __restrict__ conv_w, float* __restrict__ wt_ex) {
    __shared__ float t[32][33];
    int kb = blockIdx.x * 32;   // k' base (4608/32 = 144), single tap per tile
    int cb = blockIdx.y * 32;
    int lx = threadIdx.x, ly = threadIdx.y;
    int tap = kb >> 9, ci0 = kb & 511;
    for (int r = ly; r < 32; r += 8)
        t[r][lx] = conv_w[((size_t)(cb + r) * 512 + ci0 + lx) * 9 + tap];
    __syncthreads();
    for (int r = ly; r < 32; r += 8)
        wt_ex[(size_t)(kb + r) * 512 + cb + lx] = t[lx][r];
}

// ---------------------------------------------------------------------------
// Approx conv v2: bf16 MFMA 16x16x32. Block = 64 co x (16x16 px), 4 waves.
// Per 32-ci chunk: stage halo[18][18][40] + ALL 9 taps wtile[9][64][40] once.
// ---------------------------------------------------------------------------
__global__ __launch_bounds__(256)
__attribute__((amdgpu_waves_per_eu(2, 4)))
void k_conv3_mfma(const ushort* __restrict__ feat_t, const ushort* __restrict__ wt_t,
                  const float* __restrict__ bias, ushort* __restrict__ xab) {
    __shared__ ushort halo[18 * 18 * 40];   // [r][c][32ci + pad8]  25.9 KB
    __shared__ ushort wtile[9 * 64 * 40];   // [tap][co][32ci+pad8] 46.1 KB
    int b = blockIdx.x;
    int cot = b / 169;
    int tile = b - cot * 169;
    int xt = tile % 13, yt = tile / 13;
    int x0 = xt * 16, y0 = yt * 16;
    int co0 = cot * 64;
    int tid = threadIdx.x;
    int lane = tid & 63, wid = tid >> 6;
    int l15 = lane & 15, l4 = lane >> 4;

    f32x4 acc[4][4];
#pragma unroll
    for (int i = 0; i < 4; ++i)
#pragma unroll
        for (int j = 0; j < 4; ++j) acc[i][j] = (f32x4){0.f, 0.f, 0.f, 0.f};

    for (int ch = 0; ch < 16; ++ch) {
        int ci0 = ch * 32;
        __syncthreads();   // previous chunk's reads done
        for (int u = tid; u < 1296; u += 256) {
            int p = u >> 2, q = u & 3;
            int r = p / 18, c = p - r * 18;
            const ushort* src = feat_t + ((size_t)(y0 + r) * FT + (x0 + c)) * 512 + ci0 + q * 8;
            *(uint4*)&halo[(r * 18 + c) * 40 + q * 8] = *(const uint4*)src;
        }
        for (int u = tid; u < 2304; u += 256) {
            int row = u >> 2, q = u & 3;       // row = tap*64 + co
            int tap = row >> 6, co = row & 63;
            const ushort* src = wt_t + ((size_t)(tap * 512 + co0 + co)) * 512 + ci0 + q * 8;
            *(uint4*)&wtile[row * 40 + q * 8] = *(const uint4*)src;
        }
        __syncthreads();
#pragma unroll
        for (int tap = 0; tap < 9; ++tap) {
            int th = tap / 3, tw = tap - th * 3;
            bf16x8 af[4], bf[4];
#pragma unroll
            for (int pi = 0; pi < 4; ++pi)
                af[pi] = *(const bf16x8*)&halo[((wid * 4 + pi + th) * 18 + (l15 + tw)) * 40 + l4 * 8];
#pragma unroll
            for (int cj = 0; cj < 4; ++cj)
                bf[cj] = *(const bf16x8*)&wtile[(tap * 64 + cj * 16 + l15) * 40 + l4 * 8];
#pragma unroll
            for (int pi = 0; pi < 4; ++pi)
#pragma unroll
                for (int cj = 0; cj < 4; ++cj)
                    acc[pi][cj] = __builtin_amdgcn_mfma_f32_16x16x32_bf16(af[pi], bf[cj], acc[pi][cj], 0, 0, 0);
        }
    }

    float bv[4];
#pragma unroll
    for (int cj = 0; cj < 4; ++cj) bv[cj] = bias[co0 + cj * 16 + l15];
#pragma unroll
    for (int pi = 0; pi < 4; ++pi) {
        int yy = y0 + wid * 4 + pi;
        if (yy >= H_) continue;
#pragma unroll
        for (int cj = 0; cj < 4; ++cj) {
            int co = co0 + cj * 16 + l15;
#pragma unroll
            for (int r = 0; r < 4; ++r) {
                int xx = x0 + l4 * 4 + r;
                if (xx < W_) {
                    float v = acc[pi][cj][r] + bv[cj];
                    xab[((size_t)(yy * W_ + xx)) * 512 + co] = f2bf(v > 0.f ? v : 0.f);
                }
            }
        }
    }
}

// ---------------------------------------------------------------------------
// Approx cls: scores[px*9+a] = sigmoid(dot(xab row, cls_w[a]) + b). Wave/px.
// ---------------------------------------------------------------------------
__global__ void k_cls(const ushort* __restrict__ xab, const float* __restrict__ cls_w,
                      const float* __restrict__ cls_b, float* __restrict__ scores) {
    __shared__ float wl[9 * 512];
    int tid = threadIdx.x;
    for (int t = tid; t < 4608; t += 256) wl[t] = cls_w[t];
    __syncthreads();
    int l = tid & 63, w = tid >> 6;
    int pbase = blockIdx.x * 64 + w * 16;
    for (int u = 0; u < 16; ++u) {
        int px = pbase + u;
        float xv[8];
#pragma unroll
        for (int k = 0; k < 8; ++k) xv[k] = bf2f(xab[(size_t)px * 512 + k * 64 + l]);
#pragma unroll
        for (int a = 0; a < 9; ++a) {
            float s = 0.f;
#pragma unroll
            for (int k = 0; k < 8; ++k) s = fmaf(xv[k], wl[a * 512 + k * 64 + l], s);
#pragma unroll
            for (int o = 32; o > 0; o >>= 1) s += __shfl_down(s, o);
            if (l == 0) scores[(size_t)px * 9 + a] = 1.f / (1.f + expf(-(s + cls_b[a])));
        }
    }
}

// ---------------------------------------------------------------------------
// Radix-select helpers
// meta: [0]=P [1]=cntAboveP [2]=T [3]=cntGtT [4]=need [8]=atomGt [9]=atomEq [10]=npx
// ---------------------------------------------------------------------------
__global__ void k_hist1_lds(const float* __restrict__ scores, unsigned* __restrict__ hist) {
    __shared__ unsigned h[16384];
    int tid = threadIdx.x;
    for (int j = tid; j < 16384; j += 256) h[j] = 0u;
    __syncthreads();
    int stride = gridDim.x * 256;
    for (int i = blockIdx.x * 256 + tid; i < NANCH; i += stride)
        atomicAdd(&h[(__float_as_uint(scores[i]) >> 16) & 16383], 1u);
    __syncthreads();
    for (int j = tid; j < 16384; j += 256) {
        unsigned v = h[j];
        if (v) atomicAdd(&hist[j], v);
    }
}

__global__ void k_find_thr(const unsigned* __restrict__ hist, unsigned* __restrict__ meta,
                           int mode, int Kwant) {
    __shared__ unsigned csum[1024];
    int t = threadIdx.x;
    unsigned base = (mode == 0) ? 0u : meta[1];
    unsigned s = 0;
    for (int b = 0; b < 64; ++b) s += hist[t * 64 + b];
    csum[t] = s;
    __syncthreads();
    for (int off = 1; off < 1024; off <<= 1) {
        unsigned add = (t + off < 1024) ? csum[t + off] : 0u;
        __syncthreads();
        csum[t] += add;
        __syncthreads();
    }
    unsigned run = base + ((t < 1023) ? csum[t + 1] : 0u);
    for (int b = 63; b >= 0; --b) {
        unsigned h = hist[t * 64 + b];
        if (run < (unsigned)Kwant && run + h >= (unsigned)Kwant) {
            if (mode == 0) {
                meta[0] = (unsigned)(t * 64 + b);
                meta[1] = run;
            } else {
                meta[2] = (meta[0] << 16) | (unsigned)(t * 64 + b);
                meta[3] = run;
                meta[4] = (unsigned)Kwant - run;
            }
            break;
        }
        run += h;
    }
}

// mark candidate pixels: anchors with hi16(score) >= P
__global__ void k_collect_cand(const float* __restrict__ scores, const unsigned* __restrict__ meta,
                               unsigned* __restrict__ flags) {
    int i = blockIdx.x * 256 + threadIdx.x;
    if (i >= NANCH) return;
    if ((__float_as_uint(scores[i]) >> 16) >= meta[0]) flags[i / 9] = 1u;
}

__global__ void k_px_compact(unsigned* __restrict__ flags, unsigned* __restrict__ meta,
                             unsigned* __restrict__ px_list) {
    int px = blockIdx.x * 256 + threadIdx.x;
    if (px >= HW_) return;
    if (flags[px]) {
        unsigned s = atomicAdd(&meta[10], 1u);
        if (s < (unsigned)PXCAP) { px_list[s] = (unsigned)px; flags[px] = s + 1u; }
        else flags[px] = 0u;
    }
}

// ---------------------------------------------------------------------------
// Exact fp32 conv GEMM v3: C[128co x 64px], K' = tap*512+ci (tap-major),
// K-split x4 -> xpart[kz]. B staged DIRECTLY from feat_px.
// ---------------------------------------------------------------------------
__global__ __attribute__((amdgpu_waves_per_eu(2, 4)))
void k_exact_gemm(const float* __restrict__ feat_px, const float* __restrict__ wt_ex,
                  const unsigned* __restrict__ meta, const unsigned* __restrict__ px_list,
                  float* __restrict__ xpart) {
    int npx = (int)meta[10]; if (npx > PXCAP) npx = PXCAP;
    int pb = blockIdx.x;
    if (pb * 64 >= npx) return;
    int cot = blockIdx.y;
    int kz = blockIdx.z;
    __shared__ float A[32][132];
    __shared__ float B[32][68];
    __shared__ int plist[64];
    int tid = threadIdx.x;
    int co0 = cot * 128;
    if (tid < 64) {
        int slot = pb * 64 + tid;
        plist[tid] = (slot < npx) ? (int)px_list[slot] : (int)px_list[0];
    }
    int tcog = tid >> 4;   // 8 co each
    int tpxg = tid & 15;   // 4 px each
    float acc[8][4];
#pragma unroll
    for (int i = 0; i < 8; ++i)
#pragma unroll
        for (int j = 0; j < 4; ++j) acc[i][j] = 0.f;
    int kbase = kz * 1152;
    for (int kc = 0; kc < 36; ++kc) {
        int k0 = kbase + kc * 32;
        int tap = k0 >> 9, ci0c = k0 & 511;
        int th = tap / 3, tw = tap - th * 3;
        __syncthreads();
        for (int u = tid; u < 1024; u += 256) {          // A: 32k x 128co from wt_ex
            int k = u >> 5, cp = (u & 31) * 4;
            float4 v = *(const float4*)&wt_ex[(size_t)(k0 + k) * 512 + co0 + cp];
            *(float4*)&A[k][cp] = v;
        }
        for (int u = tid; u < 512; u += 256) {           // B: 64px x 32ci from feat_px
            int s = u >> 3, part = u & 7;
            int px = plist[s];
            int y = px / W_, x = px - y * W_;
            float4 v = *(const float4*)&feat_px[((size_t)(y + th) * FP + (x + tw)) * 512 + ci0c + part * 4];
            B[part * 4 + 0][s] = v.x; B[part * 4 + 1][s] = v.y;
            B[part * 4 + 2][s] = v.z; B[part * 4 + 3][s] = v.w;
        }
        __syncthreads();
#pragma unroll 4
        for (int k = 0; k < 32; ++k) {
            float wv[8], pv[4];
            *(float4*)&wv[0] = *(const float4*)&A[k][tcog * 8];
            *(float4*)&wv[4] = *(const float4*)&A[k][tcog * 8 + 4];
            *(float4*)&pv[0] = *(const float4*)&B[k][tpxg * 4];
#pragma unroll
            for (int i = 0; i < 8; ++i)
#pragma unroll
                for (int j = 0; j < 4; ++j) acc[i][j] = fmaf(wv[i], pv[j], acc[i][j]);
        }
    }
#pragma unroll
    for (int j = 0; j < 4; ++j) {
        int slot = pb * 64 + tpxg * 4 + j;
        if (slot >= npx) continue;
#pragma unroll
        for (int i = 0; i < 8; ++i) {
            int co = co0 + tcog * 8 + i;
            xpart[((size_t)kz * PXCAP + slot) * 512 + co] = acc[i][j];
        }
    }
}

// fixed-order reduce of K-split partials + bias + relu -> xex
__global__ void k_exact_reduce(const float* __restrict__ xpart, const float* __restrict__ bias,
                               const unsigned* __restrict__ meta, float* __restrict__ xex) {
    int npx = (int)meta[10]; if (npx > PXCAP) npx = PXCAP;
    int idx = blockIdx.x * 256 + threadIdx.x;
    int slot = idx >> 9, co = idx & 511;
    if (slot >= npx) return;
    float v = xpart[(size_t)slot * 512 + co];
    v += xpart[((size_t)PXCAP + slot) * 512 + co];
    v += xpart[((size_t)2 * PXCAP + slot) * 512 + co];
    v += xpart[((size_t)3 * PXCAP + slot) * 512 + co];
    v += bias[co];
    xex[(size_t)slot * 512 + co] = v > 0.f ? v : 0.f;
}

// exact scores for all 9 anchors of each candidate pixel
__global__ void k_exact_scores(const float* __restrict__ xex, const float* __restrict__ cls_w,
                               const float* __restrict__ cls_b, const unsigned* __restrict__ meta,
                               float* __restrict__ scores_ex) {
    int slot = blockIdx.x;
    int npx = (int)meta[10]; if (npx > PXCAP) npx = PXCAP;
    if (slot >= npx) return;
    int l = threadIdx.x;
    float xv[8];
#pragma unroll
    for (int k = 0; k < 8; ++k) xv[k] = xex[(size_t)slot * 512 + k * 64 + l];
#pragma unroll
    for (int a = 0; a < 9; ++a) {
        float s = 0.f;
#pragma unroll
        for (int k = 0; k < 8; ++k) s = fmaf(xv[k], cls_w[a * 512 + k * 64 + l], s);
#pragma unroll
        for (int o = 32; o > 0; o >>= 1) s += __shfl_down(s, o);
        if (l == 0) scores_ex[slot * 9 + a] = 1.f / (1.f + expf(-(s + cls_b[a])));
    }
}

__global__ void k_hist1_ex_lds(const float* __restrict__ scores_ex, const unsigned* __restrict__ meta,
                               unsigned* __restrict__ hist) {
    __shared__ unsigned h[16384];
    int npx = (int)meta[10]; if (npx > PXCAP) npx = PXCAP;
    int n = npx * 9;
    int tid = threadIdx.x;
    for (int j = tid; j < 16384; j += 256) h[j] = 0u;
    __syncthreads();
    for (int i = blockIdx.x * 256 + tid; i < n; i += 32 * 256)
        atomicAdd(&h[(__float_as_uint(scores_ex[i]) >> 16) & 16383], 1u);
    __syncthreads();
    for (int j = tid; j < 16384; j += 256) {
        unsigned v = h[j];
        if (v) atomicAdd(&hist[j], v);
    }
}

__global__ void k_hist2_ex(const float* __restrict__ scores_ex, const unsigned* __restrict__ meta,
                           const unsigned* __restrict__ meta_ex, unsigned* __restrict__ hist2) {
    int npx = (int)meta[10]; if (npx > PXCAP) npx = PXCAP;
    int i = blockIdx.x * 256 + threadIdx.x;
    if (i >= npx * 9) return;
    unsigned b = __float_as_uint(scores_ex[i]);
    if ((b >> 16) == meta_ex[0]) atomicAdd(&hist2[b & 0xFFFFu], 1u);
}

__global__ void k_collect_ex(const float* __restrict__ scores_ex, const unsigned* __restrict__ meta,
                             unsigned* __restrict__ meta_ex, const unsigned* __restrict__ px_list,
                             unsigned* __restrict__ sel_bits, unsigned* __restrict__ sel_idx,
                             unsigned* __restrict__ eq_idx) {
    int npx = (int)meta[10]; if (npx > PXCAP) npx = PXCAP;
    int i = blockIdx.x * 256 + threadIdx.x;
    if (i >= npx * 9) return;
    unsigned b = __float_as_uint(scores_ex[i]);
    unsigned T = meta_ex[2];
    unsigned g = px_list[i / 9] * 9u + (unsigned)(i % 9);
    if (b > T) {
        unsigned s = atomicAdd(&meta_ex[8], 1u);
        if (s < 1024u) { sel_bits[s] = b; sel_idx[s] = g; }
    } else if (b == T) {
        unsigned s = atomicAdd(&meta_ex[9], 1u);
        if (s < 65536u) eq_idx[s] = g;
    }
}

// exact stable top-1000 (ties -> smallest global idx), bitonic final order
__global__ void k_topk_final(const unsigned* __restrict__ sel_bits, const unsigned* __restrict__ sel_idx,
                             const unsigned* __restrict__ eq_idx, const unsigned* __restrict__ meta,
                             unsigned* __restrict__ top_idx, float* __restrict__ top_sc) {
    __shared__ uint64_t keys[1024];
    __shared__ int lcnt;
    __shared__ int lred;
    int t = threadIdx.x;
    unsigned cntGt = meta[3];
    unsigned need = meta[4];
    unsigned cntEq = meta[9];
    unsigned T = meta[2];

    unsigned idx_cut = 0xFFFFFFFFu;
    if (cntEq > need) {
        unsigned lo = 0, hi = NANCH - 1;
        while (lo < hi) {
            unsigned mid = (lo + hi) >> 1;
            int c = 0;
            for (unsigned e = t; e < cntEq; e += 1024)
                if (eq_idx[e] <= mid) c++;
            if (t == 0) lred = 0;
            __syncthreads();
            atomicAdd(&lred, c);
            __syncthreads();
            int tot = lred;
            __syncthreads();
            if ((unsigned)tot >= need) hi = mid; else lo = mid + 1;
        }
        idx_cut = lo;
    }

    keys[t] = 0ull;
    if (t == 0) lcnt = 0;
    __syncthreads();
    for (unsigned s = t; s < cntGt; s += 1024)
        keys[s] = ((uint64_t)sel_bits[s] << 32) | (uint64_t)(0xFFFFFFFFu - sel_idx[s]);
    for (unsigned e = t; e < cntEq; e += 1024) {
        unsigned ix = eq_idx[e];
        if (ix <= idx_cut) {
            int s2 = (int)cntGt + atomicAdd(&lcnt, 1);
            keys[s2] = ((uint64_t)T << 32) | (uint64_t)(0xFFFFFFFFu - ix);
        }
    }
    __syncthreads();
    for (int k = 2; k <= 1024; k <<= 1) {
        for (int j = k >> 1; j > 0; j >>= 1) {
            int ixj = t ^ j;
            if (ixj > t) {
                uint64_t a = keys[t], b = keys[ixj];
                bool desc = (t & k) == 0;
                if (desc ? (a < b) : (a > b)) { keys[t] = b; keys[ixj] = a; }
            }
            __syncthreads();
        }
    }
    if (t < KPRE) {
        top_sc[t] = __uint_as_float((unsigned)(keys[t] >> 32));
        top_idx[t] = 0xFFFFFFFFu - (unsigned)keys[t];
    }
}

// ---------------------------------------------------------------------------
// decode from exact x (via flags px->slot map)
// ---------------------------------------------------------------------------
__global__ void k_decode(const float* __restrict__ xex, const unsigned* __restrict__ flags,
                         const float* __restrict__ reg_w, const float* __restrict__ reg_b,
                         const unsigned* __restrict__ top_idx,
                         float* __restrict__ props, float* __restrict__ areas) {
    int j = blockIdx.x;
    int lane = threadIdx.x;  // 64
    unsigned idx = top_idx[j];
    int pix = (int)(idx / 9u);
    int a = (int)(idx - (unsigned)pix * 9u);
    int slot = (int)flags[pix] - 1;
    if (slot < 0) slot = 0;
    const float* xr = xex + (size_t)slot * 512;
    float s0 = 0, s1 = 0, s2 = 0, s3 = 0;
    for (int c = lane; c < C_; c += 64) {
        float xv = xr[c];
        s0 = fmaf(xv, reg_w[(a * 4 + 0) * C_ + c], s0);
        s1 = fmaf(xv, reg_w[(a * 4 + 1) * C_ + c], s1);
        s2 = fmaf(xv, reg_w[(a * 4 + 2) * C_ + c], s2);
        s3 = fmaf(xv, reg_w[(a * 4 + 3) * C_ + c], s3);
    }
#pragma unroll
    for (int o = 32; o > 0; o >>= 1) {
        s0 += __shfl_down(s0, o);
        s1 += __shfl_down(s1, o);
        s2 += __shfl_down(s2, o);
        s3 += __shfl_down(s3, o);
    }
    if (lane == 0) {
        float d0 = s0 + reg_b[a * 4 + 0];
        float d1 = s1 + reg_b[a * 4 + 1];
        float d2 = s2 + reg_b[a * 4 + 2];
        float d3 = s3 + reg_b[a * 4 + 3];
        int h = pix / W_, w2 = pix - h * W_;
        int rr = a / 3, ss = a - rr * 3;
        float ratio = (rr == 0) ? 0.5f : (rr == 1) ? 1.0f : 2.0f;
        float scale = (ss == 0) ? 128.f : (ss == 1) ? 256.f : 512.f;
        float hr = sqrtf(ratio);
        float wr = 1.0f / hr;
        float wsc = wr * scale, hsc = hr * scale;
        float sx = (float)w2 * 16.f, sy = (float)h * 16.f;
        float a0 = sx - wsc * 0.5f, a1 = sy - hsc * 0.5f;
        float a2 = sx + wsc * 0.5f, a3 = sy + hsc * 0.5f;
        float bw = a2 - a0, bh = a3 - a1;
        float cx = a0 + 0.5f * bw, cy = a1 + 0.5f * bh;
        float px = d0 * bw + cx, py = d1 * bh + cy;
        float pw = expf(d2) * bw, ph = expf(d3) * bh;
        float b0 = px - 0.5f * pw, b1 = py - 0.5f * ph;
        float b2 = px + 0.5f * pw, b3 = py + 0.5f * ph;
        b0 = fminf(fmaxf(b0, 0.f), 3200.f);
        b1 = fminf(fmaxf(b1, 0.f), 3200.f);
        b2 = fminf(fmaxf(b2, 0.f), 3200.f);
        b3 = fminf(fmaxf(b3, 0.f), 3200.f);
        props[j * 4 + 0] = b0;
        props[j * 4 + 1] = b1;
        props[j * 4 + 2] = b2;
        props[j * 4 + 3] = b3;
        areas[j] = (b2 - b0) * (b3 - b1);
    }
}

// ---------------------------------------------------------------------------
__global__ void k_nms_mask(const float* __restrict__ props, const float* __restrict__ areas,
                           unsigned long long* __restrict__ mask, float* __restrict__ out) {
    int i = blockIdx.x;
    int tid = threadIdx.x;  // 256
    if (i == 0) {
        for (int t = tid; t < KPOST * 5; t += 256) out[t] = 0.f;
    }
    float x1i = props[i * 4 + 0], y1i = props[i * 4 + 1];
    float x2i = props[i * 4 + 2], y2i = props[i * 4 + 3];
    float ai = areas[i];
#pragma unroll
    for (int k = 0; k < 4; ++k) {
        int j = k * 256 + tid;
        bool sup = false;
        if (j < KPRE && j > i) {
            float iw = fminf(x2i, props[j * 4 + 2]) - fmaxf(x1i, props[j * 4 + 0]);
            float ih = fminf(y2i, props[j * 4 + 3]) - fmaxf(y1i, props[j * 4 + 1]);
            iw = fmaxf(iw, 0.f);
            ih = fmaxf(ih, 0.f);
            float inter = iw * ih;
            float iou = inter / (ai + areas[j] - inter);
            sup = iou > 0.7f;
        }
        unsigned long long b = __ballot(sup);
        int word = k * 4 + (tid >> 6);
        if ((tid & 63) == 0) mask[(size_t)i * 16 + word] = b;
    }
}

// ---------------------------------------------------------------------------
// NMS scan v2: kept-box iteration with early exit at 100 kept.
// Lane 0 holds all 16 keep words in NAMED registers (no runtime indexing);
// skips suppressed boxes in bulk via ctz; applies a 128B mask row only for
// kept boxes (<=100 rows before exit -> ~100 L2 row reads on the chain).
// Exactness of early exit: box i's keep status depends only on j<i, and
// valid = arange(100) < sum(keep) is all-true once 100 are kept.
// ---------------------------------------------------------------------------
__global__ void k_nms_scan_out(const unsigned long long* __restrict__ mask,
                               const float* __restrict__ props, const float* __restrict__ top_sc,
                               float* __restrict__ out) {
    __shared__ int kidx[KPOST];
    __shared__ int nk;
    int lane = threadIdx.x;  // 64
    if (lane == 0) {
        unsigned long long k0 = ~0ull, k1 = ~0ull, k2 = ~0ull, k3 = ~0ull;
        unsigned long long k4 = ~0ull, k5 = ~0ull, k6 = ~0ull, k7 = ~0ull;
        unsigned long long k8 = ~0ull, k9 = ~0ull, k10 = ~0ull, k11 = ~0ull;
        unsigned long long k12 = ~0ull, k13 = ~0ull, k14 = ~0ull;
        unsigned long long k15 = (1ull << 40) - 1ull;   // 1000 bits total
        int kept = 0;
#define APPLY_ROW(ii) { const unsigned long long* row = &mask[(size_t)(ii) * 16];          \
        k0 &= ~row[0];  k1 &= ~row[1];  k2 &= ~row[2];  k3 &= ~row[3];                     \
        k4 &= ~row[4];  k5 &= ~row[5];  k6 &= ~row[6];  k7 &= ~row[7];                     \
        k8 &= ~row[8];  k9 &= ~row[9];  k10 &= ~row[10]; k11 &= ~row[11];                  \
        k12 &= ~row[12]; k13 &= ~row[13]; k14 &= ~row[14]; k15 &= ~row[15]; }
#define SCAN_WORD(w, kw) { \
        unsigned long long rem = kw; \
        while (rem) { \
            int b = __builtin_ctzll(rem); \
            kidx[kept++] = (w) * 64 + b; \
            if (kept == KPOST) goto done; \
            APPLY_ROW((w) * 64 + b); \
            rem &= kw; \
            rem &= (b >= 63) ? 0ull : ~((2ull << b) - 1ull); \
        } }
        SCAN_WORD(0, k0)  SCAN_WORD(1, k1)  SCAN_WORD(2, k2)  SCAN_WORD(3, k3)
        SCAN_WORD(4, k4)  SCAN_WORD(5, k5)  SCAN_WORD(6, k6)  SCAN_WORD(7, k7)
        SCAN_WORD(8, k8)  SCAN_WORD(9, k9)  SCAN_WORD(10, k10) SCAN_WORD(11, k11)
        SCAN_WORD(12, k12) SCAN_WORD(13, k13) SCAN_WORD(14, k14) SCAN_WORD(15, k15)
done:
        nk = kept;
#undef SCAN_WORD
#undef APPLY_ROW
    }
    __syncthreads();
    int n = nk;
    for (int t = lane; t < KPOST; t += 64) {
        if (t < n) {
            int i = kidx[t];
            out[t * 4 + 0] = props[i * 4 + 0];
            out[t * 4 + 1] = props[i * 4 + 1];
            out[t * 4 + 2] = props[i * 4 + 2];
            out[t * 4 + 3] = props[i * 4 + 3];
            out[KPOST * 4 + t] = top_sc[i];
        }
    }
}

// ---------------------------------------------------------------------------
extern "C" void kernel_launch(void* const* d_in, const int* in_sizes, int n_in,
                              void* d_out, int out_size, void* d_ws, size_t ws_size,
                              hipStream_t stream) {
    const float* feat   = (const float*)d_in[0];
    const float* conv_w = (const float*)d_in[1];
    const float* conv_b = (const float*)d_in[2];
    const float* cls_w  = (const float*)d_in[3];
    const float* cls_b  = (const float*)d_in[4];
    const float* reg_w  = (const float*)d_in[5];
    const float* reg_b  = (const float*)d_in[6];
    float* out = (float*)d_out;

    size_t off = 0;
    auto alloc = [&](size_t bytes) -> void* {
        off = (off + 255) & ~(size_t)255;
        void* p = (char*)d_ws + off;
        off += bytes;
        return p;
    };
    ushort* feat_t  = (ushort*)alloc((size_t)FT * FT * 512 * 2);        // 46.0 MB
    float*  feat_px = (float*)alloc((size_t)FP * FP * 512 * 4);         // 83.6 MB
    ushort* wt_t    = (ushort*)alloc((size_t)9 * 512 * 512 * 2);        // 4.7 MB
    float*  wt_ex   = (float*)alloc((size_t)9 * 512 * 512 * 4);         // 9.4 MB
    ushort* xab     = (ushort*)alloc((size_t)HW_ * 512 * 2);            // 41 MB
    float*  xpart   = (float*)alloc((size_t)KSPLIT * PXCAP * 512 * 4);  // 33.6 MB
    float*  xex     = (float*)alloc((size_t)PXCAP * 512 * 4);           // 8.4 MB
    float*  scores  = (float*)alloc((size_t)NANCH * 4);                 // 1.44 MB
    float*  scores_ex = (float*)alloc((size_t)PXCAP * 9 * 4);
    // contiguous zero region: hist1, hist2, meta, meta_ex, flags
    unsigned* hist1   = (unsigned*)alloc(65536 * 4);
    unsigned* hist2   = (unsigned*)alloc(65536 * 4);
    unsigned* meta    = (unsigned*)alloc(64 * 4);
    unsigned* meta_ex = (unsigned*)alloc(64 * 4);
    unsigned* flags   = (unsigned*)alloc((size_t)HW_ * 4);
    unsigned* px_list = (unsigned*)alloc(PXCAP * 4);
    unsigned* sel_bits = (unsigned*)alloc(1024 * 4);
    unsigned* sel_idx  = (unsigned*)alloc(1024 * 4);
    unsigned* eq_idx   = (unsigned*)alloc(65536 * 4);
    unsigned* top_idx  = (unsigned*)alloc(KPRE * 4);
    float* top_sc      = (float*)alloc(KPRE * 4);
    float* props       = (float*)alloc(KPRE * 4 * 4);
    float* areas       = (float*)alloc(KPRE * 4);
    unsigned long long* mask = (unsigned long long*)alloc((size_t)KPRE * 16 * 8);
    (void)ws_size; (void)in_sizes; (void)n_in; (void)out_size;

    // 0) prep: border-only zero of feat_t/feat_px + zero radix region; layouts
    k_zero_border_t<<<(4944 * 64 + 255) / 256, 256, 0, stream>>>(feat_t);
    k_zero_border_px<<<(804 * 128 + 255) / 256, 256, 0, stream>>>(feat_px);
    int zrDw = 65536 * 2 + 64 + 64 + HW_;
    k_zero_u32<<<(zrDw + 255) / 256, 256, 0, stream>>>(hist1, zrDw);
    k_feat_t<<<dim3(7, 25, 16), 256, 0, stream>>>(feat, feat_t);
    k_feat_px<<<dim3(7, 25, 16), 256, 0, stream>>>(feat, feat_px);
    k_wt_t<<<(9 * 512 * 512 + 255) / 256, 256, 0, stream>>>(conv_w, wt_t);
    k_wt_ex<<<dim3(144, 16), dim3(32, 8), 0, stream>>>(conv_w, wt_ex);
    // 1) approx conv (bf16 MFMA, 64co x 16x16px tiles) + approx cls
    k_conv3_mfma<<<8 * 169, 256, 0, stream>>>(feat_t, wt_t, conv_b, xab);
    k_cls<<<HW_ / 64, 256, 0, stream>>>(xab, cls_w, cls_b, scores);
    // 2) candidate pixels: approx top-KSEL bucket threshold (LDS hist)
    k_hist1_lds<<<64, 256, 0, stream>>>(scores, hist1);
    k_find_thr<<<1, 1024, 0, stream>>>(hist1, meta, 0, KSEL);
    k_collect_cand<<<(NANCH + 255) / 256, 256, 0, stream>>>(scores, meta, flags);
    k_px_compact<<<(HW_ + 255) / 256, 256, 0, stream>>>(flags, meta, px_list);
    // 3) exact fp32 conv at candidates: direct-staged K-split GEMM -> reduce
    k_zero_u32<<<(65536 * 2 + 255) / 256, 256, 0, stream>>>(hist1, 65536 * 2);
    k_exact_gemm<<<dim3(PXCAP / 64, 4, KSPLIT), 256, 0, stream>>>(feat_px, wt_ex, meta, px_list, xpart);
    k_exact_reduce<<<PXCAP * 512 / 256, 256, 0, stream>>>(xpart, conv_b, meta, xex);
    k_exact_scores<<<PXCAP, 64, 0, stream>>>(xex, cls_w, cls_b, meta, scores_ex);
    // 4) exact stable top-1000 among candidate anchors (global indices)
    k_hist1_ex_lds<<<32, 256, 0, stream>>>(scores_ex, meta, hist1);
    k_find_thr<<<1, 1024, 0, stream>>>(hist1, meta_ex, 0, KPRE);
    k_hist2_ex<<<(PXCAP * 9 + 255) / 256, 256, 0, stream>>>(scores_ex, meta, meta_ex, hist2);
    k_find_thr<<<1, 1024, 0, stream>>>(hist2, meta_ex, 1, KPRE);
    k_collect_ex<<<(PXCAP * 9 + 255) / 256, 256, 0, stream>>>(scores_ex, meta, meta_ex, px_list,
                                                              sel_bits, sel_idx, eq_idx);
    k_topk_final<<<1, 1024, 0, stream>>>(sel_bits, sel_idx, eq_idx, meta_ex, top_idx, top_sc);
    // 5) exact decode + NMS
    k_decode<<<KPRE, 64, 0, stream>>>(xex, flags, reg_w, reg_b, top_idx, props, areas);
    k_nms_mask<<<KPRE, 256, 0, stream>>>(props, areas, mask, out);
    k_nms_scan_out<<<1, 64, 0, stream>>>(mask, props, top_sc, out);
}

// Round 8
// 791.712 us; speedup vs baseline: 8.8374x; 1.1047x over previous
//
#include <hip/hip_runtime.h>
#include <stdint.h>

// Problem constants
static constexpr int H_ = 200, W_ = 200, HW_ = 40000;
static constexpr int C_ = 512;
static constexpr int NANCH = 360000;   // HW_ * 9
static constexpr int KPRE = 1000;
static constexpr int KPOST = 100;
static constexpr int KSEL = 1400;      // approx candidate margin (top-1000 + 400)
static constexpr int PXCAP = 4096;     // candidate pixel cap (est npx ~1600)
static constexpr int KSPLIT = 4;       // exact-gemm K split (4608 = 4 x 1152)
// feat_t padded dims: [212 y][212 x][512 ci] bf16, real (y,x) at (y+1,x+1)
static constexpr int FT = 212;
// feat_px padded dims: [202][202][512] fp32, real (y,x) at (y+1,x+1)
static constexpr int FP = 202;

typedef __attribute__((ext_vector_type(8))) short bf16x8;
typedef __attribute__((ext_vector_type(4))) float f32x4;

__device__ inline ushort f2bf(float f) {               // RNE float->bf16 bits
    unsigned u = __float_as_uint(f);
    u += 0x7FFFu + ((u >> 16) & 1u);
    return (ushort)(u >> 16);
}
__device__ inline float bf2f(ushort h) { return __uint_as_float(((unsigned)h) << 16); }

// async global->LDS 16B: per-lane global src, LDS dst = wave-uniform base + lane*16
// (CK amd_direct_load cast pattern: numeric reinterpret to AS(1)/AS(3))
typedef const __attribute__((address_space(1))) uint32_t gas_u32;
typedef __attribute__((address_space(3))) uint32_t las_u32;
__device__ __forceinline__ void gload_lds16(const void* g, void* l) {
    __builtin_amdgcn_global_load_lds((gas_u32*)(uintptr_t)g, (las_u32*)(uintptr_t)l, 16, 0, 0);
}

// ---------------------------------------------------------------------------
__global__ void k_zero_u32(unsigned* __restrict__ p, int n) {
    int i = blockIdx.x * 256 + threadIdx.x;
    if (i < n) p[i] = 0u;
}

// Border-only zeroing (interiors are fully overwritten by k_feat_t/k_feat_px).
__global__ void k_zero_border_t(ushort* __restrict__ feat_t) {
    int t = blockIdx.x * 256 + threadIdx.x;
    int total = 4944 * 64;           // 512 bf16 = 64 x uint4 per px
    if (t >= total) return;
    int px = t >> 6, part = t & 63;
    int y, x;
    if (px < 2544) { int ri = px / 212; x = px - ri * 212; y = (ri == 0) ? 0 : 200 + ri; }
    else { int q = px - 2544; int r12 = q / 12; int c = q - r12 * 12; y = 1 + r12; x = (c == 0) ? 0 : 200 + c; }
    uint4 z = {0u, 0u, 0u, 0u};
    *(uint4*)&feat_t[((size_t)y * FT + x) * 512 + part * 8] = z;
}

__global__ void k_zero_border_px(float* __restrict__ feat_px) {
    int t = blockIdx.x * 256 + threadIdx.x;
    int total = 804 * 128;           // 512 f32 = 128 x float4 per px
    if (t >= total) return;
    int px = t >> 7, part = t & 127;
    int y, x;
    if (px < 202)      { y = 0;   x = px; }
    else if (px < 404) { y = 201; x = px - 202; }
    else if (px < 604) { x = 0;   y = 1 + (px - 404); }
    else               { x = 201; y = 1 + (px - 604); }
    float4 z = {0.f, 0.f, 0.f, 0.f};
    *(float4*)&feat_px[((size_t)y * FP + x) * 512 + part * 4] = z;
}

// ---------------------------------------------------------------------------
// feat [512][200][200] f32 -> feat_t [212][212][512] bf16 (zero-padded)
// ---------------------------------------------------------------------------
__global__ void k_feat_t(const float* __restrict__ feat, ushort* __restrict__ feat_t) {
    __shared__ ushort lt[32 * 8 * 33];
    int x0 = blockIdx.x * 32, y0 = blockIdx.y * 8, ci0 = blockIdx.z * 32;
    int tid = threadIdx.x;
    for (int u = tid; u < 8192; u += 256) {
        int ciL = u >> 8, rem = u & 255;
        int yy = rem >> 5, xx = rem & 31;
        int x = x0 + xx;
        float v = (x < W_) ? feat[(size_t)(ci0 + ciL) * HW_ + (y0 + yy) * W_ + x] : 0.f;
        lt[(ciL * 8 + yy) * 33 + xx] = f2bf(v);
    }
    __syncthreads();
    for (int u = tid; u < 1024; u += 256) {
        int pxu = u >> 2, part = u & 3;
        int yy = pxu >> 5, xx = pxu & 31;
        if (x0 + xx >= W_) continue;
        ushort tmp[8];
#pragma unroll
        for (int k = 0; k < 8; ++k) tmp[k] = lt[((part * 8 + k) * 8 + yy) * 33 + xx];
        *(uint4*)&feat_t[((size_t)(y0 + yy + 1) * FT + (x0 + xx + 1)) * 512 + ci0 + part * 8] =
            *(const uint4*)&tmp[0];
    }
}

// feat -> feat_px [202][202][512] fp32 (zero-padded)
__global__ void k_feat_px(const float* __restrict__ feat, float* __restrict__ feat_px) {
    __shared__ float lt[32 * 8 * 33];
    int x0 = blockIdx.x * 32, y0 = blockIdx.y * 8, ci0 = blockIdx.z * 32;
    int tid = threadIdx.x;
    for (int u = tid; u < 8192; u += 256) {
        int ciL = u >> 8, rem = u & 255;
        int yy = rem >> 5, xx = rem & 31;
        int x = x0 + xx;
        float v = (x < W_) ? feat[(size_t)(ci0 + ciL) * HW_ + (y0 + yy) * W_ + x] : 0.f;
        lt[(ciL * 8 + yy) * 33 + xx] = v;
    }
    __syncthreads();
    for (int u = tid; u < 1024; u += 256) {
        int pxu = u >> 2, part = u & 3;
        int yy = pxu >> 5, xx = pxu & 31;
        if (x0 + xx >= W_) continue;
        float tmp[8];
#pragma unroll
        for (int k = 0; k < 8; ++k) tmp[k] = lt[((part * 8 + k) * 8 + yy) * 33 + xx];
        float* dst = &feat_px[((size_t)(y0 + yy + 1) * FP + (x0 + xx + 1)) * 512 + ci0 + part * 8];
        *(float4*)&dst[0] = *(const float4*)&tmp[0];
        *(float4*)&dst[4] = *(const float4*)&tmp[4];
    }
}

// conv_w [co][ci][th][tw] f32 -> wt_t [tap9][co512][ci512] bf16
__global__ void k_wt_t(const float* __restrict__ conv_w, ushort* __restrict__ wt_t) {
    int i = blockIdx.x * 256 + threadIdx.x;
    if (i >= 9 * 512 * 512) return;
    int tap = i >> 18;
    int rem = i & 262143;
    int co = rem >> 9, ci = rem & 511;
    wt_t[i] = f2bf(conv_w[((size_t)co * 512 + ci) * 9 + tap]);
}

// conv_w -> wt_ex [k'=tap*512+ci][co512] fp32 (LDS 32x32 transpose)
__global__ void k_wt_ex(const float* __restrict__ conv_w, float* __restrict__ wt_ex) {
    __shared__ float t[32][33];
    int kb = blockIdx.x * 32;   // k' base (4608/32 = 144), single tap per tile
    int cb = blockIdx.y * 32;
    int lx = threadIdx.x, ly = threadIdx.y;
    int tap = kb >> 9, ci0 = kb & 511;
    for (int r = ly; r < 32; r += 8)
        t[r][lx] = conv_w[((size_t)(cb + r) * 512 + ci0 + lx) * 9 + tap];
    __syncthreads();
    for (int r = ly; r < 32; r += 8)
        wt_ex[(size_t)(kb + r) * 512 + cb + lx] = t[lx][r];
}

// ---------------------------------------------------------------------------
// Approx conv v3: bf16 MFMA 16x16x32. Block = 64 co x (16x16 px), 4 waves.
// - XCD swizzle: cot = b&7 -> each XCD owns one 64-co slice (590 KB, L2-fit);
//   all XCDs sweep the same spatial tile concurrently (halo L3-hits).
// - Staging via global_load_lds width=16; LDS layout UNPADDED [..][32ci]
//   (dest must be linear in staging index, m104). Fragment reads are
//   conflict-free: 64 lanes read 64 distinct contiguous 16B of a 1KB span.
// - LDS 57.6 KB; loads queue in vmcnt, no VGPR round-trip.
// ---------------------------------------------------------------------------
__global__ __launch_bounds__(256)
__attribute__((amdgpu_waves_per_eu(2, 4)))
void k_conv3_mfma(const ushort* __restrict__ feat_t, const ushort* __restrict__ wt_t,
                  const float* __restrict__ bias, ushort* __restrict__ xab) {
    __shared__ ushort halo[18 * 18 * 32];   // [r][c][32ci] 20.7 KB (linear)
    __shared__ ushort wtile[9 * 64 * 32];   // [tap][co][32ci] 36.9 KB (linear)
    int b = blockIdx.x;
    int cot = b & 7;            // XCD-aligned co-slice
    int tile = b >> 3;          // 0..168
    int xt = tile % 13, yt = tile / 13;
    int x0 = xt * 16, y0 = yt * 16;
    int co0 = cot * 64;
    int tid = threadIdx.x;
    int lane = tid & 63, wid = tid >> 6;
    int l15 = lane & 15, l4 = lane >> 4;

    f32x4 acc[4][4];
#pragma unroll
    for (int i = 0; i < 4; ++i)
#pragma unroll
        for (int j = 0; j < 4; ++j) acc[i][j] = (f32x4){0.f, 0.f, 0.f, 0.f};

    for (int ch = 0; ch < 16; ++ch) {
        int ci0 = ch * 32;
        __syncthreads();   // previous chunk's reads done
        // halo: 1296 units of 16B; unit u -> LDS byte offset u*16 (linear)
        for (int u = tid; u < 1296; u += 256) {
            int p = u >> 2, q = u & 3;
            int r = p / 18, c = p - r * 18;
            const ushort* src = feat_t + ((size_t)(y0 + r) * FT + (x0 + c)) * 512 + ci0 + q * 8;
            gload_lds16(src, &halo[(u & ~63) * 8]);
        }
        // weights: 2304 units of 16B; unit u -> LDS byte offset u*16 (linear)
        for (int u = tid; u < 2304; u += 256) {
            int row = u >> 2, q = u & 3;       // row = tap*64 + co
            int tap = row >> 6, co = row & 63;
            const ushort* src = wt_t + ((size_t)(tap * 512 + co0 + co)) * 512 + ci0 + q * 8;
            gload_lds16(src, &wtile[(u & ~63) * 8]);
        }
        __syncthreads();   // drains vmcnt (compiler inserts) -> LDS valid
#pragma unroll
        for (int tap = 0; tap < 9; ++tap) {
            int th = tap / 3, tw = tap - th * 3;
            bf16x8 af[4], bf[4];
#pragma unroll
            for (int pi = 0; pi < 4; ++pi)
                af[pi] = *(const bf16x8*)&halo[((wid * 4 + pi + th) * 18 + (l15 + tw)) * 32 + l4 * 8];
#pragma unroll
            for (int cj = 0; cj < 4; ++cj)
                bf[cj] = *(const bf16x8*)&wtile[(tap * 64 + cj * 16 + l15) * 32 + l4 * 8];
#pragma unroll
            for (int pi = 0; pi < 4; ++pi)
#pragma unroll
                for (int cj = 0; cj < 4; ++cj)
                    acc[pi][cj] = __builtin_amdgcn_mfma_f32_16x16x32_bf16(af[pi], bf[cj], acc[pi][cj], 0, 0, 0);
        }
    }

    float bv[4];
#pragma unroll
    for (int cj = 0; cj < 4; ++cj) bv[cj] = bias[co0 + cj * 16 + l15];
#pragma unroll
    for (int pi = 0; pi < 4; ++pi) {
        int yy = y0 + wid * 4 + pi;
        if (yy >= H_) continue;
#pragma unroll
        for (int cj = 0; cj < 4; ++cj) {
            int co = co0 + cj * 16 + l15;
#pragma unroll
            for (int r = 0; r < 4; ++r) {
                int xx = x0 + l4 * 4 + r;
                if (xx < W_) {
                    float v = acc[pi][cj][r] + bv[cj];
                    xab[((size_t)(yy * W_ + xx)) * 512 + co] = f2bf(v > 0.f ? v : 0.f);
                }
            }
        }
    }
}

// ---------------------------------------------------------------------------
// Approx cls: scores[px*9+a] = sigmoid(dot(xab row, cls_w[a]) + b). Wave/px.
// ---------------------------------------------------------------------------
__global__ void k_cls(const ushort* __restrict__ xab, const float* __restrict__ cls_w,
                      const float* __restrict__ cls_b, float* __restrict__ scores) {
    __shared__ float wl[9 * 512];
    int tid = threadIdx.x;
    for (int t = tid; t < 4608; t += 256) wl[t] = cls_w[t];
    __syncthreads();
    int l = tid & 63, w = tid >> 6;
    int pbase = blockIdx.x * 64 + w * 16;
    for (int u = 0; u < 16; ++u) {
        int px = pbase + u;
        float xv[8];
#pragma unroll
        for (int k = 0; k < 8; ++k) xv[k] = bf2f(xab[(size_t)px * 512 + k * 64 + l]);
#pragma unroll
        for (int a = 0; a < 9; ++a) {
            float s = 0.f;
#pragma unroll
            for (int k = 0; k < 8; ++k) s = fmaf(xv[k], wl[a * 512 + k * 64 + l], s);
#pragma unroll
            for (int o = 32; o > 0; o >>= 1) s += __shfl_down(s, o);
            if (l == 0) scores[(size_t)px * 9 + a] = 1.f / (1.f + expf(-(s + cls_b[a])));
        }
    }
}

// ---------------------------------------------------------------------------
// Radix-select helpers
// meta: [0]=P [1]=cntAboveP [2]=T [3]=cntGtT [4]=need [8]=atomGt [9]=atomEq [10]=npx
// ---------------------------------------------------------------------------
__global__ void k_hist1_lds(const float* __restrict__ scores, unsigned* __restrict__ hist) {
    __shared__ unsigned h[16384];
    int tid = threadIdx.x;
    for (int j = tid; j < 16384; j += 256) h[j] = 0u;
    __syncthreads();
    int stride = gridDim.x * 256;
    for (int i = blockIdx.x * 256 + tid; i < NANCH; i += stride)
        atomicAdd(&h[(__float_as_uint(scores[i]) >> 16) & 16383], 1u);
    __syncthreads();
    for (int j = tid; j < 16384; j += 256) {
        unsigned v = h[j];
        if (v) atomicAdd(&hist[j], v);
    }
}

__global__ void k_find_thr(const unsigned* __restrict__ hist, unsigned* __restrict__ meta,
                           int mode, int Kwant) {
    __shared__ unsigned csum[1024];
    int t = threadIdx.x;
    unsigned base = (mode == 0) ? 0u : meta[1];
    unsigned s = 0;
    for (int b = 0; b < 64; ++b) s += hist[t * 64 + b];
    csum[t] = s;
    __syncthreads();
    for (int off = 1; off < 1024; off <<= 1) {
        unsigned add = (t + off < 1024) ? csum[t + off] : 0u;
        __syncthreads();
        csum[t] += add;
        __syncthreads();
    }
    unsigned run = base + ((t < 1023) ? csum[t + 1] : 0u);
    for (int b = 63; b >= 0; --b) {
        unsigned h = hist[t * 64 + b];
        if (run < (unsigned)Kwant && run + h >= (unsigned)Kwant) {
            if (mode == 0) {
                meta[0] = (unsigned)(t * 64 + b);
                meta[1] = run;
            } else {
                meta[2] = (meta[0] << 16) | (unsigned)(t * 64 + b);
                meta[3] = run;
                meta[4] = (unsigned)Kwant - run;
            }
            break;
        }
        run += h;
    }
}

// mark candidate pixels: anchors with hi16(score) >= P
__global__ void k_collect_cand(const float* __restrict__ scores, const unsigned* __restrict__ meta,
                               unsigned* __restrict__ flags) {
    int i = blockIdx.x * 256 + threadIdx.x;
    if (i >= NANCH) return;
    if ((__float_as_uint(scores[i]) >> 16) >= meta[0]) flags[i / 9] = 1u;
}

__global__ void k_px_compact(unsigned* __restrict__ flags, unsigned* __restrict__ meta,
                             unsigned* __restrict__ px_list) {
    int px = blockIdx.x * 256 + threadIdx.x;
    if (px >= HW_) return;
    if (flags[px]) {
        unsigned s = atomicAdd(&meta[10], 1u);
        if (s < (unsigned)PXCAP) { px_list[s] = (unsigned)px; flags[px] = s + 1u; }
        else flags[px] = 0u;
    }
}

// ---------------------------------------------------------------------------
// Exact fp32 conv GEMM v3: C[128co x 64px], K' = tap*512+ci (tap-major),
// K-split x4 -> xpart[kz]. B staged DIRECTLY from feat_px.
// ---------------------------------------------------------------------------
__global__ __attribute__((amdgpu_waves_per_eu(2, 4)))
void k_exact_gemm(const float* __restrict__ feat_px, const float* __restrict__ wt_ex,
                  const unsigned* __restrict__ meta, const unsigned* __restrict__ px_list,
                  float* __restrict__ xpart) {
    int npx = (int)meta[10]; if (npx > PXCAP) npx = PXCAP;
    int pb = blockIdx.x;
    if (pb * 64 >= npx) return;
    int cot = blockIdx.y;
    int kz = blockIdx.z;
    __shared__ float A[32][132];
    __shared__ float B[32][68];
    __shared__ int plist[64];
    int tid = threadIdx.x;
    int co0 = cot * 128;
    if (tid < 64) {
        int slot = pb * 64 + tid;
        plist[tid] = (slot < npx) ? (int)px_list[slot] : (int)px_list[0];
    }
    int tcog = tid >> 4;   // 8 co each
    int tpxg = tid & 15;   // 4 px each
    float acc[8][4];
#pragma unroll
    for (int i = 0; i < 8; ++i)
#pragma unroll
        for (int j = 0; j < 4; ++j) acc[i][j] = 0.f;
    int kbase = kz * 1152;
    for (int kc = 0; kc < 36; ++kc) {
        int k0 = kbase + kc * 32;
        int tap = k0 >> 9, ci0c = k0 & 511;
        int th = tap / 3, tw = tap - th * 3;
        __syncthreads();
        for (int u = tid; u < 1024; u += 256) {          // A: 32k x 128co from wt_ex
            int k = u >> 5, cp = (u & 31) * 4;
            float4 v = *(const float4*)&wt_ex[(size_t)(k0 + k) * 512 + co0 + cp];
            *(float4*)&A[k][cp] = v;
        }
        for (int u = tid; u < 512; u += 256) {           // B: 64px x 32ci from feat_px
            int s = u >> 3, part = u & 7;
            int px = plist[s];
            int y = px / W_, x = px - y * W_;
            float4 v = *(const float4*)&feat_px[((size_t)(y + th) * FP + (x + tw)) * 512 + ci0c + part * 4];
            B[part * 4 + 0][s] = v.x; B[part * 4 + 1][s] = v.y;
            B[part * 4 + 2][s] = v.z; B[part * 4 + 3][s] = v.w;
        }
        __syncthreads();
#pragma unroll 4
        for (int k = 0; k < 32; ++k) {
            float wv[8], pv[4];
            *(float4*)&wv[0] = *(const float4*)&A[k][tcog * 8];
            *(float4*)&wv[4] = *(const float4*)&A[k][tcog * 8 + 4];
            *(float4*)&pv[0] = *(const float4*)&B[k][tpxg * 4];
#pragma unroll
            for (int i = 0; i < 8; ++i)
#pragma unroll
                for (int j = 0; j < 4; ++j) acc[i][j] = fmaf(wv[i], pv[j], acc[i][j]);
        }
    }
#pragma unroll
    for (int j = 0; j < 4; ++j) {
        int slot = pb * 64 + tpxg * 4 + j;
        if (slot >= npx) continue;
#pragma unroll
        for (int i = 0; i < 8; ++i) {
            int co = co0 + tcog * 8 + i;
            xpart[((size_t)kz * PXCAP + slot) * 512 + co] = acc[i][j];
        }
    }
}

// fixed-order reduce of K-split partials + bias + relu -> xex
__global__ void k_exact_reduce(const float* __restrict__ xpart, const float* __restrict__ bias,
                               const unsigned* __restrict__ meta, float* __restrict__ xex) {
    int npx = (int)meta[10]; if (npx > PXCAP) npx = PXCAP;
    int idx = blockIdx.x * 256 + threadIdx.x;
    int slot = idx >> 9, co = idx & 511;
    if (slot >= npx) return;
    float v = xpart[(size_t)slot * 512 + co];
    v += xpart[((size_t)PXCAP + slot) * 512 + co];
    v += xpart[((size_t)2 * PXCAP + slot) * 512 + co];
    v += xpart[((size_t)3 * PXCAP + slot) * 512 + co];
    v += bias[co];
    xex[(size_t)slot * 512 + co] = v > 0.f ? v : 0.f;
}

// exact scores for all 9 anchors of each candidate pixel
__global__ void k_exact_scores(const float* __restrict__ xex, const float* __restrict__ cls_w,
                               const float* __restrict__ cls_b, const unsigned* __restrict__ meta,
                               float* __restrict__ scores_ex) {
    int slot = blockIdx.x;
    int npx = (int)meta[10]; if (npx > PXCAP) npx = PXCAP;
    if (slot >= npx) return;
    int l = threadIdx.x;
    float xv[8];
#pragma unroll
    for (int k = 0; k < 8; ++k) xv[k] = xex[(size_t)slot * 512 + k * 64 + l];
#pragma unroll
    for (int a = 0; a < 9; ++a) {
        float s = 0.f;
#pragma unroll
        for (int k = 0; k < 8; ++k) s = fmaf(xv[k], cls_w[a * 512 + k * 64 + l], s);
#pragma unroll
        for (int o = 32; o > 0; o >>= 1) s += __shfl_down(s, o);
        if (l == 0) scores_ex[slot * 9 + a] = 1.f / (1.f + expf(-(s + cls_b[a])));
    }
}

__global__ void k_hist1_ex_lds(const float* __restrict__ scores_ex, const unsigned* __restrict__ meta,
                               unsigned* __restrict__ hist) {
    __shared__ unsigned h[16384];
    int npx = (int)meta[10]; if (npx > PXCAP) npx = PXCAP;
    int n = npx * 9;
    int tid = threadIdx.x;
    for (int j = tid; j < 16384; j += 256) h[j] = 0u;
    __syncthreads();
    for (int i = blockIdx.x * 256 + tid; i < n; i += 32 * 256)
        atomicAdd(&h[(__float_as_uint(scores_ex[i]) >> 16) & 16383], 1u);
    __syncthreads();
    for (int j = tid; j < 16384; j += 256) {
        unsigned v = h[j];
        if (v) atomicAdd(&hist[j], v);
    }
}

__global__ void k_hist2_ex(const float* __restrict__ scores_ex, const unsigned* __restrict__ meta,
                           const unsigned* __restrict__ meta_ex, unsigned* __restrict__ hist2) {
    int npx = (int)meta[10]; if (npx > PXCAP) npx = PXCAP;
    int i = blockIdx.x * 256 + threadIdx.x;
    if (i >= npx * 9) return;
    unsigned b = __float_as_uint(scores_ex[i]);
    if ((b >> 16) == meta_ex[0]) atomicAdd(&hist2[b & 0xFFFFu], 1u);
}

__global__ void k_collect_ex(const float* __restrict__ scores_ex, const unsigned* __restrict__ meta,
                             unsigned* __restrict__ meta_ex, const unsigned* __restrict__ px_list,
                             unsigned* __restrict__ sel_bits, unsigned* __restrict__ sel_idx,
                             unsigned* __restrict__ eq_idx) {
    int npx = (int)meta[10]; if (npx > PXCAP) npx = PXCAP;
    int i = blockIdx.x * 256 + threadIdx.x;
    if (i >= npx * 9) return;
    unsigned b = __float_as_uint(scores_ex[i]);
    unsigned T = meta_ex[2];
    unsigned g = px_list[i / 9] * 9u + (unsigned)(i % 9);
    if (b > T) {
        unsigned s = atomicAdd(&meta_ex[8], 1u);
        if (s < 1024u) { sel_bits[s] = b; sel_idx[s] = g; }
    } else if (b == T) {
        unsigned s = atomicAdd(&meta_ex[9], 1u);
        if (s < 65536u) eq_idx[s] = g;
    }
}

// exact stable top-1000 (ties -> smallest global idx), bitonic final order
__global__ void k_topk_final(const unsigned* __restrict__ sel_bits, const unsigned* __restrict__ sel_idx,
                             const unsigned* __restrict__ eq_idx, const unsigned* __restrict__ meta,
                             unsigned* __restrict__ top_idx, float* __restrict__ top_sc) {
    __shared__ uint64_t keys[1024];
    __shared__ int lcnt;
    __shared__ int lred;
    int t = threadIdx.x;
    unsigned cntGt = meta[3];
    unsigned need = meta[4];
    unsigned cntEq = meta[9];
    unsigned T = meta[2];

    unsigned idx_cut = 0xFFFFFFFFu;
    if (cntEq > need) {
        unsigned lo = 0, hi = NANCH - 1;
        while (lo < hi) {
            unsigned mid = (lo + hi) >> 1;
            int c = 0;
            for (unsigned e = t; e < cntEq; e += 1024)
                if (eq_idx[e] <= mid) c++;
            if (t == 0) lred = 0;
            __syncthreads();
            atomicAdd(&lred, c);
            __syncthreads();
            int tot = lred;
            __syncthreads();
            if ((unsigned)tot >= need) hi = mid; else lo = mid + 1;
        }
        idx_cut = lo;
    }

    keys[t] = 0ull;
    if (t == 0) lcnt = 0;
    __syncthreads();
    for (unsigned s = t; s < cntGt; s += 1024)
        keys[s] = ((uint64_t)sel_bits[s] << 32) | (uint64_t)(0xFFFFFFFFu - sel_idx[s]);
    for (unsigned e = t; e < cntEq; e += 1024) {
        unsigned ix = eq_idx[e];
        if (ix <= idx_cut) {
            int s2 = (int)cntGt + atomicAdd(&lcnt, 1);
            keys[s2] = ((uint64_t)T << 32) | (uint64_t)(0xFFFFFFFFu - ix);
        }
    }
    __syncthreads();
    for (int k = 2; k <= 1024; k <<= 1) {
        for (int j = k >> 1; j > 0; j >>= 1) {
            int ixj = t ^ j;
            if (ixj > t) {
                uint64_t a = keys[t], b = keys[ixj];
                bool desc = (t & k) == 0;
                if (desc ? (a < b) : (a > b)) { keys[t] = b; keys[ixj] = a; }
            }
            __syncthreads();
        }
    }
    if (t < KPRE) {
        top_sc[t] = __uint_as_float((unsigned)(keys[t] >> 32));
        top_idx[t] = 0xFFFFFFFFu - (unsigned)keys[t];
    }
}

// ---------------------------------------------------------------------------
// decode from exact x (via flags px->slot map)
// ---------------------------------------------------------------------------
__global__ void k_decode(const float* __restrict__ xex, const unsigned* __restrict__ flags,
                         const float* __restrict__ reg_w, const float* __restrict__ reg_b,
                         const unsigned* __restrict__ top_idx,
                         float* __restrict__ props, float* __restrict__ areas) {
    int j = blockIdx.x;
    int lane = threadIdx.x;  // 64
    unsigned idx = top_idx[j];
    int pix = (int)(idx / 9u);
    int a = (int)(idx - (unsigned)pix * 9u);
    int slot = (int)flags[pix] - 1;
    if (slot < 0) slot = 0;
    const float* xr = xex + (size_t)slot * 512;
    float s0 = 0, s1 = 0, s2 = 0, s3 = 0;
    for (int c = lane; c < C_; c += 64) {
        float xv = xr[c];
        s0 = fmaf(xv, reg_w[(a * 4 + 0) * C_ + c], s0);
        s1 = fmaf(xv, reg_w[(a * 4 + 1) * C_ + c], s1);
        s2 = fmaf(xv, reg_w[(a * 4 + 2) * C_ + c], s2);
        s3 = fmaf(xv, reg_w[(a * 4 + 3) * C_ + c], s3);
    }
#pragma unroll
    for (int o = 32; o > 0; o >>= 1) {
        s0 += __shfl_down(s0, o);
        s1 += __shfl_down(s1, o);
        s2 += __shfl_down(s2, o);
        s3 += __shfl_down(s3, o);
    }
    if (lane == 0) {
        float d0 = s0 + reg_b[a * 4 + 0];
        float d1 = s1 + reg_b[a * 4 + 1];
        float d2 = s2 + reg_b[a * 4 + 2];
        float d3 = s3 + reg_b[a * 4 + 3];
        int h = pix / W_, w2 = pix - h * W_;
        int rr = a / 3, ss = a - rr * 3;
        float ratio = (rr == 0) ? 0.5f : (rr == 1) ? 1.0f : 2.0f;
        float scale = (ss == 0) ? 128.f : (ss == 1) ? 256.f : 512.f;
        float hr = sqrtf(ratio);
        float wr = 1.0f / hr;
        float wsc = wr * scale, hsc = hr * scale;
        float sx = (float)w2 * 16.f, sy = (float)h * 16.f;
        float a0 = sx - wsc * 0.5f, a1 = sy - hsc * 0.5f;
        float a2 = sx + wsc * 0.5f, a3 = sy + hsc * 0.5f;
        float bw = a2 - a0, bh = a3 - a1;
        float cx = a0 + 0.5f * bw, cy = a1 + 0.5f * bh;
        float px = d0 * bw + cx, py = d1 * bh + cy;
        float pw = expf(d2) * bw, ph = expf(d3) * bh;
        float b0 = px - 0.5f * pw, b1 = py - 0.5f * ph;
        float b2 = px + 0.5f * pw, b3 = py + 0.5f * ph;
        b0 = fminf(fmaxf(b0, 0.f), 3200.f);
        b1 = fminf(fmaxf(b1, 0.f), 3200.f);
        b2 = fminf(fmaxf(b2, 0.f), 3200.f);
        b3 = fminf(fmaxf(b3, 0.f), 3200.f);
        props[j * 4 + 0] = b0;
        props[j * 4 + 1] = b1;
        props[j * 4 + 2] = b2;
        props[j * 4 + 3] = b3;
        areas[j] = (b2 - b0) * (b3 - b1);
    }
}

// ---------------------------------------------------------------------------
__global__ void k_nms_mask(const float* __restrict__ props, const float* __restrict__ areas,
                           unsigned long long* __restrict__ mask, float* __restrict__ out) {
    int i = blockIdx.x;
    int tid = threadIdx.x;  // 256
    if (i == 0) {
        for (int t = tid; t < KPOST * 5; t += 256) out[t] = 0.f;
    }
    float x1i = props[i * 4 + 0], y1i = props[i * 4 + 1];
    float x2i = props[i * 4 + 2], y2i = props[i * 4 + 3];
    float ai = areas[i];
#pragma unroll
    for (int k = 0; k < 4; ++k) {
        int j = k * 256 + tid;
        bool sup = false;
        if (j < KPRE && j > i) {
            float iw = fminf(x2i, props[j * 4 + 2]) - fmaxf(x1i, props[j * 4 + 0]);
            float ih = fminf(y2i, props[j * 4 + 3]) - fmaxf(y1i, props[j * 4 + 1]);
            iw = fmaxf(iw, 0.f);
            ih = fmaxf(ih, 0.f);
            float inter = iw * ih;
            float iou = inter / (ai + areas[j] - inter);
            sup = iou > 0.7f;
        }
        unsigned long long b = __ballot(sup);
        int word = k * 4 + (tid >> 6);
        if ((tid & 63) == 0) mask[(size_t)i * 16 + word] = b;
    }
}

// ---------------------------------------------------------------------------
// NMS scan v2: kept-box iteration with early exit at 100 kept.
// ---------------------------------------------------------------------------
__global__ void k_nms_scan_out(const unsigned long long* __restrict__ mask,
                               const float* __restrict__ props, const float* __restrict__ top_sc,
                               float* __restrict__ out) {
    __shared__ int kidx[KPOST];
    __shared__ int nk;
    int lane = threadIdx.x;  // 64
    if (lane == 0) {
        unsigned long long k0 = ~0ull, k1 = ~0ull, k2 = ~0ull, k3 = ~0ull;
        unsigned long long k4 = ~0ull, k5 = ~0ull, k6 = ~0ull, k7 = ~0ull;
        unsigned long long k8 = ~0ull, k9 = ~0ull, k10 = ~0ull, k11 = ~0ull;
        unsigned long long k12 = ~0ull, k13 = ~0ull, k14 = ~0ull;
        unsigned long long k15 = (1ull << 40) - 1ull;   // 1000 bits total
        int kept = 0;
#define APPLY_ROW(ii) { const unsigned long long* row = &mask[(size_t)(ii) * 16];          \
        k0 &= ~row[0];  k1 &= ~row[1];  k2 &= ~row[2];  k3 &= ~row[3];                     \
        k4 &= ~row[4];  k5 &= ~row[5];  k6 &= ~row[6];  k7 &= ~row[7];                     \
        k8 &= ~row[8];  k9 &= ~row[9];  k10 &= ~row[10]; k11 &= ~row[11];                  \
        k12 &= ~row[12]; k13 &= ~row[13]; k14 &= ~row[14]; k15 &= ~row[15]; }
#define SCAN_WORD(w, kw) { \
        unsigned long long rem = kw; \
        while (rem) { \
            int b = __builtin_ctzll(rem); \
            kidx[kept++] = (w) * 64 + b; \
            if (kept == KPOST) goto done; \
            APPLY_ROW((w) * 64 + b); \
            rem &= kw; \
            rem &= (b >= 63) ? 0ull : ~((2ull << b) - 1ull); \
        } }
        SCAN_WORD(0, k0)  SCAN_WORD(1, k1)  SCAN_WORD(2, k2)  SCAN_WORD(3, k3)
        SCAN_WORD(4, k4)  SCAN_WORD(5, k5)  SCAN_WORD(6, k6)  SCAN_WORD(7, k7)
        SCAN_WORD(8, k8)  SCAN_WORD(9, k9)  SCAN_WORD(10, k10) SCAN_WORD(11, k11)
        SCAN_WORD(12, k12) SCAN_WORD(13, k13) SCAN_WORD(14, k14) SCAN_WORD(15, k15)
done:
        nk = kept;
#undef SCAN_WORD
#undef APPLY_ROW
    }
    __syncthreads();
    int n = nk;
    for (int t = lane; t < KPOST; t += 64) {
        if (t < n) {
            int i = kidx[t];
            out[t * 4 + 0] = props[i * 4 + 0];
            out[t * 4 + 1] = props[i * 4 + 1];
            out[t * 4 + 2] = props[i * 4 + 2];
            out[t * 4 + 3] = props[i * 4 + 3];
            out[KPOST * 4 + t] = top_sc[i];
        }
    }
}

// ---------------------------------------------------------------------------
extern "C" void kernel_launch(void* const* d_in, const int* in_sizes, int n_in,
                              void* d_out, int out_size, void* d_ws, size_t ws_size,
                              hipStream_t stream) {
    const float* feat   = (const float*)d_in[0];
    const float* conv_w = (const float*)d_in[1];
    const float* conv_b = (const float*)d_in[2];
    const float* cls_w  = (const float*)d_in[3];
    const float* cls_b  = (const float*)d_in[4];
    const float* reg_w  = (const float*)d_in[5];
    const float* reg_b  = (const float*)d_in[6];
    float* out = (float*)d_out;

    size_t off = 0;
    auto alloc = [&](size_t bytes) -> void* {
        off = (off + 255) & ~(size_t)255;
        void* p = (char*)d_ws + off;
        off += bytes;
        return p;
    };
    ushort* feat_t  = (ushort*)alloc((size_t)FT * FT * 512 * 2);        // 46.0 MB
    float*  feat_px = (float*)alloc((size_t)FP * FP * 512 * 4);         // 83.6 MB
    ushort* wt_t    = (ushort*)alloc((size_t)9 * 512 * 512 * 2);        // 4.7 MB
    float*  wt_ex   = (float*)alloc((size_t)9 * 512 * 512 * 4);         // 9.4 MB
    ushort* xab     = (ushort*)alloc((size_t)HW_ * 512 * 2);            // 41 MB
    float*  xpart   = (float*)alloc((size_t)KSPLIT * PXCAP * 512 * 4);  // 33.6 MB
    float*  xex     = (float*)alloc((size_t)PXCAP * 512 * 4);           // 8.4 MB
    float*  scores  = (float*)alloc((size_t)NANCH * 4);                 // 1.44 MB
    float*  scores_ex = (float*)alloc((size_t)PXCAP * 9 * 4);
    // contiguous zero region: hist1, hist2, meta, meta_ex, flags
    unsigned* hist1   = (unsigned*)alloc(65536 * 4);
    unsigned* hist2   = (unsigned*)alloc(65536 * 4);
    unsigned* meta    = (unsigned*)alloc(64 * 4);
    unsigned* meta_ex = (unsigned*)alloc(64 * 4);
    unsigned* flags   = (unsigned*)alloc((size_t)HW_ * 4);
    unsigned* px_list = (unsigned*)alloc(PXCAP * 4);
    unsigned* sel_bits = (unsigned*)alloc(1024 * 4);
    unsigned* sel_idx  = (unsigned*)alloc(1024 * 4);
    unsigned* eq_idx   = (unsigned*)alloc(65536 * 4);
    unsigned* top_idx  = (unsigned*)alloc(KPRE * 4);
    float* top_sc      = (float*)alloc(KPRE * 4);
    float* props       = (float*)alloc(KPRE * 4 * 4);
    float* areas       = (float*)alloc(KPRE * 4);
    unsigned long long* mask = (unsigned long long*)alloc((size_t)KPRE * 16 * 8);
    (void)ws_size; (void)in_sizes; (void)n_in; (void)out_size;

    // 0) prep for APPROX path only (keep feat_t/wt_t L3-resident for conv:
    //    feat_px/wt_ex builds are deferred until after conv+cls)
    k_zero_border_t<<<(4944 * 64 + 255) / 256, 256, 0, stream>>>(feat_t);
    int zrDw = 65536 * 2 + 64 + 64 + HW_;
    k_zero_u32<<<(zrDw + 255) / 256, 256, 0, stream>>>(hist1, zrDw);
    k_feat_t<<<dim3(7, 25, 16), 256, 0, stream>>>(feat, feat_t);
    k_wt_t<<<(9 * 512 * 512 + 255) / 256, 256, 0, stream>>>(conv_w, wt_t);
    // 1) approx conv (bf16 MFMA, XCD-swizzled, async-staged) + approx cls
    k_conv3_mfma<<<8 * 169, 256, 0, stream>>>(feat_t, wt_t, conv_b, xab);
    k_cls<<<HW_ / 64, 256, 0, stream>>>(xab, cls_w, cls_b, scores);
    // 2) candidate pixels: approx top-KSEL bucket threshold (LDS hist)
    k_hist1_lds<<<64, 256, 0, stream>>>(scores, hist1);
    k_find_thr<<<1, 1024, 0, stream>>>(hist1, meta, 0, KSEL);
    k_collect_cand<<<(NANCH + 255) / 256, 256, 0, stream>>>(scores, meta, flags);
    k_px_compact<<<(HW_ + 255) / 256, 256, 0, stream>>>(flags, meta, px_list);
    // 2b) exact-path layouts (deferred from step 0)
    k_zero_border_px<<<(804 * 128 + 255) / 256, 256, 0, stream>>>(feat_px);
    k_feat_px<<<dim3(7, 25, 16), 256, 0, stream>>>(feat, feat_px);
    k_wt_ex<<<dim3(144, 16), dim3(32, 8), 0, stream>>>(conv_w, wt_ex);
    // 3) exact fp32 conv at candidates: direct-staged K-split GEMM -> reduce
    k_zero_u32<<<(65536 * 2 + 255) / 256, 256, 0, stream>>>(hist1, 65536 * 2);
    k_exact_gemm<<<dim3(PXCAP / 64, 4, KSPLIT), 256, 0, stream>>>(feat_px, wt_ex, meta, px_list, xpart);
    k_exact_reduce<<<PXCAP * 512 / 256, 256, 0, stream>>>(xpart, conv_b, meta, xex);
    k_exact_scores<<<PXCAP, 64, 0, stream>>>(xex, cls_w, cls_b, meta, scores_ex);
    // 4) exact stable top-1000 among candidate anchors (global indices)
    k_hist1_ex_lds<<<32, 256, 0, stream>>>(scores_ex, meta, hist1);
    k_find_thr<<<1, 1024, 0, stream>>>(hist1, meta_ex, 0, KPRE);
    k_hist2_ex<<<(PXCAP * 9 + 255) / 256, 256, 0, stream>>>(scores_ex, meta, meta_ex, hist2);
    k_find_thr<<<1, 1024, 0, stream>>>(hist2, meta_ex, 1, KPRE);
    k_collect_ex<<<(PXCAP * 9 + 255) / 256, 256, 0, stream>>>(scores_ex, meta, meta_ex, px_list,
                                                              sel_bits, sel_idx, eq_idx);
    k_topk_final<<<1, 1024, 0, stream>>>(sel_bits, sel_idx, eq_idx, meta_ex, top_idx, top_sc);
    // 5) exact decode + NMS
    k_decode<<<KPRE, 64, 0, stream>>>(xex, flags, reg_w, reg_b, top_idx, props, areas);
    k_nms_mask<<<KPRE, 256, 0, stream>>>(props, areas, mask, out);
    k_nms_scan_out<<<1, 64, 0, stream>>>(mask, props, top_sc, out);
}

// Round 9
// 693.350 us; speedup vs baseline: 10.0912x; 1.1419x over previous
//
#include <hip/hip_runtime.h>
#include <stdint.h>

// Problem constants
static constexpr int H_ = 200, W_ = 200, HW_ = 40000;
static constexpr int C_ = 512;
static constexpr int NANCH = 360000;   // HW_ * 9
static constexpr int KPRE = 1000;
static constexpr int KPOST = 100;
static constexpr int KSEL = 1400;      // approx candidate margin (top-1000 + 400)
static constexpr int PXCAP = 4096;     // candidate pixel cap (est npx ~1600)
static constexpr int KSPLIT = 8;       // exact-gemm K split (4608 = 8 x 576)
// feat_t padded dims: [212 y][212 x][512 ci] bf16, real (y,x) at (y+1,x+1)
static constexpr int FT = 212;
// feat_px padded dims: [202][202][512] fp32, real (y,x) at (y+1,x+1)
static constexpr int FP = 202;

typedef __attribute__((ext_vector_type(8))) short bf16x8;
typedef __attribute__((ext_vector_type(4))) float f32x4;

__device__ inline ushort f2bf(float f) {               // RNE float->bf16 bits
    unsigned u = __float_as_uint(f);
    u += 0x7FFFu + ((u >> 16) & 1u);
    return (ushort)(u >> 16);
}
__device__ inline float bf2f(ushort h) { return __uint_as_float(((unsigned)h) << 16); }

// async global->LDS 16B: per-lane global src, LDS dst = wave-uniform base + lane*16
typedef const __attribute__((address_space(1))) uint32_t gas_u32;
typedef __attribute__((address_space(3))) uint32_t las_u32;
__device__ __forceinline__ void gload_lds16(const void* g, void* l) {
    __builtin_amdgcn_global_load_lds((gas_u32*)(uintptr_t)g, (las_u32*)(uintptr_t)l, 16, 0, 0);
}

// ---------------------------------------------------------------------------
__global__ void k_zero_u32(unsigned* __restrict__ p, int n) {
    int i = blockIdx.x * 256 + threadIdx.x;
    if (i < n) p[i] = 0u;
}

// Border-only zeroing (interiors are fully overwritten by k_feat_t/k_feat_px).
__global__ void k_zero_border_t(ushort* __restrict__ feat_t) {
    int t = blockIdx.x * 256 + threadIdx.x;
    int total = 4944 * 64;           // 512 bf16 = 64 x uint4 per px
    if (t >= total) return;
    int px = t >> 6, part = t & 63;
    int y, x;
    if (px < 2544) { int ri = px / 212; x = px - ri * 212; y = (ri == 0) ? 0 : 200 + ri; }
    else { int q = px - 2544; int r12 = q / 12; int c = q - r12 * 12; y = 1 + r12; x = (c == 0) ? 0 : 200 + c; }
    uint4 z = {0u, 0u, 0u, 0u};
    *(uint4*)&feat_t[((size_t)y * FT + x) * 512 + part * 8] = z;
}

__global__ void k_zero_border_px(float* __restrict__ feat_px) {
    int t = blockIdx.x * 256 + threadIdx.x;
    int total = 804 * 128;           // 512 f32 = 128 x float4 per px
    if (t >= total) return;
    int px = t >> 7, part = t & 127;
    int y, x;
    if (px < 202)      { y = 0;   x = px; }
    else if (px < 404) { y = 201; x = px - 202; }
    else if (px < 604) { x = 0;   y = 1 + (px - 404); }
    else               { x = 201; y = 1 + (px - 604); }
    float4 z = {0.f, 0.f, 0.f, 0.f};
    *(float4*)&feat_px[((size_t)y * FP + x) * 512 + part * 4] = z;
}

// ---------------------------------------------------------------------------
// feat [512][200][200] f32 -> feat_t [212][212][512] bf16 (zero-padded)
// ---------------------------------------------------------------------------
__global__ void k_feat_t(const float* __restrict__ feat, ushort* __restrict__ feat_t) {
    __shared__ ushort lt[32 * 8 * 33];
    int x0 = blockIdx.x * 32, y0 = blockIdx.y * 8, ci0 = blockIdx.z * 32;
    int tid = threadIdx.x;
    for (int u = tid; u < 8192; u += 256) {
        int ciL = u >> 8, rem = u & 255;
        int yy = rem >> 5, xx = rem & 31;
        int x = x0 + xx;
        float v = (x < W_) ? feat[(size_t)(ci0 + ciL) * HW_ + (y0 + yy) * W_ + x] : 0.f;
        lt[(ciL * 8 + yy) * 33 + xx] = f2bf(v);
    }
    __syncthreads();
    for (int u = tid; u < 1024; u += 256) {
        int pxu = u >> 2, part = u & 3;
        int yy = pxu >> 5, xx = pxu & 31;
        if (x0 + xx >= W_) continue;
        ushort tmp[8];
#pragma unroll
        for (int k = 0; k < 8; ++k) tmp[k] = lt[((part * 8 + k) * 8 + yy) * 33 + xx];
        *(uint4*)&feat_t[((size_t)(y0 + yy + 1) * FT + (x0 + xx + 1)) * 512 + ci0 + part * 8] =
            *(const uint4*)&tmp[0];
    }
}

// feat -> feat_px [202][202][512] fp32 (zero-padded)
__global__ void k_feat_px(const float* __restrict__ feat, float* __restrict__ feat_px) {
    __shared__ float lt[32 * 8 * 33];
    int x0 = blockIdx.x * 32, y0 = blockIdx.y * 8, ci0 = blockIdx.z * 32;
    int tid = threadIdx.x;
    for (int u = tid; u < 8192; u += 256) {
        int ciL = u >> 8, rem = u & 255;
        int yy = rem >> 5, xx = rem & 31;
        int x = x0 + xx;
        float v = (x < W_) ? feat[(size_t)(ci0 + ciL) * HW_ + (y0 + yy) * W_ + x] : 0.f;
        lt[(ciL * 8 + yy) * 33 + xx] = v;
    }
    __syncthreads();
    for (int u = tid; u < 1024; u += 256) {
        int pxu = u >> 2, part = u & 3;
        int yy = pxu >> 5, xx = pxu & 31;
        if (x0 + xx >= W_) continue;
        float tmp[8];
#pragma unroll
        for (int k = 0; k < 8; ++k) tmp[k] = lt[((part * 8 + k) * 8 + yy) * 33 + xx];
        float* dst = &feat_px[((size_t)(y0 + yy + 1) * FP + (x0 + xx + 1)) * 512 + ci0 + part * 8];
        *(float4*)&dst[0] = *(const float4*)&tmp[0];
        *(float4*)&dst[4] = *(const float4*)&tmp[4];
    }
}

// conv_w [co][ci][th][tw] f32 -> wt_t [tap9][co512][ci512] bf16
__global__ void k_wt_t(const float* __restrict__ conv_w, ushort* __restrict__ wt_t) {
    int i = blockIdx.x * 256 + threadIdx.x;
    if (i >= 9 * 512 * 512) return;
    int tap = i >> 18;
    int rem = i & 262143;
    int co = rem >> 9, ci = rem & 511;
    wt_t[i] = f2bf(conv_w[((size_t)co * 512 + ci) * 9 + tap]);
}

// conv_w -> wt_ex [k'=tap*512+ci][co512] fp32 (LDS 32x32 transpose)
__global__ void k_wt_ex(const float* __restrict__ conv_w, float* __restrict__ wt_ex) {
    __shared__ float t[32][33];
    int kb = blockIdx.x * 32;   // k' base (4608/32 = 144), single tap per tile
    int cb = blockIdx.y * 32;
    int lx = threadIdx.x, ly = threadIdx.y;
    int tap = kb >> 9, ci0 = kb & 511;
    for (int r = ly; r < 32; r += 8)
        t[r][lx] = conv_w[((size_t)(cb + r) * 512 + ci0 + lx) * 9 + tap];
    __syncthreads();
    for (int r = ly; r < 32; r += 8)
        wt_ex[(size_t)(kb + r) * 512 + cb + lx] = t[lx][r];
}

// ---------------------------------------------------------------------------
// Approx conv v3: bf16 MFMA 16x16x32. Block = 64 co x (16x16 px), 4 waves.
// XCD swizzle (cot = b&7); staging via global_load_lds width=16, linear LDS.
// ---------------------------------------------------------------------------
__global__ __launch_bounds__(256)
__attribute__((amdgpu_waves_per_eu(2, 4)))
void k_conv3_mfma(const ushort* __restrict__ feat_t, const ushort* __restrict__ wt_t,
                  const float* __restrict__ bias, ushort* __restrict__ xab) {
    __shared__ ushort halo[18 * 18 * 32];   // [r][c][32ci] 20.7 KB (linear)
    __shared__ ushort wtile[9 * 64 * 32];   // [tap][co][32ci] 36.9 KB (linear)
    int b = blockIdx.x;
    int cot = b & 7;            // XCD-aligned co-slice
    int tile = b >> 3;          // 0..168
    int xt = tile % 13, yt = tile / 13;
    int x0 = xt * 16, y0 = yt * 16;
    int co0 = cot * 64;
    int tid = threadIdx.x;
    int lane = tid & 63, wid = tid >> 6;
    int l15 = lane & 15, l4 = lane >> 4;

    f32x4 acc[4][4];
#pragma unroll
    for (int i = 0; i < 4; ++i)
#pragma unroll
        for (int j = 0; j < 4; ++j) acc[i][j] = (f32x4){0.f, 0.f, 0.f, 0.f};

    for (int ch = 0; ch < 16; ++ch) {
        int ci0 = ch * 32;
        __syncthreads();   // previous chunk's reads done
        for (int u = tid; u < 1296; u += 256) {
            int p = u >> 2, q = u & 3;
            int r = p / 18, c = p - r * 18;
            const ushort* src = feat_t + ((size_t)(y0 + r) * FT + (x0 + c)) * 512 + ci0 + q * 8;
            gload_lds16(src, &halo[(u & ~63) * 8]);
        }
        for (int u = tid; u < 2304; u += 256) {
            int row = u >> 2, q = u & 3;       // row = tap*64 + co
            int tap = row >> 6, co = row & 63;
            const ushort* src = wt_t + ((size_t)(tap * 512 + co0 + co)) * 512 + ci0 + q * 8;
            gload_lds16(src, &wtile[(u & ~63) * 8]);
        }
        __syncthreads();   // drains vmcnt -> LDS valid
#pragma unroll
        for (int tap = 0; tap < 9; ++tap) {
            int th = tap / 3, tw = tap - th * 3;
            bf16x8 af[4], bf[4];
#pragma unroll
            for (int pi = 0; pi < 4; ++pi)
                af[pi] = *(const bf16x8*)&halo[((wid * 4 + pi + th) * 18 + (l15 + tw)) * 32 + l4 * 8];
#pragma unroll
            for (int cj = 0; cj < 4; ++cj)
                bf[cj] = *(const bf16x8*)&wtile[(tap * 64 + cj * 16 + l15) * 32 + l4 * 8];
#pragma unroll
            for (int pi = 0; pi < 4; ++pi)
#pragma unroll
                for (int cj = 0; cj < 4; ++cj)
                    acc[pi][cj] = __builtin_amdgcn_mfma_f32_16x16x32_bf16(af[pi], bf[cj], acc[pi][cj], 0, 0, 0);
        }
    }

    float bv[4];
#pragma unroll
    for (int cj = 0; cj < 4; ++cj) bv[cj] = bias[co0 + cj * 16 + l15];
#pragma unroll
    for (int pi = 0; pi < 4; ++pi) {
        int yy = y0 + wid * 4 + pi;
        if (yy >= H_) continue;
#pragma unroll
        for (int cj = 0; cj < 4; ++cj) {
            int co = co0 + cj * 16 + l15;
#pragma unroll
            for (int r = 0; r < 4; ++r) {
                int xx = x0 + l4 * 4 + r;
                if (xx < W_) {
                    float v = acc[pi][cj][r] + bv[cj];
                    xab[((size_t)(yy * W_ + xx)) * 512 + co] = f2bf(v > 0.f ? v : 0.f);
                }
            }
        }
    }
}

// ---------------------------------------------------------------------------
// Approx cls: scores[px*9+a] = sigmoid(dot(xab row, cls_w[a]) + b). Wave/px.
// ---------------------------------------------------------------------------
__global__ void k_cls(const ushort* __restrict__ xab, const float* __restrict__ cls_w,
                      const float* __restrict__ cls_b, float* __restrict__ scores) {
    __shared__ float wl[9 * 512];
    int tid = threadIdx.x;
    for (int t = tid; t < 4608; t += 256) wl[t] = cls_w[t];
    __syncthreads();
    int l = tid & 63, w = tid >> 6;
    int pbase = blockIdx.x * 64 + w * 16;
    for (int u = 0; u < 16; ++u) {
        int px = pbase + u;
        float xv[8];
#pragma unroll
        for (int k = 0; k < 8; ++k) xv[k] = bf2f(xab[(size_t)px * 512 + k * 64 + l]);
#pragma unroll
        for (int a = 0; a < 9; ++a) {
            float s = 0.f;
#pragma unroll
            for (int k = 0; k < 8; ++k) s = fmaf(xv[k], wl[a * 512 + k * 64 + l], s);
#pragma unroll
            for (int o = 32; o > 0; o >>= 1) s += __shfl_down(s, o);
            if (l == 0) scores[(size_t)px * 9 + a] = 1.f / (1.f + expf(-(s + cls_b[a])));
        }
    }
}

// ---------------------------------------------------------------------------
// Radix-select helpers
// meta: [0]=P [1]=cntAboveP [2]=T [3]=cntGtT [4]=need [8]=atomGt [9]=atomEq [10]=npx
// ---------------------------------------------------------------------------
__global__ void k_hist1_lds(const float* __restrict__ scores, unsigned* __restrict__ hist) {
    __shared__ unsigned h[16384];
    int tid = threadIdx.x;
    for (int j = tid; j < 16384; j += 256) h[j] = 0u;
    __syncthreads();
    int stride = gridDim.x * 256;
    for (int i = blockIdx.x * 256 + tid; i < NANCH; i += stride)
        atomicAdd(&h[(__float_as_uint(scores[i]) >> 16) & 16383], 1u);
    __syncthreads();
    for (int j = tid; j < 16384; j += 256) {
        unsigned v = h[j];
        if (v) atomicAdd(&hist[j], v);
    }
}

__global__ void k_find_thr(const unsigned* __restrict__ hist, unsigned* __restrict__ meta,
                           int mode, int Kwant) {
    __shared__ unsigned csum[1024];
    int t = threadIdx.x;
    unsigned base = (mode == 0) ? 0u : meta[1];
    unsigned s = 0;
    for (int b = 0; b < 64; ++b) s += hist[t * 64 + b];
    csum[t] = s;
    __syncthreads();
    for (int off = 1; off < 1024; off <<= 1) {
        unsigned add = (t + off < 1024) ? csum[t + off] : 0u;
        __syncthreads();
        csum[t] += add;
        __syncthreads();
    }
    unsigned run = base + ((t < 1023) ? csum[t + 1] : 0u);
    for (int b = 63; b >= 0; --b) {
        unsigned h = hist[t * 64 + b];
        if (run < (unsigned)Kwant && run + h >= (unsigned)Kwant) {
            if (mode == 0) {
                meta[0] = (unsigned)(t * 64 + b);
                meta[1] = run;
            } else {
                meta[2] = (meta[0] << 16) | (unsigned)(t * 64 + b);
                meta[3] = run;
                meta[4] = (unsigned)Kwant - run;
            }
            break;
        }
        run += h;
    }
}

// mark candidate pixels: anchors with hi16(score) >= P
__global__ void k_collect_cand(const float* __restrict__ scores, const unsigned* __restrict__ meta,
                               unsigned* __restrict__ flags) {
    int i = blockIdx.x * 256 + threadIdx.x;
    if (i >= NANCH) return;
    if ((__float_as_uint(scores[i]) >> 16) >= meta[0]) flags[i / 9] = 1u;
}

__global__ void k_px_compact(unsigned* __restrict__ flags, unsigned* __restrict__ meta,
                             unsigned* __restrict__ px_list) {
    int px = blockIdx.x * 256 + threadIdx.x;
    if (px >= HW_) return;
    if (flags[px]) {
        unsigned s = atomicAdd(&meta[10], 1u);
        if (s < (unsigned)PXCAP) { px_list[s] = (unsigned)px; flags[px] = s + 1u; }
        else flags[px] = 0u;
    }
}

// ---------------------------------------------------------------------------
// Exact fp32 conv GEMM v4: C[64co x 64px], K split x8 (576 each; every 32-k
// chunk lies in one tap since 512%32==0). ~25x8x8=1600 active blocks -> ~6/CU,
// staging latency hidden by TLP (v3 was 1.6 blocks/CU, VALUBusy 23%).
// ---------------------------------------------------------------------------
__global__ __attribute__((amdgpu_waves_per_eu(2, 4)))
void k_exact_gemm(const float* __restrict__ feat_px, const float* __restrict__ wt_ex,
                  const unsigned* __restrict__ meta, const unsigned* __restrict__ px_list,
                  float* __restrict__ xpart) {
    int npx = (int)meta[10]; if (npx > PXCAP) npx = PXCAP;
    int pb = blockIdx.x;
    if (pb * 64 >= npx) return;
    int cot = blockIdx.y;           // 0..7 -> 64 co
    int kz = blockIdx.z;            // 0..7 -> K = 576
    __shared__ float A[32][68];
    __shared__ float B[32][68];
    __shared__ int plist[64];
    int tid = threadIdx.x;
    int co0 = cot * 64;
    if (tid < 64) {
        int slot = pb * 64 + tid;
        plist[tid] = (slot < npx) ? (int)px_list[slot] : (int)px_list[0];
    }
    int tcog = tid >> 4;   // 16 groups x 4 co
    int tpxg = tid & 15;   // 16 groups x 4 px
    float acc[4][4];
#pragma unroll
    for (int i = 0; i < 4; ++i)
#pragma unroll
        for (int j = 0; j < 4; ++j) acc[i][j] = 0.f;
    int kbase = kz * 576;
    for (int kc = 0; kc < 18; ++kc) {
        int k0 = kbase + kc * 32;
        int tap = k0 >> 9, ci0c = k0 & 511;
        int th = tap / 3, tw = tap - th * 3;
        __syncthreads();
        for (int u = tid; u < 512; u += 256) {           // A: 32k x 64co from wt_ex
            int k = u >> 4, cp = (u & 15) * 4;
            *(float4*)&A[k][cp] = *(const float4*)&wt_ex[(size_t)(k0 + k) * 512 + co0 + cp];
        }
        for (int u = tid; u < 512; u += 256) {           // B: 64px x 32ci from feat_px
            int s = u >> 3, part = u & 7;
            int px = plist[s];
            int y = px / W_, x = px - y * W_;
            float4 v = *(const float4*)&feat_px[((size_t)(y + th) * FP + (x + tw)) * 512 + ci0c + part * 4];
            B[part * 4 + 0][s] = v.x; B[part * 4 + 1][s] = v.y;
            B[part * 4 + 2][s] = v.z; B[part * 4 + 3][s] = v.w;
        }
        __syncthreads();
#pragma unroll 4
        for (int k = 0; k < 32; ++k) {
            float wv[4], pv[4];
            *(float4*)&wv[0] = *(const float4*)&A[k][tcog * 4];
            *(float4*)&pv[0] = *(const float4*)&B[k][tpxg * 4];
#pragma unroll
            for (int i = 0; i < 4; ++i)
#pragma unroll
                for (int j = 0; j < 4; ++j) acc[i][j] = fmaf(wv[i], pv[j], acc[i][j]);
        }
    }
#pragma unroll
    for (int j = 0; j < 4; ++j) {
        int slot = pb * 64 + tpxg * 4 + j;
        if (slot >= npx) continue;
        float tmp[4];
#pragma unroll
        for (int i = 0; i < 4; ++i) tmp[i] = acc[i][j];
        *(float4*)&xpart[((size_t)kz * PXCAP + slot) * 512 + co0 + tcog * 4] = *(float4*)&tmp[0];
    }
}

// fixed-order reduce of K-split partials + bias + relu -> xex
__global__ void k_exact_reduce(const float* __restrict__ xpart, const float* __restrict__ bias,
                               const unsigned* __restrict__ meta, float* __restrict__ xex) {
    int npx = (int)meta[10]; if (npx > PXCAP) npx = PXCAP;
    int idx = blockIdx.x * 256 + threadIdx.x;
    int slot = idx >> 9, co = idx & 511;
    if (slot >= npx) return;
    float v = 0.f;
#pragma unroll
    for (int kz = 0; kz < KSPLIT; ++kz)
        v += xpart[((size_t)kz * PXCAP + slot) * 512 + co];
    v += bias[co];
    xex[(size_t)slot * 512 + co] = v > 0.f ? v : 0.f;
}

// exact scores for all 9 anchors of each candidate pixel
__global__ void k_exact_scores(const float* __restrict__ xex, const float* __restrict__ cls_w,
                               const float* __restrict__ cls_b, const unsigned* __restrict__ meta,
                               float* __restrict__ scores_ex) {
    int slot = blockIdx.x;
    int npx = (int)meta[10]; if (npx > PXCAP) npx = PXCAP;
    if (slot >= npx) return;
    int l = threadIdx.x;
    float xv[8];
#pragma unroll
    for (int k = 0; k < 8; ++k) xv[k] = xex[(size_t)slot * 512 + k * 64 + l];
#pragma unroll
    for (int a = 0; a < 9; ++a) {
        float s = 0.f;
#pragma unroll
        for (int k = 0; k < 8; ++k) s = fmaf(xv[k], cls_w[a * 512 + k * 64 + l], s);
#pragma unroll
        for (int o = 32; o > 0; o >>= 1) s += __shfl_down(s, o);
        if (l == 0) scores_ex[slot * 9 + a] = 1.f / (1.f + expf(-(s + cls_b[a])));
    }
}

__global__ void k_hist1_ex_lds(const float* __restrict__ scores_ex, const unsigned* __restrict__ meta,
                               unsigned* __restrict__ hist) {
    __shared__ unsigned h[16384];
    int npx = (int)meta[10]; if (npx > PXCAP) npx = PXCAP;
    int n = npx * 9;
    int tid = threadIdx.x;
    for (int j = tid; j < 16384; j += 256) h[j] = 0u;
    __syncthreads();
    for (int i = blockIdx.x * 256 + tid; i < n; i += 32 * 256)
        atomicAdd(&h[(__float_as_uint(scores_ex[i]) >> 16) & 16383], 1u);
    __syncthreads();
    for (int j = tid; j < 16384; j += 256) {
        unsigned v = h[j];
        if (v) atomicAdd(&hist[j], v);
    }
}

__global__ void k_hist2_ex(const float* __restrict__ scores_ex, const unsigned* __restrict__ meta,
                           const unsigned* __restrict__ meta_ex, unsigned* __restrict__ hist2) {
    int npx = (int)meta[10]; if (npx > PXCAP) npx = PXCAP;
    int i = blockIdx.x * 256 + threadIdx.x;
    if (i >= npx * 9) return;
    unsigned b = __float_as_uint(scores_ex[i]);
    if ((b >> 16) == meta_ex[0]) atomicAdd(&hist2[b & 0xFFFFu], 1u);
}

__global__ void k_collect_ex(const float* __restrict__ scores_ex, const unsigned* __restrict__ meta,
                             unsigned* __restrict__ meta_ex, const unsigned* __restrict__ px_list,
                             unsigned* __restrict__ sel_bits, unsigned* __restrict__ sel_idx,
                             unsigned* __restrict__ eq_idx) {
    int npx = (int)meta[10]; if (npx > PXCAP) npx = PXCAP;
    int i = blockIdx.x * 256 + threadIdx.x;
    if (i >= npx * 9) return;
    unsigned b = __float_as_uint(scores_ex[i]);
    unsigned T = meta_ex[2];
    unsigned g = px_list[i / 9] * 9u + (unsigned)(i % 9);
    if (b > T) {
        unsigned s = atomicAdd(&meta_ex[8], 1u);
        if (s < 1024u) { sel_bits[s] = b; sel_idx[s] = g; }
    } else if (b == T) {
        unsigned s = atomicAdd(&meta_ex[9], 1u);
        if (s < 65536u) eq_idx[s] = g;
    }
}

// exact stable top-1000 (ties -> smallest global idx), bitonic final order
__global__ void k_topk_final(const unsigned* __restrict__ sel_bits, const unsigned* __restrict__ sel_idx,
                             const unsigned* __restrict__ eq_idx, const unsigned* __restrict__ meta,
                             unsigned* __restrict__ top_idx, float* __restrict__ top_sc) {
    __shared__ uint64_t keys[1024];
    __shared__ int lcnt;
    __shared__ int lred;
    int t = threadIdx.x;
    unsigned cntGt = meta[3];
    unsigned need = meta[4];
    unsigned cntEq = meta[9];
    unsigned T = meta[2];

    unsigned idx_cut = 0xFFFFFFFFu;
    if (cntEq > need) {
        unsigned lo = 0, hi = NANCH - 1;
        while (lo < hi) {
            unsigned mid = (lo + hi) >> 1;
            int c = 0;
            for (unsigned e = t; e < cntEq; e += 1024)
                if (eq_idx[e] <= mid) c++;
            if (t == 0) lred = 0;
            __syncthreads();
            atomicAdd(&lred, c);
            __syncthreads();
            int tot = lred;
            __syncthreads();
            if ((unsigned)tot >= need) hi = mid; else lo = mid + 1;
        }
        idx_cut = lo;
    }

    keys[t] = 0ull;
    if (t == 0) lcnt = 0;
    __syncthreads();
    for (unsigned s = t; s < cntGt; s += 1024)
        keys[s] = ((uint64_t)sel_bits[s] << 32) | (uint64_t)(0xFFFFFFFFu - sel_idx[s]);
    for (unsigned e = t; e < cntEq; e += 1024) {
        unsigned ix = eq_idx[e];
        if (ix <= idx_cut) {
            int s2 = (int)cntGt + atomicAdd(&lcnt, 1);
            keys[s2] = ((uint64_t)T << 32) | (uint64_t)(0xFFFFFFFFu - ix);
        }
    }
    __syncthreads();
    for (int k = 2; k <= 1024; k <<= 1) {
        for (int j = k >> 1; j > 0; j >>= 1) {
            int ixj = t ^ j;
            if (ixj > t) {
                uint64_t a = keys[t], b = keys[ixj];
                bool desc = (t & k) == 0;
                if (desc ? (a < b) : (a > b)) { keys[t] = b; keys[ixj] = a; }
            }
            __syncthreads();
        }
    }
    if (t < KPRE) {
        top_sc[t] = __uint_as_float((unsigned)(keys[t] >> 32));
        top_idx[t] = 0xFFFFFFFFu - (unsigned)keys[t];
    }
}

// ---------------------------------------------------------------------------
// decode from exact x (via flags px->slot map)
// ---------------------------------------------------------------------------
__global__ void k_decode(const float* __restrict__ xex, const unsigned* __restrict__ flags,
                         const float* __restrict__ reg_w, const float* __restrict__ reg_b,
                         const unsigned* __restrict__ top_idx,
                         float* __restrict__ props, float* __restrict__ areas) {
    int j = blockIdx.x;
    int lane = threadIdx.x;  // 64
    unsigned idx = top_idx[j];
    int pix = (int)(idx / 9u);
    int a = (int)(idx - (unsigned)pix * 9u);
    int slot = (int)flags[pix] - 1;
    if (slot < 0) slot = 0;
    const float* xr = xex + (size_t)slot * 512;
    float s0 = 0, s1 = 0, s2 = 0, s3 = 0;
    for (int c = lane; c < C_; c += 64) {
        float xv = xr[c];
        s0 = fmaf(xv, reg_w[(a * 4 + 0) * C_ + c], s0);
        s1 = fmaf(xv, reg_w[(a * 4 + 1) * C_ + c], s1);
        s2 = fmaf(xv, reg_w[(a * 4 + 2) * C_ + c], s2);
        s3 = fmaf(xv, reg_w[(a * 4 + 3) * C_ + c], s3);
    }
#pragma unroll
    for (int o = 32; o > 0; o >>= 1) {
        s0 += __shfl_down(s0, o);
        s1 += __shfl_down(s1, o);
        s2 += __shfl_down(s2, o);
        s3 += __shfl_down(s3, o);
    }
    if (lane == 0) {
        float d0 = s0 + reg_b[a * 4 + 0];
        float d1 = s1 + reg_b[a * 4 + 1];
        float d2 = s2 + reg_b[a * 4 + 2];
        float d3 = s3 + reg_b[a * 4 + 3];
        int h = pix / W_, w2 = pix - h * W_;
        int rr = a / 3, ss = a - rr * 3;
        float ratio = (rr == 0) ? 0.5f : (rr == 1) ? 1.0f : 2.0f;
        float scale = (ss == 0) ? 128.f : (ss == 1) ? 256.f : 512.f;
        float hr = sqrtf(ratio);
        float wr = 1.0f / hr;
        float wsc = wr * scale, hsc = hr * scale;
        float sx = (float)w2 * 16.f, sy = (float)h * 16.f;
        float a0 = sx - wsc * 0.5f, a1 = sy - hsc * 0.5f;
        float a2 = sx + wsc * 0.5f, a3 = sy + hsc * 0.5f;
        float bw = a2 - a0, bh = a3 - a1;
        float cx = a0 + 0.5f * bw, cy = a1 + 0.5f * bh;
        float px = d0 * bw + cx, py = d1 * bh + cy;
        float pw = expf(d2) * bw, ph = expf(d3) * bh;
        float b0 = px - 0.5f * pw, b1 = py - 0.5f * ph;
        float b2 = px + 0.5f * pw, b3 = py + 0.5f * ph;
        b0 = fminf(fmaxf(b0, 0.f), 3200.f);
        b1 = fminf(fmaxf(b1, 0.f), 3200.f);
        b2 = fminf(fmaxf(b2, 0.f), 3200.f);
        b3 = fminf(fmaxf(b3, 0.f), 3200.f);
        props[j * 4 + 0] = b0;
        props[j * 4 + 1] = b1;
        props[j * 4 + 2] = b2;
        props[j * 4 + 3] = b3;
        areas[j] = (b2 - b0) * (b3 - b1);
    }
}

// ---------------------------------------------------------------------------
__global__ void k_nms_mask(const float* __restrict__ props, const float* __restrict__ areas,
                           unsigned long long* __restrict__ mask, float* __restrict__ out) {
    int i = blockIdx.x;
    int tid = threadIdx.x;  // 256
    if (i == 0) {
        for (int t = tid; t < KPOST * 5; t += 256) out[t] = 0.f;
    }
    float x1i = props[i * 4 + 0], y1i = props[i * 4 + 1];
    float x2i = props[i * 4 + 2], y2i = props[i * 4 + 3];
    float ai = areas[i];
#pragma unroll
    for (int k = 0; k < 4; ++k) {
        int j = k * 256 + tid;
        bool sup = false;
        if (j < KPRE && j > i) {
            float iw = fminf(x2i, props[j * 4 + 2]) - fmaxf(x1i, props[j * 4 + 0]);
            float ih = fminf(y2i, props[j * 4 + 3]) - fmaxf(y1i, props[j * 4 + 1]);
            iw = fmaxf(iw, 0.f);
            ih = fmaxf(ih, 0.f);
            float inter = iw * ih;
            float iou = inter / (ai + areas[j] - inter);
            sup = iou > 0.7f;
        }
        unsigned long long b = __ballot(sup);
        int word = k * 4 + (tid >> 6);
        if ((tid & 63) == 0) mask[(size_t)i * 16 + word] = b;
    }
}

// ---------------------------------------------------------------------------
// NMS scan v2: kept-box iteration with early exit at 100 kept.
// ---------------------------------------------------------------------------
__global__ void k_nms_scan_out(const unsigned long long* __restrict__ mask,
                               const float* __restrict__ props, const float* __restrict__ top_sc,
                               float* __restrict__ out) {
    __shared__ int kidx[KPOST];
    __shared__ int nk;
    int lane = threadIdx.x;  // 64
    if (lane == 0) {
        unsigned long long k0 = ~0ull, k1 = ~0ull, k2 = ~0ull, k3 = ~0ull;
        unsigned long long k4 = ~0ull, k5 = ~0ull, k6 = ~0ull, k7 = ~0ull;
        unsigned long long k8 = ~0ull, k9 = ~0ull, k10 = ~0ull, k11 = ~0ull;
        unsigned long long k12 = ~0ull, k13 = ~0ull, k14 = ~0ull;
        unsigned long long k15 = (1ull << 40) - 1ull;   // 1000 bits total
        int kept = 0;
#define APPLY_ROW(ii) { const unsigned long long* row = &mask[(size_t)(ii) * 16];          \
        k0 &= ~row[0];  k1 &= ~row[1];  k2 &= ~row[2];  k3 &= ~row[3];                     \
        k4 &= ~row[4];  k5 &= ~row[5];  k6 &= ~row[6];  k7 &= ~row[7];                     \
        k8 &= ~row[8];  k9 &= ~row[9];  k10 &= ~row[10]; k11 &= ~row[11];                  \
        k12 &= ~row[12]; k13 &= ~row[13]; k14 &= ~row[14]; k15 &= ~row[15]; }
#define SCAN_WORD(w, kw) { \
        unsigned long long rem = kw; \
        while (rem) { \
            int b = __builtin_ctzll(rem); \
            kidx[kept++] = (w) * 64 + b; \
            if (kept == KPOST) goto done; \
            APPLY_ROW((w) * 64 + b); \
            rem &= kw; \
            rem &= (b >= 63) ? 0ull : ~((2ull << b) - 1ull); \
        } }
        SCAN_WORD(0, k0)  SCAN_WORD(1, k1)  SCAN_WORD(2, k2)  SCAN_WORD(3, k3)
        SCAN_WORD(4, k4)  SCAN_WORD(5, k5)  SCAN_WORD(6, k6)  SCAN_WORD(7, k7)
        SCAN_WORD(8, k8)  SCAN_WORD(9, k9)  SCAN_WORD(10, k10) SCAN_WORD(11, k11)
        SCAN_WORD(12, k12) SCAN_WORD(13, k13) SCAN_WORD(14, k14) SCAN_WORD(15, k15)
done:
        nk = kept;
#undef SCAN_WORD
#undef APPLY_ROW
    }
    __syncthreads();
    int n = nk;
    for (int t = lane; t < KPOST; t += 64) {
        if (t < n) {
            int i = kidx[t];
            out[t * 4 + 0] = props[i * 4 + 0];
            out[t * 4 + 1] = props[i * 4 + 1];
            out[t * 4 + 2] = props[i * 4 + 2];
            out[t * 4 + 3] = props[i * 4 + 3];
            out[KPOST * 4 + t] = top_sc[i];
        }
    }
}

// ---------------------------------------------------------------------------
extern "C" void kernel_launch(void* const* d_in, const int* in_sizes, int n_in,
                              void* d_out, int out_size, void* d_ws, size_t ws_size,
                              hipStream_t stream) {
    const float* feat   = (const float*)d_in[0];
    const float* conv_w = (const float*)d_in[1];
    const float* conv_b = (const float*)d_in[2];
    const float* cls_w  = (const float*)d_in[3];
    const float* cls_b  = (const float*)d_in[4];
    const float* reg_w  = (const float*)d_in[5];
    const float* reg_b  = (const float*)d_in[6];
    float* out = (float*)d_out;

    size_t off = 0;
    auto alloc = [&](size_t bytes) -> void* {
        off = (off + 255) & ~(size_t)255;
        void* p = (char*)d_ws + off;
        off += bytes;
        return p;
    };
    ushort* feat_t  = (ushort*)alloc((size_t)FT * FT * 512 * 2);        // 46.0 MB
    float*  feat_px = (float*)alloc((size_t)FP * FP * 512 * 4);         // 83.6 MB
    ushort* wt_t    = (ushort*)alloc((size_t)9 * 512 * 512 * 2);        // 4.7 MB
    float*  wt_ex   = (float*)alloc((size_t)9 * 512 * 512 * 4);         // 9.4 MB
    ushort* xab     = (ushort*)alloc((size_t)HW_ * 512 * 2);            // 41 MB
    float*  xpart   = (float*)alloc((size_t)KSPLIT * PXCAP * 512 * 4);  // 67 MB
    float*  xex     = (float*)alloc((size_t)PXCAP * 512 * 4);           // 8.4 MB
    float*  scores  = (float*)alloc((size_t)NANCH * 4);                 // 1.44 MB
    float*  scores_ex = (float*)alloc((size_t)PXCAP * 9 * 4);
    // contiguous zero region: hist1, hist2, meta, meta_ex, flags
    unsigned* hist1   = (unsigned*)alloc(65536 * 4);
    unsigned* hist2   = (unsigned*)alloc(65536 * 4);
    unsigned* meta    = (unsigned*)alloc(64 * 4);
    unsigned* meta_ex = (unsigned*)alloc(64 * 4);
    unsigned* flags   = (unsigned*)alloc((size_t)HW_ * 4);
    unsigned* px_list = (unsigned*)alloc(PXCAP * 4);
    unsigned* sel_bits = (unsigned*)alloc(1024 * 4);
    unsigned* sel_idx  = (unsigned*)alloc(1024 * 4);
    unsigned* eq_idx   = (unsigned*)alloc(65536 * 4);
    unsigned* top_idx  = (unsigned*)alloc(KPRE * 4);
    float* top_sc      = (float*)alloc(KPRE * 4);
    float* props       = (float*)alloc(KPRE * 4 * 4);
    float* areas       = (float*)alloc(KPRE * 4);
    unsigned long long* mask = (unsigned long long*)alloc((size_t)KPRE * 16 * 8);
    (void)ws_size; (void)in_sizes; (void)n_in; (void)out_size;

    // 0) prep for APPROX path only (feat_px/wt_ex deferred to keep feat_t/wt_t
    //    L3-resident for conv)
    k_zero_border_t<<<(4944 * 64 + 255) / 256, 256, 0, stream>>>(feat_t);
    int zrDw = 65536 * 2 + 64 + 64 + HW_;
    k_zero_u32<<<(zrDw + 255) / 256, 256, 0, stream>>>(hist1, zrDw);
    k_feat_t<<<dim3(7, 25, 16), 256, 0, stream>>>(feat, feat_t);
    k_wt_t<<<(9 * 512 * 512 + 255) / 256, 256, 0, stream>>>(conv_w, wt_t);
    // 1) approx conv (bf16 MFMA, XCD-swizzled, async-staged) + approx cls
    k_conv3_mfma<<<8 * 169, 256, 0, stream>>>(feat_t, wt_t, conv_b, xab);
    k_cls<<<HW_ / 64, 256, 0, stream>>>(xab, cls_w, cls_b, scores);
    // 2) candidate pixels: approx top-KSEL bucket threshold (LDS hist)
    k_hist1_lds<<<64, 256, 0, stream>>>(scores, hist1);
    k_find_thr<<<1, 1024, 0, stream>>>(hist1, meta, 0, KSEL);
    k_collect_cand<<<(NANCH + 255) / 256, 256, 0, stream>>>(scores, meta, flags);
    k_px_compact<<<(HW_ + 255) / 256, 256, 0, stream>>>(flags, meta, px_list);
    // 2b) exact-path layouts (deferred from step 0)
    k_zero_border_px<<<(804 * 128 + 255) / 256, 256, 0, stream>>>(feat_px);
    k_feat_px<<<dim3(7, 25, 16), 256, 0, stream>>>(feat, feat_px);
    k_wt_ex<<<dim3(144, 16), dim3(32, 8), 0, stream>>>(conv_w, wt_ex);
    // 3) exact fp32 conv at candidates: direct-staged K-split GEMM -> reduce
    k_zero_u32<<<(65536 * 2 + 255) / 256, 256, 0, stream>>>(hist1, 65536 * 2);
    k_exact_gemm<<<dim3(PXCAP / 64, 8, KSPLIT), 256, 0, stream>>>(feat_px, wt_ex, meta, px_list, xpart);
    k_exact_reduce<<<PXCAP * 512 / 256, 256, 0, stream>>>(xpart, conv_b, meta, xex);
    k_exact_scores<<<PXCAP, 64, 0, stream>>>(xex, cls_w, cls_b, meta, scores_ex);
    // 4) exact stable top-1000 among candidate anchors (global indices)
    k_hist1_ex_lds<<<32, 256, 0, stream>>>(scores_ex, meta, hist1);
    k_find_thr<<<1, 1024, 0, stream>>>(hist1, meta_ex, 0, KPRE);
    k_hist2_ex<<<(PXCAP * 9 + 255) / 256, 256, 0, stream>>>(scores_ex, meta, meta_ex, hist2);
    k_find_thr<<<1, 1024, 0, stream>>>(hist2, meta_ex, 1, KPRE);
    k_collect_ex<<<(PXCAP * 9 + 255) / 256, 256, 0, stream>>>(scores_ex, meta, meta_ex, px_list,
                                                              sel_bits, sel_idx, eq_idx);
    k_topk_final<<<1, 1024, 0, stream>>>(sel_bits, sel_idx, eq_idx, meta_ex, top_idx, top_sc);
    // 5) exact decode + NMS
    k_decode<<<KPRE, 64, 0, stream>>>(xex, flags, reg_w, reg_b, top_idx, props, areas);
    k_nms_mask<<<KPRE, 256, 0, stream>>>(props, areas, mask, out);
    k_nms_scan_out<<<1, 64, 0, stream>>>(mask, props, top_sc, out);
}